// Round 3
// baseline (2346.541 us; speedup 1.0000x reference)
//
#include <hip/hip_runtime.h>

typedef unsigned short u16;
#define DEV __device__ __forceinline__

constexpr int NP = 32768;
constexpr int C  = 128;
constexpr int NS = 16;
constexpr int RTOT = NP * NS;              // 524288 rows of [N,NS]
constexpr float EPS = 1e-5f;
constexpr float INV_R = 1.0f / (float)RTOT;

// ---- workspace layout (bytes); intermediates bf16 to fit proven ws>=42.1MB
constexpr size_t oXQ = 0;                              // NP*C bf16 = 8388608
constexpr size_t oXK = (size_t)NP * C * 2;
constexpr size_t oXV = oXK * 2;
constexpr size_t oW1 = oXK * 3;                        // w1 logits: RTOT*16 bf16 = 16MB
constexpr size_t oP1 = oW1 + (size_t)RTOT * 16 * 2;    // bn1 stats: 8 floats
constexpr size_t oP2 = oP1 + 8 * 4;                    // bn2 stats: 256 floats
constexpr size_t oP3 = oP2 + 256 * 4;                  // bn3 stats: 32 floats
constexpr size_t PART_BYTES = 8*4 + 256*4 + 32*4;
constexpr size_t WS_NEED = oP3 + 32 * 4;               // ~41.94 MB

DEV float bu2f(u16 v){ return __uint_as_float(((unsigned)v) << 16); }
DEV u16 f2bu(float f){
  unsigned u = __float_as_uint(f);
  return (u16)((u + 0x7fffu + ((u >> 16) & 1u)) >> 16);   // RNE
}
DEV unsigned pk2(float a, float b){ return (unsigned)f2bu(a) | ((unsigned)f2bu(b) << 16); }
DEV void b2x2(unsigned v, float& lo, float& hi){
  lo = __uint_as_float(v << 16);
  hi = __uint_as_float(v & 0xffff0000u);
}
DEV int clampg(int g){ return g < 0 ? 0 : (g > NP-1 ? NP-1 : g); }

// ---------------- diagnostics ----------------
__global__ __launch_bounds__(256) void k_sig(float* __restrict__ out, float val){
  int i = blockIdx.x * 256 + threadIdx.x;
  if (i < NP*C) out[i] = val;
}

// ---------------- QKV GEMM (fp32, W staged in LDS, 4 rows x 8 cols/thread)
__global__ __launch_bounds__(256) void k_qkv(const float* __restrict__ x,
                                             const float* __restrict__ Wq,
                                             const float* __restrict__ Wk,
                                             const float* __restrict__ Wv,
                                             const float* __restrict__ bq,
                                             const float* __restrict__ bk,
                                             const float* __restrict__ bv,
                                             u16* __restrict__ outw){
  __shared__ __align__(16) float Wl[128*128];   // 64 KB
  const int t = threadIdx.x;
  const int mat = blockIdx.y;
  const float* W    = (mat==0) ? Wq : ((mat==1) ? Wk : Wv);
  const float* bias = (mat==0) ? bq : ((mat==1) ? bk : bv);
  u16* outp = outw + (size_t)mat * NP * C;

  {
    const float4* Ws4 = (const float4*)W;
    float4* Wl4 = (float4*)Wl;
    #pragma unroll
    for (int i = 0; i < 16; ++i) Wl4[t + i*256] = Ws4[t + i*256];
  }
  __syncthreads();

  const int tr = t >> 4, cg = t & 15;
  const int row0 = blockIdx.x * 64 + tr * 4;
  float acc[4][8];
  #pragma unroll
  for (int j = 0; j < 8; ++j){
    float bj = bias[cg*8 + j];
    #pragma unroll
    for (int rr = 0; rr < 4; ++rr) acc[rr][j] = bj;
  }
  const float4* Wl4 = (const float4*)Wl;
  for (int k0 = 0; k0 < 128; k0 += 4){
    float4 xa[4];
    #pragma unroll
    for (int rr = 0; rr < 4; ++rr)
      xa[rr] = *(const float4*)(x + (size_t)(row0+rr)*C + k0);
    #pragma unroll
    for (int u = 0; u < 4; ++u){
      float4 w0 = Wl4[(k0+u)*32 + cg*2];
      float4 w1 = Wl4[(k0+u)*32 + cg*2 + 1];
      #pragma unroll
      for (int rr = 0; rr < 4; ++rr){
        float a = (&xa[rr].x)[u];
        acc[rr][0] = fmaf(a, w0.x, acc[rr][0]);
        acc[rr][1] = fmaf(a, w0.y, acc[rr][1]);
        acc[rr][2] = fmaf(a, w0.z, acc[rr][2]);
        acc[rr][3] = fmaf(a, w0.w, acc[rr][3]);
        acc[rr][4] = fmaf(a, w1.x, acc[rr][4]);
        acc[rr][5] = fmaf(a, w1.y, acc[rr][5]);
        acc[rr][6] = fmaf(a, w1.z, acc[rr][6]);
        acc[rr][7] = fmaf(a, w1.w, acc[rr][7]);
      }
    }
  }
  #pragma unroll
  for (int rr = 0; rr < 4; ++rr){
    uint4 pkd;
    #pragma unroll
    for (int q2 = 0; q2 < 4; ++q2)
      (&pkd.x)[q2] = pk2(acc[rr][q2*2], acc[rr][q2*2+1]);
    *(uint4*)(outp + (size_t)(row0+rr)*C + cg*8) = pkd;
  }
}

// ---------------- bn1 stats: t1 = (p[g]-p[n]) @ pW1 + pb1, 3 channels ----
__global__ __launch_bounds__(256) void k_bn1(const float* __restrict__ p,
                                             const int* __restrict__ idx,
                                             const float* __restrict__ pW1,
                                             const float* __restrict__ pb1,
                                             float* __restrict__ part1){
  const int t = threadIdx.x;
  float w[9], b3[3];
  #pragma unroll
  for (int i = 0; i < 9; ++i) w[i] = pW1[i];
  #pragma unroll
  for (int i = 0; i < 3; ++i) b3[i] = pb1[i];
  float s[3] = {0,0,0}, q[3] = {0,0,0};
  const int base = blockIdx.x * 1024 + t;
  #pragma unroll
  for (int i = 0; i < 4; ++i){
    int r = base + i*256;
    int g = clampg(idx[r]);
    int n = r >> 4;
    float d0 = p[3*g]   - p[3*n];
    float d1 = p[3*g+1] - p[3*n+1];
    float d2 = p[3*g+2] - p[3*n+2];
    #pragma unroll
    for (int k = 0; k < 3; ++k){
      float tv = d0*w[k] + d1*w[3+k] + d2*w[6+k] + b3[k];
      s[k] += tv; q[k] = fmaf(tv, tv, q[k]);
    }
  }
  #pragma unroll
  for (int k = 0; k < 3; ++k){
    #pragma unroll
    for (int m = 1; m < 64; m <<= 1){
      s[k] += __shfl_xor(s[k], m);
      q[k] += __shfl_xor(q[k], m);
    }
  }
  if ((t & 63) == 0){
    #pragma unroll
    for (int k = 0; k < 3; ++k){
      atomicAdd(&part1[k],   s[k]);
      atomicAdd(&part1[4+k], q[k]);
    }
  }
}

// ---------------- bn2 stats over w0 = xk[g] - xq[n] + pr, 128 channels --
__global__ __launch_bounds__(256) void k_bn2(const float* __restrict__ p,
                                             const int* __restrict__ idx,
                                             const float* __restrict__ pW1,
                                             const float* __restrict__ pb1,
                                             const float* __restrict__ pg1,
                                             const float* __restrict__ pbe1,
                                             const float* __restrict__ pW2,
                                             const float* __restrict__ pb2,
                                             const u16* __restrict__ xq,
                                             const u16* __restrict__ xk,
                                             const float* __restrict__ part1,
                                             float* __restrict__ part2){
  __shared__ float sq0[64], sq1[64], sq2[64];
  __shared__ int   sgi[64];
  __shared__ __align__(16) float4 pW2t[128];
  __shared__ float bn1s[8];
  __shared__ float redS[256], redQ[256];
  const int t = threadIdx.x;
  if (t < 3){
    float sv = part1[t], sq = part1[4+t];
    float mu = sv * INV_R, var = sq * INV_R - mu*mu;
    float rs = rsqrtf(var + EPS);
    float sc = rs * pg1[t];
    bn1s[t]   = sc;
    bn1s[4+t] = pb1[t] * sc + pbe1[t] - mu * sc;
  }
  if (t < 128)
    pW2t[t] = make_float4(pW2[t], pW2[128+t], pW2[256+t], pb2[t]);
  __syncthreads();
  const int c = t & 127, half = t >> 7;
  const float4 pw = pW2t[c];
  float w9[9];
  if (t < 64){
    #pragma unroll
    for (int i = 0; i < 9; ++i) w9[i] = pW1[i];
  }
  float s = 0.f, s2 = 0.f;
  const int rowbase = blockIdx.x * 256;
  for (int bt = 0; bt < 4; ++bt){
    const int b0 = rowbase + bt*64;
    if (t < 64){
      int r = b0 + t, n = r >> 4;
      int g = clampg(idx[r]);
      float d0 = p[3*g]   - p[3*n];
      float d1 = p[3*g+1] - p[3*n+1];
      float d2 = p[3*g+2] - p[3*n+2];
      sq0[t] = fmaxf((d0*w9[0] + d1*w9[3] + d2*w9[6]) * bn1s[0] + bn1s[4], 0.f);
      sq1[t] = fmaxf((d0*w9[1] + d1*w9[4] + d2*w9[7]) * bn1s[1] + bn1s[5], 0.f);
      sq2[t] = fmaxf((d0*w9[2] + d1*w9[5] + d2*w9[8]) * bn1s[2] + bn1s[6], 0.f);
      sgi[t] = g;
    }
    __syncthreads();
    for (int rr = half; rr < 64; rr += 2){
      int g = sgi[rr];
      int n = (b0 + rr) >> 4;
      float xkf = bu2f(xk[(size_t)g*C + c]);
      float xqf = bu2f(xq[(size_t)n*C + c]);
      float w0 = xkf - xqf + (sq0[rr]*pw.x + sq1[rr]*pw.y + sq2[rr]*pw.z + pw.w);
      s += w0; s2 = fmaf(w0, w0, s2);
    }
    __syncthreads();
  }
  redS[t] = s; redQ[t] = s2;
  __syncthreads();
  if (t < 128){
    atomicAdd(&part2[t],     redS[t] + redS[128+t]);
    atomicAdd(&part2[128+t], redQ[t] + redQ[128+t]);
  }
}

// ---------------- w1 = relu(bn2(w0)) @ wW1 + wb1 ; store bf16 + bn3 stats
__global__ __launch_bounds__(256) void k_w1(const float* __restrict__ p,
                                            const int* __restrict__ idx,
                                            const float* __restrict__ pW1,
                                            const float* __restrict__ pb1,
                                            const float* __restrict__ pg1,
                                            const float* __restrict__ pbe1,
                                            const float* __restrict__ pW2,
                                            const float* __restrict__ pb2,
                                            const float* __restrict__ wg1,
                                            const float* __restrict__ wbe1,
                                            const float* __restrict__ wW1,
                                            const float* __restrict__ wb1,
                                            const u16* __restrict__ xq,
                                            const u16* __restrict__ xk,
                                            u16* __restrict__ w1out,
                                            const float* __restrict__ part1,
                                            const float* __restrict__ part2,
                                            float* __restrict__ part3){
  __shared__ __align__(16) float4 pW2t[128];
  __shared__ float2 ss2[128];
  __shared__ float bn1s[8];
  __shared__ __align__(16) float wW1f[2048];
  __shared__ float wb1f[16];
  __shared__ float pW1f[9];
  const int t = threadIdx.x;
  if (t < 3){
    float sv = part1[t], sq = part1[4+t];
    float mu = sv * INV_R, var = sq * INV_R - mu*mu;
    float rs = rsqrtf(var + EPS);
    float sc = rs * pg1[t];
    bn1s[t]   = sc;
    bn1s[4+t] = pb1[t] * sc + pbe1[t] - mu * sc;
  }
  if (t < 9)  pW1f[t] = pW1[t];
  if (t < 16) wb1f[t] = wb1[t];
  if (t < 128){
    pW2t[t] = make_float4(pW2[t], pW2[128+t], pW2[256+t], pb2[t]);
    float sv = part2[t], sq = part2[128+t];
    float mu = sv * INV_R, var = sq * INV_R - mu*mu;
    float rs = rsqrtf(var + EPS);
    float sc = rs * wg1[t];
    ss2[t] = make_float2(sc, wbe1[t] - mu * sc);
  }
  #pragma unroll
  for (int i = 0; i < 8; ++i) wW1f[t + i*256] = wW1[t + i*256];
  __syncthreads();

  const int r = blockIdx.x * 256 + t;       // 2048 blocks -> 524288 rows
  const int n = r >> 4;
  const int g = clampg(idx[r]);
  float q0, q1, q2;
  {
    float d0 = p[3*g]   - p[3*n];
    float d1 = p[3*g+1] - p[3*n+1];
    float d2 = p[3*g+2] - p[3*n+2];
    q0 = fmaxf((d0*pW1f[0] + d1*pW1f[3] + d2*pW1f[6]) * bn1s[0] + bn1s[4], 0.f);
    q1 = fmaxf((d0*pW1f[1] + d1*pW1f[4] + d2*pW1f[7]) * bn1s[1] + bn1s[5], 0.f);
    q2 = fmaxf((d0*pW1f[2] + d1*pW1f[5] + d2*pW1f[8]) * bn1s[2] + bn1s[6], 0.f);
  }
  float acc[16];
  #pragma unroll
  for (int o = 0; o < 16; ++o) acc[o] = wb1f[o];
  const u16* xkp = xk + (size_t)g * C;
  const u16* xqp = xq + (size_t)n * C;
  for (int c0 = 0; c0 < 128; c0 += 8){
    uint4 A = *(const uint4*)(xkp + c0);
    uint4 Q = *(const uint4*)(xqp + c0);
    #pragma unroll
    for (int uu = 0; uu < 4; ++uu){
      float xl, xh, ql, qh;
      b2x2((&A.x)[uu], xl, xh);
      b2x2((&Q.x)[uu], ql, qh);
      #pragma unroll
      for (int pe = 0; pe < 2; ++pe){
        int c = c0 + uu*2 + pe;
        float xkf = pe ? xh : xl;
        float xqf = pe ? qh : ql;
        float4 pw = pW2t[c];
        float2 sc = ss2[c];
        float pr = q0*pw.x + q1*pw.y + q2*pw.z + pw.w;
        float h = fmaxf(fmaf(xkf - xqf + pr, sc.x, sc.y), 0.f);
        const float4* wr = (const float4*)&wW1f[c*16];
        #pragma unroll
        for (int o4 = 0; o4 < 4; ++o4){
          float4 wv = wr[o4];
          acc[o4*4]   = fmaf(h, wv.x, acc[o4*4]);
          acc[o4*4+1] = fmaf(h, wv.y, acc[o4*4+1]);
          acc[o4*4+2] = fmaf(h, wv.z, acc[o4*4+2]);
          acc[o4*4+3] = fmaf(h, wv.w, acc[o4*4+3]);
        }
      }
    }
  }
  {
    uint4 v0, v1;
    #pragma unroll
    for (int q2i = 0; q2i < 4; ++q2i){
      (&v0.x)[q2i] = pk2(acc[q2i*2],   acc[q2i*2+1]);
      (&v1.x)[q2i] = pk2(acc[8+q2i*2], acc[8+q2i*2+1]);
    }
    uint4* dst = (uint4*)(w1out + (size_t)r * 16);
    dst[0] = v0; dst[1] = v1;
  }
  const int lane = t & 63;
  #pragma unroll
  for (int o = 0; o < 16; ++o){
    float v  = acc[o];
    float v2 = acc[o] * acc[o];
    #pragma unroll
    for (int m = 1; m < 64; m <<= 1){
      v  += __shfl_xor(v,  m);
      v2 += __shfl_xor(v2, m);
    }
    if (lane == 0){ atomicAdd(&part3[o], v); atomicAdd(&part3[16+o], v2); }
  }
}

// ---------------- final: bn3 -> relu -> wW2 -> softmax(j) -> aggregate --
__global__ __launch_bounds__(256) void k_out(const float* __restrict__ p,
                                             const int* __restrict__ idx,
                                             const float* __restrict__ pW1,
                                             const float* __restrict__ pb1,
                                             const float* __restrict__ pg1,
                                             const float* __restrict__ pbe1,
                                             const float* __restrict__ pW2,
                                             const float* __restrict__ pb2,
                                             const float* __restrict__ wg2,
                                             const float* __restrict__ wbe2,
                                             const float* __restrict__ wW2,
                                             const float* __restrict__ wb2,
                                             const u16* __restrict__ xv,
                                             const u16* __restrict__ w1ws,
                                             const float* __restrict__ part1,
                                             const float* __restrict__ part3,
                                             float* __restrict__ out){
  __shared__ __align__(16) float4 pW2t[128];
  __shared__ float pW1f[9];
  __shared__ float bn1s[8];
  __shared__ float sc3[16], sh3[16], wb2f[16];
  __shared__ float wW2f[256];
  __shared__ float s_w2[16*16*16];
  __shared__ float s_q0[256], s_q1[256], s_q2[256];
  __shared__ int   s_g[256];
  const int t = threadIdx.x;
  if (t < 3){
    float sv = part1[t], sq = part1[4+t];
    float mu = sv * INV_R, var = sq * INV_R - mu*mu;
    float rs = rsqrtf(var + EPS);
    float sc = rs * pg1[t];
    bn1s[t]   = sc;
    bn1s[4+t] = pb1[t] * sc + pbe1[t] - mu * sc;
  }
  if (t < 9) pW1f[t] = pW1[t];
  if (t < 16){
    float sv = part3[t], sq = part3[16+t];
    float mu = sv * INV_R, var = sq * INV_R - mu*mu;
    float rs = rsqrtf(var + EPS);
    float sc = rs * wg2[t];
    sc3[t] = sc;
    sh3[t] = wbe2[t] - mu * sc;
    wb2f[t] = wb2[t];
  }
  if (t < 128)
    pW2t[t] = make_float4(pW2[t], pW2[128+t], pW2[256+t], pb2[t]);
  wW2f[t] = wW2[t];
  __syncthreads();

  const int pt = t >> 4;
  const int jj = t & 15;
  const int n0 = blockIdx.x * 16;
  {
    const int n = n0 + pt;
    const int r = n * NS + jj;
    const int g = clampg(idx[r]);
    float d0 = p[3*g]   - p[3*n];
    float d1 = p[3*g+1] - p[3*n+1];
    float d2 = p[3*g+2] - p[3*n+2];
    s_q0[t] = fmaxf((d0*pW1f[0] + d1*pW1f[3] + d2*pW1f[6]) * bn1s[0] + bn1s[4], 0.f);
    s_q1[t] = fmaxf((d0*pW1f[1] + d1*pW1f[4] + d2*pW1f[7]) * bn1s[1] + bn1s[5], 0.f);
    s_q2[t] = fmaxf((d0*pW1f[2] + d1*pW1f[5] + d2*pW1f[8]) * bn1s[2] + bn1s[6], 0.f);
    s_g[t]  = g;
    const uint4* wp = (const uint4*)(w1ws + (size_t)r * 16);
    uint4 Wa = wp[0], Wb = wp[1];
    float h2[16];
    #pragma unroll
    for (int o2 = 0; o2 < 4; ++o2){
      float lo, hi;
      b2x2((&Wa.x)[o2], lo, hi);
      h2[o2*2]     = fmaxf(lo * sc3[o2*2]     + sh3[o2*2],     0.f);
      h2[o2*2+1]   = fmaxf(hi * sc3[o2*2+1]   + sh3[o2*2+1],   0.f);
      b2x2((&Wb.x)[o2], lo, hi);
      h2[8+o2*2]   = fmaxf(lo * sc3[8+o2*2]   + sh3[8+o2*2],   0.f);
      h2[8+o2*2+1] = fmaxf(hi * sc3[8+o2*2+1] + sh3[8+o2*2+1], 0.f);
    }
    float w2[16];
    #pragma unroll
    for (int o = 0; o < 16; ++o) w2[o] = wb2f[o];
    #pragma unroll
    for (int o2 = 0; o2 < 16; ++o2){
      float h = h2[o2];
      const float* wr = &wW2f[o2*16];
      #pragma unroll
      for (int o = 0; o < 16; ++o) w2[o] = fmaf(h, wr[o], w2[o]);
    }
    float* dst = &s_w2[(pt*16 + jj)*16];
    #pragma unroll
    for (int o = 0; o < 16; ++o) dst[o] = w2[o];
  }
  __syncthreads();
  const int cs = t & 15;
  {
    float mx = -1e30f;
    #pragma unroll
    for (int j2 = 0; j2 < 16; ++j2) mx = fmaxf(mx, s_w2[(pt*16+j2)*16 + cs]);
    float e[16]; float sum = 0.f;
    #pragma unroll
    for (int j2 = 0; j2 < 16; ++j2){
      e[j2] = __expf(s_w2[(pt*16+j2)*16 + cs] - mx);
      sum += e[j2];
    }
    float inv = 1.0f / sum;
    #pragma unroll
    for (int j2 = 0; j2 < 16; ++j2) s_w2[(pt*16+j2)*16 + cs] = e[j2] * inv;
  }
  float4 pwv[8];
  #pragma unroll
  for (int s8 = 0; s8 < 8; ++s8) pwv[s8] = pW2t[s8*16 + cs];
  float acc[8];
  #pragma unroll
  for (int s8 = 0; s8 < 8; ++s8) acc[s8] = 0.f;
  const int n = n0 + pt;
  #pragma unroll
  for (int j2 = 0; j2 < 16; ++j2){
    float pj = s_w2[(pt*16+j2)*16 + cs];
    int   g  = s_g[pt*16 + j2];
    float qa = s_q0[pt*16 + j2], qb = s_q1[pt*16 + j2], qc = s_q2[pt*16 + j2];
    const u16* xr = xv + (size_t)g * C;
    #pragma unroll
    for (int s8 = 0; s8 < 8; ++s8){
      float pr = qa*pwv[s8].x + qb*pwv[s8].y + qc*pwv[s8].z + pwv[s8].w;
      float xvf = bu2f(xr[s8*16 + cs]);
      acc[s8] = fmaf(xvf + pr, pj, acc[s8]);
    }
  }
  #pragma unroll
  for (int s8 = 0; s8 < 8; ++s8)
    out[(size_t)n*C + s8*16 + cs] = acc[s8];
}

extern "C" void kernel_launch(void* const* d_in, const int* in_sizes, int n_in,
                              void* d_out, int out_size, void* d_ws, size_t ws_size,
                              hipStream_t stream) {
  // ---- layout guard: absmax ~10000 => input layout mismatch ----
  bool ok = (n_in == 23) && (out_size == NP*C) &&
            in_sizes[0] == NP*3 && in_sizes[1] == NP*C &&
            in_sizes[2] == C*C  && in_sizes[8] == 9 &&
            in_sizes[12] == 3*C && in_sizes[16] == C*(C/8) &&
            in_sizes[20] == (C/8)*(C/8) && in_sizes[22] == RTOT;
  if (!ok){
    k_sig<<<(NP*C+255)/256, 256, 0, stream>>>((float*)d_out, 10000.0f);
    return;
  }
  if (ws_size < WS_NEED){   // absmax ~20000 => workspace too small
    k_sig<<<(NP*C+255)/256, 256, 0, stream>>>((float*)d_out, 20000.0f);
    return;
  }
  const float* p    = (const float*)d_in[0];
  const float* x    = (const float*)d_in[1];
  const float* Wq   = (const float*)d_in[2];
  const float* bq   = (const float*)d_in[3];
  const float* Wk   = (const float*)d_in[4];
  const float* bk   = (const float*)d_in[5];
  const float* Wv   = (const float*)d_in[6];
  const float* bv   = (const float*)d_in[7];
  const float* pW1  = (const float*)d_in[8];
  const float* pb1  = (const float*)d_in[9];
  const float* pg1  = (const float*)d_in[10];
  const float* pbe1 = (const float*)d_in[11];
  const float* pW2  = (const float*)d_in[12];
  const float* pb2  = (const float*)d_in[13];
  const float* wg1  = (const float*)d_in[14];
  const float* wbe1 = (const float*)d_in[15];
  const float* wW1  = (const float*)d_in[16];
  const float* wb1  = (const float*)d_in[17];
  const float* wg2  = (const float*)d_in[18];
  const float* wbe2 = (const float*)d_in[19];
  const float* wW2  = (const float*)d_in[20];
  const float* wb2  = (const float*)d_in[21];
  const int* idx    = (const int*)d_in[22];

  char* ws = (char*)d_ws;
  u16* xqkv  = (u16*)(ws + oXQ);
  u16* w1ws  = (u16*)(ws + oW1);
  float* p1  = (float*)(ws + oP1);
  float* p2  = (float*)(ws + oP2);
  float* p3  = (float*)(ws + oP3);
  u16* xq = xqkv;
  u16* xk = xqkv + (size_t)NP * C;
  u16* xv = xqkv + (size_t)2 * NP * C;

  hipMemsetAsync(ws + oP1, 0, PART_BYTES, stream);
  k_qkv<<<dim3(512, 3), 256, 0, stream>>>(x, Wq, Wk, Wv, bq, bk, bv, xqkv);
  k_bn1<<<512,  256, 0, stream>>>(p, idx, pW1, pb1, p1);
  k_bn2<<<2048, 256, 0, stream>>>(p, idx, pW1, pb1, pg1, pbe1, pW2, pb2,
                                  xq, xk, p1, p2);
  k_w1 <<<2048, 256, 0, stream>>>(p, idx, pW1, pb1, pg1, pbe1, pW2, pb2,
                                  wg1, wbe1, wW1, wb1, xq, xk, w1ws, p1, p2, p3);
  k_out<<<2048, 256, 0, stream>>>(p, idx, pW1, pb1, pg1, pbe1, pW2, pb2,
                                  wg2, wbe2, wW2, wb2, xv, w1ws, p1, p3,
                                  (float*)d_out);
}

// Round 4
// 694.796 us; speedup vs baseline: 3.3773x; 3.3773x over previous
//
#include <hip/hip_runtime.h>

typedef unsigned short u16;
#define DEV __device__ __forceinline__

constexpr int NP = 32768;
constexpr int C  = 128;
constexpr int NS = 16;
constexpr int RTOT = NP * NS;              // 524288 rows of [N,NS]
constexpr float EPS = 1e-5f;
constexpr float INV_R = 1.0f / (float)RTOT;

// ---- workspace layout (bytes) ----
// Proven (round 1 ran): ws_size >= 42117120.
constexpr size_t oXQ = 0;                              // xq/xk/xv bf16: 3*8MB
constexpr size_t oXK = (size_t)NP * C * 2;             // 8388608
constexpr size_t oXV = oXK * 2;
constexpr size_t oW1 = oXK * 3;                        // w1 logits bf16: 16MB (25165824)
// partials1/2 alias INTO the w1out region (dead before k_w1 overwrites it):
constexpr size_t oPA = oW1;                            // partials1 [512][8] f32 = 16KB
constexpr size_t oPB = oW1 + 16384;                    // partials2 [512][256] f32 = 512KB
// stats + partials3 live AFTER w1out (must survive k_w1):
constexpr size_t oST = oW1 + (size_t)RTOT * 16 * 2;    // 41943040
constexpr size_t oS1 = oST;                            // stats1[8]
constexpr size_t oS2 = oST + 8 * 4;                    // stats2[256]
constexpr size_t oS3 = oS2 + 256 * 4;                  // stats3[32]
constexpr size_t oPC = oS3 + 32 * 4;                   // partials3 [256][32] = 32KB
constexpr size_t WS_NEED = oPC + 256 * 32 * 4;         // 41976992 < 42117120 proven

DEV float bu2f(u16 v){ return __uint_as_float(((unsigned)v) << 16); }
DEV u16 f2bu(float f){
  unsigned u = __float_as_uint(f);
  return (u16)((u + 0x7fffu + ((u >> 16) & 1u)) >> 16);   // RNE
}
DEV unsigned pk2(float a, float b){ return (unsigned)f2bu(a) | ((unsigned)f2bu(b) << 16); }
DEV void b2x2(unsigned v, float& lo, float& hi){
  lo = __uint_as_float(v << 16);
  hi = __uint_as_float(v & 0xffff0000u);
}
DEV int clampg(int g){ return g < 0 ? 0 : (g > NP-1 ? NP-1 : g); }

// ---------------- diagnostics ----------------
__global__ __launch_bounds__(256) void k_sig(float* __restrict__ out, float val){
  int i = blockIdx.x * 256 + threadIdx.x;
  if (i < NP*C) out[i] = val;
}

// ---------------- generic partial-sum finalize: out[w] = sum_i part[i][w]
__global__ __launch_bounds__(256) void k_fin(const float* __restrict__ part,
                                             float* __restrict__ out,
                                             int slots, int width){
  int w = threadIdx.x;
  if (w < width){
    float s = 0.f;
    for (int i = 0; i < slots; ++i) s += part[(size_t)i * width + w];
    out[w] = s;
  }
}

// ---------------- QKV GEMM (fp32, W staged in LDS, 4 rows x 8 cols/thread)
__global__ __launch_bounds__(256) void k_qkv(const float* __restrict__ x,
                                             const float* __restrict__ Wq,
                                             const float* __restrict__ Wk,
                                             const float* __restrict__ Wv,
                                             const float* __restrict__ bq,
                                             const float* __restrict__ bk,
                                             const float* __restrict__ bv,
                                             u16* __restrict__ outw){
  __shared__ __align__(16) float Wl[128*128];   // 64 KB
  const int t = threadIdx.x;
  const int mat = blockIdx.y;
  const float* W    = (mat==0) ? Wq : ((mat==1) ? Wk : Wv);
  const float* bias = (mat==0) ? bq : ((mat==1) ? bk : bv);
  u16* outp = outw + (size_t)mat * NP * C;

  {
    const float4* Ws4 = (const float4*)W;
    float4* Wl4 = (float4*)Wl;
    #pragma unroll
    for (int i = 0; i < 16; ++i) Wl4[t + i*256] = Ws4[t + i*256];
  }
  __syncthreads();

  const int tr = t >> 4, cg = t & 15;
  const int row0 = blockIdx.x * 64 + tr * 4;
  float acc[4][8];
  #pragma unroll
  for (int j = 0; j < 8; ++j){
    float bj = bias[cg*8 + j];
    #pragma unroll
    for (int rr = 0; rr < 4; ++rr) acc[rr][j] = bj;
  }
  const float4* Wl4 = (const float4*)Wl;
  for (int k0 = 0; k0 < 128; k0 += 4){
    float4 xa[4];
    #pragma unroll
    for (int rr = 0; rr < 4; ++rr)
      xa[rr] = *(const float4*)(x + (size_t)(row0+rr)*C + k0);
    #pragma unroll
    for (int u = 0; u < 4; ++u){
      float4 w0 = Wl4[(k0+u)*32 + cg*2];
      float4 w1 = Wl4[(k0+u)*32 + cg*2 + 1];
      #pragma unroll
      for (int rr = 0; rr < 4; ++rr){
        float a = (&xa[rr].x)[u];
        acc[rr][0] = fmaf(a, w0.x, acc[rr][0]);
        acc[rr][1] = fmaf(a, w0.y, acc[rr][1]);
        acc[rr][2] = fmaf(a, w0.z, acc[rr][2]);
        acc[rr][3] = fmaf(a, w0.w, acc[rr][3]);
        acc[rr][4] = fmaf(a, w1.x, acc[rr][4]);
        acc[rr][5] = fmaf(a, w1.y, acc[rr][5]);
        acc[rr][6] = fmaf(a, w1.z, acc[rr][6]);
        acc[rr][7] = fmaf(a, w1.w, acc[rr][7]);
      }
    }
  }
  #pragma unroll
  for (int rr = 0; rr < 4; ++rr){
    uint4 pkd;
    #pragma unroll
    for (int q2 = 0; q2 < 4; ++q2)
      (&pkd.x)[q2] = pk2(acc[rr][q2*2], acc[rr][q2*2+1]);
    *(uint4*)(outp + (size_t)(row0+rr)*C + cg*8) = pkd;
  }
}

// ---------------- bn1 stats -> per-block partials (no atomics) ----------
__global__ __launch_bounds__(256) void k_bn1(const float* __restrict__ p,
                                             const int* __restrict__ idx,
                                             const float* __restrict__ pW1,
                                             const float* __restrict__ pb1,
                                             float* __restrict__ partials1){
  __shared__ float wred[4][8];
  const int t = threadIdx.x;
  float w[9], b3[3];
  #pragma unroll
  for (int i = 0; i < 9; ++i) w[i] = pW1[i];
  #pragma unroll
  for (int i = 0; i < 3; ++i) b3[i] = pb1[i];
  float s[3] = {0,0,0}, q[3] = {0,0,0};
  const int base = blockIdx.x * 1024 + t;
  #pragma unroll
  for (int i = 0; i < 4; ++i){
    int r = base + i*256;
    int g = clampg(idx[r]);
    int n = r >> 4;
    float d0 = p[3*g]   - p[3*n];
    float d1 = p[3*g+1] - p[3*n+1];
    float d2 = p[3*g+2] - p[3*n+2];
    #pragma unroll
    for (int k = 0; k < 3; ++k){
      float tv = d0*w[k] + d1*w[3+k] + d2*w[6+k] + b3[k];
      s[k] += tv; q[k] = fmaf(tv, tv, q[k]);
    }
  }
  #pragma unroll
  for (int k = 0; k < 3; ++k){
    #pragma unroll
    for (int m = 1; m < 64; m <<= 1){
      s[k] += __shfl_xor(s[k], m);
      q[k] += __shfl_xor(q[k], m);
    }
  }
  if ((t & 63) == 0){
    int wv = t >> 6;
    wred[wv][0] = s[0]; wred[wv][1] = s[1]; wred[wv][2] = s[2]; wred[wv][3] = 0.f;
    wred[wv][4] = q[0]; wred[wv][5] = q[1]; wred[wv][6] = q[2]; wred[wv][7] = 0.f;
  }
  __syncthreads();
  if (t < 8)
    partials1[blockIdx.x*8 + t] = wred[0][t] + wred[1][t] + wred[2][t] + wred[3][t];
}

// ---------------- bn2 stats (coalesced gather) -> per-block partials -----
__global__ __launch_bounds__(256) void k_bn2(const float* __restrict__ p,
                                             const int* __restrict__ idx,
                                             const float* __restrict__ pW1,
                                             const float* __restrict__ pb1,
                                             const float* __restrict__ pg1,
                                             const float* __restrict__ pbe1,
                                             const float* __restrict__ pW2,
                                             const float* __restrict__ pb2,
                                             const u16* __restrict__ xq,
                                             const u16* __restrict__ xk,
                                             const float* __restrict__ stats1,
                                             float* __restrict__ partials2){
  __shared__ float sq0[64], sq1[64], sq2[64];
  __shared__ int   sgi[64];
  __shared__ __align__(16) float4 pW2t[128];
  __shared__ float bn1s[8];
  __shared__ float redS[256], redQ[256];
  const int t = threadIdx.x;
  if (t < 3){
    float sv = stats1[t], sq = stats1[4+t];
    float mu = sv * INV_R, var = sq * INV_R - mu*mu;
    float rs = rsqrtf(var + EPS);
    float sc = rs * pg1[t];
    bn1s[t]   = sc;
    bn1s[4+t] = pb1[t] * sc + pbe1[t] - mu * sc;
  }
  if (t < 128)
    pW2t[t] = make_float4(pW2[t], pW2[128+t], pW2[256+t], pb2[t]);
  __syncthreads();
  const int c = t & 127, half = t >> 7;
  const float4 pw = pW2t[c];
  float w9[9];
  if (t < 64){
    #pragma unroll
    for (int i = 0; i < 9; ++i) w9[i] = pW1[i];
  }
  float s = 0.f, s2 = 0.f;
  for (int tile = 0; tile < 16; ++tile){
    const int b0 = (blockIdx.x * 16 + tile) * 64;
    if (t < 64){
      int r = b0 + t, n = r >> 4;
      int g = clampg(idx[r]);
      float d0 = p[3*g]   - p[3*n];
      float d1 = p[3*g+1] - p[3*n+1];
      float d2 = p[3*g+2] - p[3*n+2];
      sq0[t] = fmaxf((d0*w9[0] + d1*w9[3] + d2*w9[6]) * bn1s[0] + bn1s[4], 0.f);
      sq1[t] = fmaxf((d0*w9[1] + d1*w9[4] + d2*w9[7]) * bn1s[1] + bn1s[5], 0.f);
      sq2[t] = fmaxf((d0*w9[2] + d1*w9[5] + d2*w9[8]) * bn1s[2] + bn1s[6], 0.f);
      sgi[t] = g;
    }
    __syncthreads();
    for (int rr = half; rr < 64; rr += 2){
      int g = sgi[rr];
      int n = (b0 + rr) >> 4;
      float xkf = bu2f(xk[(size_t)g*C + c]);
      float xqf = bu2f(xq[(size_t)n*C + c]);
      float w0 = xkf - xqf + (sq0[rr]*pw.x + sq1[rr]*pw.y + sq2[rr]*pw.z + pw.w);
      s += w0; s2 = fmaf(w0, w0, s2);
    }
    __syncthreads();
  }
  redS[t] = s; redQ[t] = s2;
  __syncthreads();
  if (t < 128){
    partials2[(size_t)blockIdx.x*256 + t]       = redS[t] + redS[128+t];
    partials2[(size_t)blockIdx.x*256 + 128 + t] = redQ[t] + redQ[128+t];
  }
}

// ---------------- w1 = relu(bn2(w0)) @ wW1 + wb1 ; cooperative tiles ----
// Phase A: 64 lanes compute pr-q per row. Phase B: coalesced gather ->
// h[64][132] in LDS. Phase C: (row, o-quad) matvec 128->16. No atomics.
__global__ __launch_bounds__(256) void k_w1(const float* __restrict__ p,
                                            const int* __restrict__ idx,
                                            const float* __restrict__ pW1,
                                            const float* __restrict__ pb1,
                                            const float* __restrict__ pg1,
                                            const float* __restrict__ pbe1,
                                            const float* __restrict__ pW2,
                                            const float* __restrict__ pb2,
                                            const float* __restrict__ wg1,
                                            const float* __restrict__ wbe1,
                                            const float* __restrict__ wW1,
                                            const float* __restrict__ wb1,
                                            const u16* __restrict__ xq,
                                            const u16* __restrict__ xk,
                                            u16* __restrict__ w1out,
                                            const float* __restrict__ stats1,
                                            const float* __restrict__ stats2){
  __shared__ __align__(16) float4 pW2t[128];
  __shared__ float2 ss2[128];
  __shared__ float bn1s[8];
  __shared__ __align__(16) float wW1f[2048];
  __shared__ float wb1f[16];
  __shared__ float pW1f[9];
  __shared__ float sq0[64], sq1[64], sq2[64];
  __shared__ int   sgi[64];
  __shared__ __align__(16) float hs[64*132];   // 33.8 KB, pad 132
  const int t = threadIdx.x;
  if (t < 3){
    float sv = stats1[t], sq = stats1[4+t];
    float mu = sv * INV_R, var = sq * INV_R - mu*mu;
    float rs = rsqrtf(var + EPS);
    float sc = rs * pg1[t];
    bn1s[t]   = sc;
    bn1s[4+t] = pb1[t] * sc + pbe1[t] - mu * sc;
  }
  if (t < 9)  pW1f[t] = pW1[t];
  if (t < 16) wb1f[t] = wb1[t];
  if (t < 128){
    pW2t[t] = make_float4(pW2[t], pW2[128+t], pW2[256+t], pb2[t]);
    float sv = stats2[t], sq = stats2[128+t];
    float mu = sv * INV_R, var = sq * INV_R - mu*mu;
    float rs = rsqrtf(var + EPS);
    float sc = rs * wg1[t];
    ss2[t] = make_float2(sc, wbe1[t] - mu * sc);
  }
  #pragma unroll
  for (int i = 0; i < 8; ++i) wW1f[t + i*256] = wW1[t + i*256];
  __syncthreads();

  const int c = t & 127, half = t >> 7;
  const float4 pwc = pW2t[c];
  const float2 scc = ss2[c];
  const int row = t >> 2, o4 = (t & 3) * 4;
  const float b0o = wb1f[o4], b1o = wb1f[o4+1], b2o = wb1f[o4+2], b3o = wb1f[o4+3];

  for (int tile = 0; tile < 4; ++tile){
    const int rb = (blockIdx.x * 4 + tile) * 64;
    // phase A
    if (t < 64){
      int r = rb + t, n = r >> 4;
      int g = clampg(idx[r]);
      float d0 = p[3*g]   - p[3*n];
      float d1 = p[3*g+1] - p[3*n+1];
      float d2 = p[3*g+2] - p[3*n+2];
      sq0[t] = fmaxf((d0*pW1f[0] + d1*pW1f[3] + d2*pW1f[6]) * bn1s[0] + bn1s[4], 0.f);
      sq1[t] = fmaxf((d0*pW1f[1] + d1*pW1f[4] + d2*pW1f[7]) * bn1s[1] + bn1s[5], 0.f);
      sq2[t] = fmaxf((d0*pW1f[2] + d1*pW1f[5] + d2*pW1f[8]) * bn1s[2] + bn1s[6], 0.f);
      sgi[t] = g;
    }
    __syncthreads();
    // phase B: coalesced gather -> h in LDS
    #pragma unroll 4
    for (int rr = half; rr < 64; rr += 2){
      int g = sgi[rr];
      int n = (rb + rr) >> 4;
      float xkf = bu2f(xk[(size_t)g*C + c]);
      float xqf = bu2f(xq[(size_t)n*C + c]);
      float w0 = xkf - xqf + (sq0[rr]*pwc.x + sq1[rr]*pwc.y + sq2[rr]*pwc.z + pwc.w);
      hs[rr*132 + c] = fmaxf(fmaf(w0, scc.x, scc.y), 0.f);
    }
    __syncthreads();
    // phase C: matvec 128 -> 4 outputs per thread
    float a0 = b0o, a1 = b1o, a2 = b2o, a3 = b3o;
    const float* hr = &hs[row*132];
    #pragma unroll 4
    for (int c0 = 0; c0 < 128; c0 += 4){
      float4 hv  = *(const float4*)(hr + c0);
      float4 w0v = *(const float4*)&wW1f[(c0  )*16 + o4];
      float4 w1v = *(const float4*)&wW1f[(c0+1)*16 + o4];
      float4 w2v = *(const float4*)&wW1f[(c0+2)*16 + o4];
      float4 w3v = *(const float4*)&wW1f[(c0+3)*16 + o4];
      a0 = fmaf(hv.x, w0v.x, a0); a1 = fmaf(hv.x, w0v.y, a1);
      a2 = fmaf(hv.x, w0v.z, a2); a3 = fmaf(hv.x, w0v.w, a3);
      a0 = fmaf(hv.y, w1v.x, a0); a1 = fmaf(hv.y, w1v.y, a1);
      a2 = fmaf(hv.y, w1v.z, a2); a3 = fmaf(hv.y, w1v.w, a3);
      a0 = fmaf(hv.z, w2v.x, a0); a1 = fmaf(hv.z, w2v.y, a1);
      a2 = fmaf(hv.z, w2v.z, a2); a3 = fmaf(hv.z, w2v.w, a3);
      a0 = fmaf(hv.w, w3v.x, a0); a1 = fmaf(hv.w, w3v.y, a1);
      a2 = fmaf(hv.w, w3v.z, a2); a3 = fmaf(hv.w, w3v.w, a3);
    }
    uint2 pv;
    pv.x = pk2(a0, a1); pv.y = pk2(a2, a3);
    *(uint2*)(w1out + (size_t)(rb + row) * 16 + o4) = pv;
    __syncthreads();
  }
}

// ---------------- bn3 stats: coalesced pass over w1 logits --------------
__global__ __launch_bounds__(256) void k_bn3(const u16* __restrict__ w1ws,
                                             float* __restrict__ partials3){
  __shared__ float rs[256][8], rq[256][8];
  const int t = threadIdx.x;
  float s[8], q[8];
  #pragma unroll
  for (int k = 0; k < 8; ++k){ s[k] = 0.f; q[k] = 0.f; }
  const uint4* w4 = (const uint4*)w1ws;
  const int base = blockIdx.x * 256 + t;
  #pragma unroll 4
  for (int it = 0; it < 16; ++it){
    uint4 v = w4[base + it * 65536];
    #pragma unroll
    for (int k = 0; k < 4; ++k){
      float lo, hi; b2x2((&v.x)[k], lo, hi);
      s[k*2]   += lo; q[k*2]   = fmaf(lo, lo, q[k*2]);
      s[k*2+1] += hi; q[k*2+1] = fmaf(hi, hi, q[k*2+1]);
    }
  }
  #pragma unroll
  for (int k = 0; k < 8; ++k){ rs[t][k] = s[k]; rq[t][k] = q[k]; }
  __syncthreads();
  // thread t (parity t&1) held channels (t&1)*8 + [0..8)
  if (t < 32){
    int isq = t >> 4, ch = t & 15;
    int par = ch >> 3, k = ch & 7;
    float acc = 0.f;
    if (isq){
      for (int i2 = par; i2 < 256; i2 += 2) acc += rq[i2][k];
    } else {
      for (int i2 = par; i2 < 256; i2 += 2) acc += rs[i2][k];
    }
    partials3[blockIdx.x*32 + isq*16 + ch] = acc;
  }
}

// ---------------- final: bn3 -> relu -> wW2 -> softmax(j) -> aggregate --
__global__ __launch_bounds__(256) void k_out(const float* __restrict__ p,
                                             const int* __restrict__ idx,
                                             const float* __restrict__ pW1,
                                             const float* __restrict__ pb1,
                                             const float* __restrict__ pg1,
                                             const float* __restrict__ pbe1,
                                             const float* __restrict__ pW2,
                                             const float* __restrict__ pb2,
                                             const float* __restrict__ wg2,
                                             const float* __restrict__ wbe2,
                                             const float* __restrict__ wW2,
                                             const float* __restrict__ wb2,
                                             const u16* __restrict__ xv,
                                             const u16* __restrict__ w1ws,
                                             const float* __restrict__ stats1,
                                             const float* __restrict__ stats3,
                                             float* __restrict__ out){
  __shared__ __align__(16) float4 pW2t[128];
  __shared__ float pW1f[9];
  __shared__ float bn1s[8];
  __shared__ float sc3[16], sh3[16], wb2f[16];
  __shared__ float wW2f[256];
  __shared__ float s_w2[16*16*16];
  __shared__ float s_q0[256], s_q1[256], s_q2[256];
  __shared__ int   s_g[256];
  const int t = threadIdx.x;
  if (t < 3){
    float sv = stats1[t], sq = stats1[4+t];
    float mu = sv * INV_R, var = sq * INV_R - mu*mu;
    float rs = rsqrtf(var + EPS);
    float sc = rs * pg1[t];
    bn1s[t]   = sc;
    bn1s[4+t] = pb1[t] * sc + pbe1[t] - mu * sc;
  }
  if (t < 9) pW1f[t] = pW1[t];
  if (t < 16){
    float sv = stats3[t], sq = stats3[16+t];
    float mu = sv * INV_R, var = sq * INV_R - mu*mu;
    float rs = rsqrtf(var + EPS);
    float sc = rs * wg2[t];
    sc3[t] = sc;
    sh3[t] = wbe2[t] - mu * sc;
    wb2f[t] = wb2[t];
  }
  if (t < 128)
    pW2t[t] = make_float4(pW2[t], pW2[128+t], pW2[256+t], pb2[t]);
  wW2f[t] = wW2[t];
  __syncthreads();

  const int pt = t >> 4;
  const int jj = t & 15;
  const int n0 = blockIdx.x * 16;
  {
    const int n = n0 + pt;
    const int r = n * NS + jj;
    const int g = clampg(idx[r]);
    float d0 = p[3*g]   - p[3*n];
    float d1 = p[3*g+1] - p[3*n+1];
    float d2 = p[3*g+2] - p[3*n+2];
    s_q0[t] = fmaxf((d0*pW1f[0] + d1*pW1f[3] + d2*pW1f[6]) * bn1s[0] + bn1s[4], 0.f);
    s_q1[t] = fmaxf((d0*pW1f[1] + d1*pW1f[4] + d2*pW1f[7]) * bn1s[1] + bn1s[5], 0.f);
    s_q2[t] = fmaxf((d0*pW1f[2] + d1*pW1f[5] + d2*pW1f[8]) * bn1s[2] + bn1s[6], 0.f);
    s_g[t]  = g;
    const uint4* wp = (const uint4*)(w1ws + (size_t)r * 16);
    uint4 Wa = wp[0], Wb = wp[1];
    float h2[16];
    #pragma unroll
    for (int o2 = 0; o2 < 4; ++o2){
      float lo, hi;
      b2x2((&Wa.x)[o2], lo, hi);
      h2[o2*2]     = fmaxf(lo * sc3[o2*2]     + sh3[o2*2],     0.f);
      h2[o2*2+1]   = fmaxf(hi * sc3[o2*2+1]   + sh3[o2*2+1],   0.f);
      b2x2((&Wb.x)[o2], lo, hi);
      h2[8+o2*2]   = fmaxf(lo * sc3[8+o2*2]   + sh3[8+o2*2],   0.f);
      h2[8+o2*2+1] = fmaxf(hi * sc3[8+o2*2+1] + sh3[8+o2*2+1], 0.f);
    }
    float w2[16];
    #pragma unroll
    for (int o = 0; o < 16; ++o) w2[o] = wb2f[o];
    #pragma unroll
    for (int o2 = 0; o2 < 16; ++o2){
      float h = h2[o2];
      const float* wr = &wW2f[o2*16];
      #pragma unroll
      for (int o = 0; o < 16; ++o) w2[o] = fmaf(h, wr[o], w2[o]);
    }
    float* dst = &s_w2[(pt*16 + jj)*16];
    #pragma unroll
    for (int o = 0; o < 16; ++o) dst[o] = w2[o];
  }
  __syncthreads();
  const int cs = t & 15;
  {
    float mx = -1e30f;
    #pragma unroll
    for (int j2 = 0; j2 < 16; ++j2) mx = fmaxf(mx, s_w2[(pt*16+j2)*16 + cs]);
    float e[16]; float sum = 0.f;
    #pragma unroll
    for (int j2 = 0; j2 < 16; ++j2){
      e[j2] = __expf(s_w2[(pt*16+j2)*16 + cs] - mx);
      sum += e[j2];
    }
    float inv = 1.0f / sum;
    #pragma unroll
    for (int j2 = 0; j2 < 16; ++j2) s_w2[(pt*16+j2)*16 + cs] = e[j2] * inv;
  }
  float4 pwv[8];
  #pragma unroll
  for (int s8 = 0; s8 < 8; ++s8) pwv[s8] = pW2t[s8*16 + cs];
  float acc[8];
  #pragma unroll
  for (int s8 = 0; s8 < 8; ++s8) acc[s8] = 0.f;
  const int n = n0 + pt;
  #pragma unroll
  for (int j2 = 0; j2 < 16; ++j2){
    float pj = s_w2[(pt*16+j2)*16 + cs];
    int   g  = s_g[pt*16 + j2];
    float qa = s_q0[pt*16 + j2], qb = s_q1[pt*16 + j2], qc = s_q2[pt*16 + j2];
    const u16* xr = xv + (size_t)g * C;
    #pragma unroll
    for (int s8 = 0; s8 < 8; ++s8){
      float pr = qa*pwv[s8].x + qb*pwv[s8].y + qc*pwv[s8].z + pwv[s8].w;
      float xvf = bu2f(xr[s8*16 + cs]);
      acc[s8] = fmaf(xvf + pr, pj, acc[s8]);
    }
  }
  #pragma unroll
  for (int s8 = 0; s8 < 8; ++s8)
    out[(size_t)n*C + s8*16 + cs] = acc[s8];
}

extern "C" void kernel_launch(void* const* d_in, const int* in_sizes, int n_in,
                              void* d_out, int out_size, void* d_ws, size_t ws_size,
                              hipStream_t stream) {
  bool ok = (n_in == 23) && (out_size == NP*C) &&
            in_sizes[0] == NP*3 && in_sizes[1] == NP*C &&
            in_sizes[2] == C*C  && in_sizes[8] == 9 &&
            in_sizes[12] == 3*C && in_sizes[16] == C*(C/8) &&
            in_sizes[20] == (C/8)*(C/8) && in_sizes[22] == RTOT;
  if (!ok){
    k_sig<<<(NP*C+255)/256, 256, 0, stream>>>((float*)d_out, 10000.0f);
    return;
  }
  if (ws_size < WS_NEED){
    k_sig<<<(NP*C+255)/256, 256, 0, stream>>>((float*)d_out, 20000.0f);
    return;
  }
  const float* p    = (const float*)d_in[0];
  const float* x    = (const float*)d_in[1];
  const float* Wq   = (const float*)d_in[2];
  const float* bq   = (const float*)d_in[3];
  const float* Wk   = (const float*)d_in[4];
  const float* bk   = (const float*)d_in[5];
  const float* Wv   = (const float*)d_in[6];
  const float* bv   = (const float*)d_in[7];
  const float* pW1  = (const float*)d_in[8];
  const float* pb1  = (const float*)d_in[9];
  const float* pg1  = (const float*)d_in[10];
  const float* pbe1 = (const float*)d_in[11];
  const float* pW2  = (const float*)d_in[12];
  const float* pb2  = (const float*)d_in[13];
  const float* wg1  = (const float*)d_in[14];
  const float* wbe1 = (const float*)d_in[15];
  const float* wW1  = (const float*)d_in[16];
  const float* wb1  = (const float*)d_in[17];
  const float* wg2  = (const float*)d_in[18];
  const float* wbe2 = (const float*)d_in[19];
  const float* wW2  = (const float*)d_in[20];
  const float* wb2  = (const float*)d_in[21];
  const int* idx    = (const int*)d_in[22];

  char* ws = (char*)d_ws;
  u16* xq    = (u16*)(ws + oXQ);
  u16* xk    = (u16*)(ws + oXK);
  u16* xv    = (u16*)(ws + oXV);
  u16* w1ws  = (u16*)(ws + oW1);
  float* pa  = (float*)(ws + oPA);
  float* pb  = (float*)(ws + oPB);
  float* pc  = (float*)(ws + oPC);
  float* s1  = (float*)(ws + oS1);
  float* s2  = (float*)(ws + oS2);
  float* s3  = (float*)(ws + oS3);

  k_qkv<<<dim3(512, 3), 256, 0, stream>>>(x, Wq, Wk, Wv, bq, bk, bv, xq);
  k_bn1<<<512, 256, 0, stream>>>(p, idx, pW1, pb1, pa);
  k_fin<<<1, 256, 0, stream>>>(pa, s1, 512, 8);
  k_bn2<<<512, 256, 0, stream>>>(p, idx, pW1, pb1, pg1, pbe1, pW2, pb2,
                                 xq, xk, s1, pb);
  k_fin<<<1, 256, 0, stream>>>(pb, s2, 512, 256);
  k_w1 <<<2048, 256, 0, stream>>>(p, idx, pW1, pb1, pg1, pbe1, pW2, pb2,
                                  wg1, wbe1, wW1, wb1, xq, xk, w1ws, s1, s2);
  k_bn3<<<256, 256, 0, stream>>>(w1ws, pc);
  k_fin<<<1, 256, 0, stream>>>(pc, s3, 256, 32);
  k_out<<<2048, 256, 0, stream>>>(p, idx, pW1, pb1, pg1, pbe1, pW2, pb2,
                                  wg2, wbe2, wW2, wb2, xv, w1ws, s1, s3,
                                  (float*)d_out);
}

// Round 5
// 475.103 us; speedup vs baseline: 4.9390x; 1.4624x over previous
//
#include <hip/hip_runtime.h>

typedef unsigned short u16;
#define DEV __device__ __forceinline__

constexpr int NP = 32768;
constexpr int C  = 128;
constexpr int NS = 16;
constexpr int RTOT = NP * NS;              // 524288 rows of [N,NS]
constexpr float EPS = 1e-5f;
constexpr float INV_R = 1.0f / (float)RTOT;

// ---- workspace layout (bytes) ----
// Proven (round 1 ran): ws_size >= 42117120.
constexpr size_t oXQ = 0;                              // xq/xk/xv bf16: 3*8MB
constexpr size_t oXK = (size_t)NP * C * 2;             // 8388608
constexpr size_t oXV = oXK * 2;
constexpr size_t oW1 = oXK * 3;                        // w1 logits bf16: 16MB
// partials1/2 alias INTO the w1out region (dead before k_w1 overwrites it):
constexpr size_t oPA = oW1;                            // partials1 [512][8] f32
constexpr size_t oPB = oW1 + 16384;                    // partials2 [2048][256] f32 = 2MB
// stats + partials3 live AFTER w1out (must survive k_w1):
constexpr size_t oST = oW1 + (size_t)RTOT * 16 * 2;    // 41943040
constexpr size_t oS1 = oST;                            // stats1[8]
constexpr size_t oS2 = oST + 8 * 4;                    // stats2[256]
constexpr size_t oS3 = oS2 + 256 * 4;                  // stats3[32]
constexpr size_t oPC = oS3 + 32 * 4;                   // partials3 [256][32]
constexpr size_t WS_NEED = oPC + 256 * 32 * 4;         // < 42117120 proven

DEV float bu2f(u16 v){ return __uint_as_float(((unsigned)v) << 16); }
DEV u16 f2bu(float f){
  unsigned u = __float_as_uint(f);
  return (u16)((u + 0x7fffu + ((u >> 16) & 1u)) >> 16);   // RNE
}
DEV unsigned pk2(float a, float b){ return (unsigned)f2bu(a) | ((unsigned)f2bu(b) << 16); }
DEV void b2x2(unsigned v, float& lo, float& hi){
  lo = __uint_as_float(v << 16);
  hi = __uint_as_float(v & 0xffff0000u);
}
DEV int clampg(int g){ return g < 0 ? 0 : (g > NP-1 ? NP-1 : g); }

// ---------------- diagnostics ----------------
__global__ __launch_bounds__(256) void k_sig(float* __restrict__ out, float val){
  int i = blockIdx.x * 256 + threadIdx.x;
  if (i < NP*C) out[i] = val;
}

// ---------------- partial-sum finalize: out[ch] = sum_i part[i][ch] ------
// block handles 64 channels, 4 waves split the slots
__global__ __launch_bounds__(256) void k_fin(const float* __restrict__ part,
                                             float* __restrict__ out,
                                             int slots, int width){
  __shared__ float red[4][64];
  const int l = threadIdx.x & 63, w = threadIdx.x >> 6;
  const int ch = blockIdx.x * 64 + l;
  float s = 0.f;
  if (ch < width)
    for (int i = w; i < slots; i += 4) s += part[(size_t)i * width + ch];
  red[w][l] = s;
  __syncthreads();
  if (threadIdx.x < 64 && ch < width)
    out[ch] = red[0][l] + red[1][l] + red[2][l] + red[3][l];
}

// ---------------- QKV GEMM (fp32, W staged in LDS, 4 rows x 8 cols/thread)
__global__ __launch_bounds__(256) void k_qkv(const float* __restrict__ x,
                                             const float* __restrict__ Wq,
                                             const float* __restrict__ Wk,
                                             const float* __restrict__ Wv,
                                             const float* __restrict__ bq,
                                             const float* __restrict__ bk,
                                             const float* __restrict__ bv,
                                             u16* __restrict__ outw){
  __shared__ __align__(16) float Wl[128*128];   // 64 KB
  const int t = threadIdx.x;
  const int mat = blockIdx.y;
  const float* W    = (mat==0) ? Wq : ((mat==1) ? Wk : Wv);
  const float* bias = (mat==0) ? bq : ((mat==1) ? bk : bv);
  u16* outp = outw + (size_t)mat * NP * C;

  {
    const float4* Ws4 = (const float4*)W;
    float4* Wl4 = (float4*)Wl;
    #pragma unroll
    for (int i = 0; i < 16; ++i) Wl4[t + i*256] = Ws4[t + i*256];
  }
  __syncthreads();

  const int tr = t >> 4, cg = t & 15;
  const int row0 = blockIdx.x * 64 + tr * 4;
  float acc[4][8];
  #pragma unroll
  for (int j = 0; j < 8; ++j){
    float bj = bias[cg*8 + j];
    #pragma unroll
    for (int rr = 0; rr < 4; ++rr) acc[rr][j] = bj;
  }
  const float4* Wl4 = (const float4*)Wl;
  for (int k0 = 0; k0 < 128; k0 += 4){
    float4 xa[4];
    #pragma unroll
    for (int rr = 0; rr < 4; ++rr)
      xa[rr] = *(const float4*)(x + (size_t)(row0+rr)*C + k0);
    #pragma unroll
    for (int u = 0; u < 4; ++u){
      float4 w0 = Wl4[(k0+u)*32 + cg*2];
      float4 w1 = Wl4[(k0+u)*32 + cg*2 + 1];
      #pragma unroll
      for (int rr = 0; rr < 4; ++rr){
        float a = (&xa[rr].x)[u];
        acc[rr][0] = fmaf(a, w0.x, acc[rr][0]);
        acc[rr][1] = fmaf(a, w0.y, acc[rr][1]);
        acc[rr][2] = fmaf(a, w0.z, acc[rr][2]);
        acc[rr][3] = fmaf(a, w0.w, acc[rr][3]);
        acc[rr][4] = fmaf(a, w1.x, acc[rr][4]);
        acc[rr][5] = fmaf(a, w1.y, acc[rr][5]);
        acc[rr][6] = fmaf(a, w1.z, acc[rr][6]);
        acc[rr][7] = fmaf(a, w1.w, acc[rr][7]);
      }
    }
  }
  #pragma unroll
  for (int rr = 0; rr < 4; ++rr){
    uint4 pkd;
    #pragma unroll
    for (int q2 = 0; q2 < 4; ++q2)
      (&pkd.x)[q2] = pk2(acc[rr][q2*2], acc[rr][q2*2+1]);
    *(uint4*)(outp + (size_t)(row0+rr)*C + cg*8) = pkd;
  }
}

// ---------------- bn1 stats -> per-block partials (no atomics) ----------
__global__ __launch_bounds__(256) void k_bn1(const float* __restrict__ p,
                                             const int* __restrict__ idx,
                                             const float* __restrict__ pW1,
                                             const float* __restrict__ pb1,
                                             float* __restrict__ partials1){
  __shared__ float wred[4][8];
  const int t = threadIdx.x;
  float w[9], b3[3];
  #pragma unroll
  for (int i = 0; i < 9; ++i) w[i] = pW1[i];
  #pragma unroll
  for (int i = 0; i < 3; ++i) b3[i] = pb1[i];
  float s[3] = {0,0,0}, q[3] = {0,0,0};
  const int base = blockIdx.x * 1024 + t;
  #pragma unroll
  for (int i = 0; i < 4; ++i){
    int r = base + i*256;
    int g = clampg(idx[r]);
    int n = r >> 4;
    float d0 = p[3*g]   - p[3*n];
    float d1 = p[3*g+1] - p[3*n+1];
    float d2 = p[3*g+2] - p[3*n+2];
    #pragma unroll
    for (int k = 0; k < 3; ++k){
      float tv = d0*w[k] + d1*w[3+k] + d2*w[6+k] + b3[k];
      s[k] += tv; q[k] = fmaf(tv, tv, q[k]);
    }
  }
  #pragma unroll
  for (int k = 0; k < 3; ++k){
    #pragma unroll
    for (int m = 1; m < 64; m <<= 1){
      s[k] += __shfl_xor(s[k], m);
      q[k] += __shfl_xor(q[k], m);
    }
  }
  if ((t & 63) == 0){
    int wv = t >> 6;
    wred[wv][0] = s[0]; wred[wv][1] = s[1]; wred[wv][2] = s[2]; wred[wv][3] = 0.f;
    wred[wv][4] = q[0]; wred[wv][5] = q[1]; wred[wv][6] = q[2]; wred[wv][7] = 0.f;
  }
  __syncthreads();
  if (t < 8)
    partials1[blockIdx.x*8 + t] = wred[0][t] + wred[1][t] + wred[2][t] + wred[3][t];
}

// ---------------- bn2 stats: wave-per-row uint gather, high occupancy ---
__global__ __launch_bounds__(256) void k_bn2(const float* __restrict__ p,
                                             const int* __restrict__ idx,
                                             const float* __restrict__ pW1,
                                             const float* __restrict__ pb1,
                                             const float* __restrict__ pg1,
                                             const float* __restrict__ pbe1,
                                             const float* __restrict__ pW2,
                                             const float* __restrict__ pb2,
                                             const u16* __restrict__ xq,
                                             const u16* __restrict__ xk,
                                             const float* __restrict__ stats1,
                                             float* __restrict__ partials2){
  __shared__ float sq0[64], sq1[64], sq2[64];
  __shared__ int   sgi[64];
  __shared__ __align__(16) float4 pW2t[128];
  __shared__ float bn1s[8];
  __shared__ __align__(16) float redS[4][128], redQ[4][128];
  const int t = threadIdx.x;
  if (t < 3){
    float sv = stats1[t], sq = stats1[4+t];
    float mu = sv * INV_R, var = sq * INV_R - mu*mu;
    float rs = rsqrtf(var + EPS);
    float sc = rs * pg1[t];
    bn1s[t]   = sc;
    bn1s[4+t] = pb1[t] * sc + pbe1[t] - mu * sc;
  }
  if (t < 128)
    pW2t[t] = make_float4(pW2[t], pW2[128+t], pW2[256+t], pb2[t]);
  float w9[9];
  if (t < 64){
    #pragma unroll
    for (int i = 0; i < 9; ++i) w9[i] = pW1[i];
  }
  __syncthreads();
  const int w = t >> 6, l = t & 63;
  const float4 pwA = pW2t[2*l], pwB = pW2t[2*l+1];
  float sA = 0.f, qA = 0.f, sB = 0.f, qB = 0.f;

  for (int tile = 0; tile < 4; ++tile){
    const int b0 = (blockIdx.x * 4 + tile) * 64;
    if (t < 64){
      int r = b0 + t, n = r >> 4;
      int g = clampg(idx[r]);
      float d0 = p[3*g]   - p[3*n];
      float d1 = p[3*g+1] - p[3*n+1];
      float d2 = p[3*g+2] - p[3*n+2];
      sq0[t] = fmaxf((d0*w9[0] + d1*w9[3] + d2*w9[6]) * bn1s[0] + bn1s[4], 0.f);
      sq1[t] = fmaxf((d0*w9[1] + d1*w9[4] + d2*w9[7]) * bn1s[1] + bn1s[5], 0.f);
      sq2[t] = fmaxf((d0*w9[2] + d1*w9[5] + d2*w9[8]) * bn1s[2] + bn1s[6], 0.f);
      sgi[t] = g;
    }
    __syncthreads();
    #pragma unroll
    for (int pt = 0; pt < 4; ++pt){
      const int n = (b0 >> 4) + pt;
      unsigned qx = *(const unsigned*)(xq + (size_t)n*C + 2*l);
      float xqA, xqB; b2x2(qx, xqA, xqB);
      #pragma unroll
      for (int k = 0; k < 4; ++k){
        int rr = pt*16 + w + k*4;
        int g = sgi[rr];
        unsigned kx = *(const unsigned*)(xk + (size_t)g*C + 2*l);
        float xkA, xkB; b2x2(kx, xkA, xkB);
        float prA = sq0[rr]*pwA.x + sq1[rr]*pwA.y + sq2[rr]*pwA.z + pwA.w;
        float prB = sq0[rr]*pwB.x + sq1[rr]*pwB.y + sq2[rr]*pwB.z + pwB.w;
        float w0A = xkA - xqA + prA;
        float w0B = xkB - xqB + prB;
        sA += w0A; qA = fmaf(w0A, w0A, qA);
        sB += w0B; qB = fmaf(w0B, w0B, qB);
      }
    }
    __syncthreads();
  }
  *(float2*)&redS[w][2*l] = make_float2(sA, sB);
  *(float2*)&redQ[w][2*l] = make_float2(qA, qB);
  __syncthreads();
  if (t < 128){
    partials2[(size_t)blockIdx.x*256 + t]       = redS[0][t]+redS[1][t]+redS[2][t]+redS[3][t];
    partials2[(size_t)blockIdx.x*256 + 128 + t] = redQ[0][t]+redQ[1][t]+redQ[2][t]+redQ[3][t];
  }
}

// ---------------- w1 = relu(bn2(w0)) @ wW1 + wb1 ; cooperative tiles ----
// Phase A: pr-q per row. Phase B: wave-per-row uint gather -> h (bf16) in
// LDS. Phase C: (row, o-quad) matvec 128->16. ~29KB LDS -> 5 blocks/CU.
__global__ __launch_bounds__(256) void k_w1(const float* __restrict__ p,
                                            const int* __restrict__ idx,
                                            const float* __restrict__ pW1,
                                            const float* __restrict__ pb1,
                                            const float* __restrict__ pg1,
                                            const float* __restrict__ pbe1,
                                            const float* __restrict__ pW2,
                                            const float* __restrict__ pb2,
                                            const float* __restrict__ wg1,
                                            const float* __restrict__ wbe1,
                                            const float* __restrict__ wW1,
                                            const float* __restrict__ wb1,
                                            const u16* __restrict__ xq,
                                            const u16* __restrict__ xk,
                                            u16* __restrict__ w1out,
                                            const float* __restrict__ stats1,
                                            const float* __restrict__ stats2){
  __shared__ __align__(16) float4 pW2t[128];
  __shared__ float2 ss2[128];
  __shared__ float bn1s[8];
  __shared__ __align__(16) float wW1f[2048];
  __shared__ float wb1f[16];
  __shared__ float pW1f[9];
  __shared__ float sq0[64], sq1[64], sq2[64];
  __shared__ int   sgi[64];
  __shared__ __align__(16) u16 hsb[64*132];   // bf16 h, 16.9 KB, pad 132
  const int t = threadIdx.x;
  if (t < 3){
    float sv = stats1[t], sq = stats1[4+t];
    float mu = sv * INV_R, var = sq * INV_R - mu*mu;
    float rs = rsqrtf(var + EPS);
    float sc = rs * pg1[t];
    bn1s[t]   = sc;
    bn1s[4+t] = pb1[t] * sc + pbe1[t] - mu * sc;
  }
  if (t < 9)  pW1f[t] = pW1[t];
  if (t < 16) wb1f[t] = wb1[t];
  if (t < 128){
    pW2t[t] = make_float4(pW2[t], pW2[128+t], pW2[256+t], pb2[t]);
    float sv = stats2[t], sq = stats2[128+t];
    float mu = sv * INV_R, var = sq * INV_R - mu*mu;
    float rs = rsqrtf(var + EPS);
    float sc = rs * wg1[t];
    ss2[t] = make_float2(sc, wbe1[t] - mu * sc);
  }
  #pragma unroll
  for (int i = 0; i < 8; ++i) wW1f[t + i*256] = wW1[t + i*256];
  __syncthreads();

  const int w = t >> 6, l = t & 63;
  const float4 pwA = pW2t[2*l], pwB = pW2t[2*l+1];
  const float2 scA = ss2[2*l],  scB = ss2[2*l+1];
  const int row = t >> 2, o4 = (t & 3) * 4;
  const float b0o = wb1f[o4], b1o = wb1f[o4+1], b2o = wb1f[o4+2], b3o = wb1f[o4+3];

  for (int tile = 0; tile < 4; ++tile){
    const int rb = (blockIdx.x * 4 + tile) * 64;
    // phase A
    if (t < 64){
      int r = rb + t, n = r >> 4;
      int g = clampg(idx[r]);
      float d0 = p[3*g]   - p[3*n];
      float d1 = p[3*g+1] - p[3*n+1];
      float d2 = p[3*g+2] - p[3*n+2];
      sq0[t] = fmaxf((d0*pW1f[0] + d1*pW1f[3] + d2*pW1f[6]) * bn1s[0] + bn1s[4], 0.f);
      sq1[t] = fmaxf((d0*pW1f[1] + d1*pW1f[4] + d2*pW1f[7]) * bn1s[1] + bn1s[5], 0.f);
      sq2[t] = fmaxf((d0*pW1f[2] + d1*pW1f[5] + d2*pW1f[8]) * bn1s[2] + bn1s[6], 0.f);
      sgi[t] = g;
    }
    __syncthreads();
    // phase B: wave-per-row uint gather -> h bf16
    #pragma unroll
    for (int pt = 0; pt < 4; ++pt){
      const int n = (rb >> 4) + pt;
      unsigned qx = *(const unsigned*)(xq + (size_t)n*C + 2*l);
      float xqA, xqB; b2x2(qx, xqA, xqB);
      #pragma unroll
      for (int k = 0; k < 4; ++k){
        int rr = pt*16 + w + k*4;
        int g = sgi[rr];
        unsigned kx = *(const unsigned*)(xk + (size_t)g*C + 2*l);
        float xkA, xkB; b2x2(kx, xkA, xkB);
        float prA = sq0[rr]*pwA.x + sq1[rr]*pwA.y + sq2[rr]*pwA.z + pwA.w;
        float prB = sq0[rr]*pwB.x + sq1[rr]*pwB.y + sq2[rr]*pwB.z + pwB.w;
        float hA = fmaxf(fmaf(xkA - xqA + prA, scA.x, scA.y), 0.f);
        float hB = fmaxf(fmaf(xkB - xqB + prB, scB.x, scB.y), 0.f);
        *(unsigned*)&hsb[rr*132 + 2*l] = pk2(hA, hB);
      }
    }
    __syncthreads();
    // phase C: matvec 128 -> 4 outputs per thread
    float a0 = b0o, a1 = b1o, a2 = b2o, a3 = b3o;
    const unsigned* hrow = (const unsigned*)&hsb[row*132];
    #pragma unroll 4
    for (int c0 = 0; c0 < 128; c0 += 4){
      unsigned u0 = hrow[c0/2], u1 = hrow[c0/2 + 1];
      float h0, h1, h2, h3;
      b2x2(u0, h0, h1); b2x2(u1, h2, h3);
      float4 w0v = *(const float4*)&wW1f[(c0  )*16 + o4];
      float4 w1v = *(const float4*)&wW1f[(c0+1)*16 + o4];
      float4 w2v = *(const float4*)&wW1f[(c0+2)*16 + o4];
      float4 w3v = *(const float4*)&wW1f[(c0+3)*16 + o4];
      a0 = fmaf(h0, w0v.x, a0); a1 = fmaf(h0, w0v.y, a1);
      a2 = fmaf(h0, w0v.z, a2); a3 = fmaf(h0, w0v.w, a3);
      a0 = fmaf(h1, w1v.x, a0); a1 = fmaf(h1, w1v.y, a1);
      a2 = fmaf(h1, w1v.z, a2); a3 = fmaf(h1, w1v.w, a3);
      a0 = fmaf(h2, w2v.x, a0); a1 = fmaf(h2, w2v.y, a1);
      a2 = fmaf(h2, w2v.z, a2); a3 = fmaf(h2, w2v.w, a3);
      a0 = fmaf(h3, w3v.x, a0); a1 = fmaf(h3, w3v.y, a1);
      a2 = fmaf(h3, w3v.z, a2); a3 = fmaf(h3, w3v.w, a3);
    }
    uint2 pv;
    pv.x = pk2(a0, a1); pv.y = pk2(a2, a3);
    *(uint2*)(w1out + (size_t)(rb + row) * 16 + o4) = pv;
    __syncthreads();
  }
}

// ---------------- bn3 stats: coalesced pass over w1 logits --------------
__global__ __launch_bounds__(256) void k_bn3(const u16* __restrict__ w1ws,
                                             float* __restrict__ partials3){
  __shared__ float rs[256][8], rq[256][8];
  const int t = threadIdx.x;
  float s[8], q[8];
  #pragma unroll
  for (int k = 0; k < 8; ++k){ s[k] = 0.f; q[k] = 0.f; }
  const uint4* w4 = (const uint4*)w1ws;
  const int base = blockIdx.x * 256 + t;
  #pragma unroll 4
  for (int it = 0; it < 16; ++it){
    uint4 v = w4[base + it * 65536];
    #pragma unroll
    for (int k = 0; k < 4; ++k){
      float lo, hi; b2x2((&v.x)[k], lo, hi);
      s[k*2]   += lo; q[k*2]   = fmaf(lo, lo, q[k*2]);
      s[k*2+1] += hi; q[k*2+1] = fmaf(hi, hi, q[k*2+1]);
    }
  }
  #pragma unroll
  for (int k = 0; k < 8; ++k){ rs[t][k] = s[k]; rq[t][k] = q[k]; }
  __syncthreads();
  // thread t (parity t&1) held channels (t&1)*8 + [0..8)
  if (t < 32){
    int isq = t >> 4, ch = t & 15;
    int par = ch >> 3, k = ch & 7;
    float acc = 0.f;
    if (isq){
      for (int i2 = par; i2 < 256; i2 += 2) acc += rq[i2][k];
    } else {
      for (int i2 = par; i2 < 256; i2 += 2) acc += rs[i2][k];
    }
    partials3[blockIdx.x*32 + isq*16 + ch] = acc;
  }
}

// ---------------- final: bn3 -> relu -> wW2 -> softmax(j) -> aggregate --
__global__ __launch_bounds__(256) void k_out(const float* __restrict__ p,
                                             const int* __restrict__ idx,
                                             const float* __restrict__ pW1,
                                             const float* __restrict__ pb1,
                                             const float* __restrict__ pg1,
                                             const float* __restrict__ pbe1,
                                             const float* __restrict__ pW2,
                                             const float* __restrict__ pb2,
                                             const float* __restrict__ wg2,
                                             const float* __restrict__ wbe2,
                                             const float* __restrict__ wW2,
                                             const float* __restrict__ wb2,
                                             const u16* __restrict__ xv,
                                             const u16* __restrict__ w1ws,
                                             const float* __restrict__ stats1,
                                             const float* __restrict__ stats3,
                                             float* __restrict__ out){
  __shared__ __align__(16) float4 pW2t[128];
  __shared__ float pW1f[9];
  __shared__ float bn1s[8];
  __shared__ float sc3[16], sh3[16], wb2f[16];
  __shared__ float wW2f[256];
  __shared__ float s_w2[16*16*16];
  __shared__ float s_q0[256], s_q1[256], s_q2[256];
  __shared__ int   s_g[256];
  const int t = threadIdx.x;
  if (t < 3){
    float sv = stats1[t], sq = stats1[4+t];
    float mu = sv * INV_R, var = sq * INV_R - mu*mu;
    float rs = rsqrtf(var + EPS);
    float sc = rs * pg1[t];
    bn1s[t]   = sc;
    bn1s[4+t] = pb1[t] * sc + pbe1[t] - mu * sc;
  }
  if (t < 9) pW1f[t] = pW1[t];
  if (t < 16){
    float sv = stats3[t], sq = stats3[16+t];
    float mu = sv * INV_R, var = sq * INV_R - mu*mu;
    float rs = rsqrtf(var + EPS);
    float sc = rs * wg2[t];
    sc3[t] = sc;
    sh3[t] = wbe2[t] - mu * sc;
    wb2f[t] = wb2[t];
  }
  if (t < 128)
    pW2t[t] = make_float4(pW2[t], pW2[128+t], pW2[256+t], pb2[t]);
  wW2f[t] = wW2[t];
  __syncthreads();

  const int pt = t >> 4;
  const int jj = t & 15;
  const int n0 = blockIdx.x * 16;
  {
    const int n = n0 + pt;
    const int r = n * NS + jj;
    const int g = clampg(idx[r]);
    float d0 = p[3*g]   - p[3*n];
    float d1 = p[3*g+1] - p[3*n+1];
    float d2 = p[3*g+2] - p[3*n+2];
    s_q0[t] = fmaxf((d0*pW1f[0] + d1*pW1f[3] + d2*pW1f[6]) * bn1s[0] + bn1s[4], 0.f);
    s_q1[t] = fmaxf((d0*pW1f[1] + d1*pW1f[4] + d2*pW1f[7]) * bn1s[1] + bn1s[5], 0.f);
    s_q2[t] = fmaxf((d0*pW1f[2] + d1*pW1f[5] + d2*pW1f[8]) * bn1s[2] + bn1s[6], 0.f);
    s_g[t]  = g;
    const uint4* wp = (const uint4*)(w1ws + (size_t)r * 16);
    uint4 Wa = wp[0], Wb = wp[1];
    float h2[16];
    #pragma unroll
    for (int o2 = 0; o2 < 4; ++o2){
      float lo, hi;
      b2x2((&Wa.x)[o2], lo, hi);
      h2[o2*2]     = fmaxf(lo * sc3[o2*2]     + sh3[o2*2],     0.f);
      h2[o2*2+1]   = fmaxf(hi * sc3[o2*2+1]   + sh3[o2*2+1],   0.f);
      b2x2((&Wb.x)[o2], lo, hi);
      h2[8+o2*2]   = fmaxf(lo * sc3[8+o2*2]   + sh3[8+o2*2],   0.f);
      h2[8+o2*2+1] = fmaxf(hi * sc3[8+o2*2+1] + sh3[8+o2*2+1], 0.f);
    }
    float w2[16];
    #pragma unroll
    for (int o = 0; o < 16; ++o) w2[o] = wb2f[o];
    #pragma unroll
    for (int o2 = 0; o2 < 16; ++o2){
      float h = h2[o2];
      const float* wr = &wW2f[o2*16];
      #pragma unroll
      for (int o = 0; o < 16; ++o) w2[o] = fmaf(h, wr[o], w2[o]);
    }
    float* dst = &s_w2[(pt*16 + jj)*16];
    #pragma unroll
    for (int o = 0; o < 16; ++o) dst[o] = w2[o];
  }
  __syncthreads();
  const int cs = t & 15;
  {
    float mx = -1e30f;
    #pragma unroll
    for (int j2 = 0; j2 < 16; ++j2) mx = fmaxf(mx, s_w2[(pt*16+j2)*16 + cs]);
    float e[16]; float sum = 0.f;
    #pragma unroll
    for (int j2 = 0; j2 < 16; ++j2){
      e[j2] = __expf(s_w2[(pt*16+j2)*16 + cs] - mx);
      sum += e[j2];
    }
    float inv = 1.0f / sum;
    #pragma unroll
    for (int j2 = 0; j2 < 16; ++j2) s_w2[(pt*16+j2)*16 + cs] = e[j2] * inv;
  }
  __syncthreads();
  // aggregation: wave-per-point, lane covers channels 2l, 2l+1 (uint loads)
  const int w = t >> 6, l = t & 63;
  const float4 pwA = pW2t[2*l], pwB = pW2t[2*l+1];
  const int csA = (2*l) & 15;
  #pragma unroll
  for (int pp = 0; pp < 4; ++pp){
    const int pt2 = pp * 4 + w;
    const int n = n0 + pt2;
    float accA = 0.f, accB = 0.f;
    #pragma unroll
    for (int j = 0; j < 16; ++j){
      const int base = pt2*16 + j;
      float2 pj2 = *(const float2*)&s_w2[base*16 + csA];
      int g = s_g[base];
      float qa = s_q0[base], qb = s_q1[base], qc = s_q2[base];
      unsigned v = *(const unsigned*)(xv + (size_t)g*C + 2*l);
      float xvA, xvB; b2x2(v, xvA, xvB);
      float prA = qa*pwA.x + qb*pwA.y + qc*pwA.z + pwA.w;
      float prB = qa*pwB.x + qb*pwB.y + qc*pwB.z + pwB.w;
      accA = fmaf(xvA + prA, pj2.x, accA);
      accB = fmaf(xvB + prB, pj2.y, accB);
    }
    *(float2*)(out + (size_t)n*C + 2*l) = make_float2(accA, accB);
  }
}

extern "C" void kernel_launch(void* const* d_in, const int* in_sizes, int n_in,
                              void* d_out, int out_size, void* d_ws, size_t ws_size,
                              hipStream_t stream) {
  bool ok = (n_in == 23) && (out_size == NP*C) &&
            in_sizes[0] == NP*3 && in_sizes[1] == NP*C &&
            in_sizes[2] == C*C  && in_sizes[8] == 9 &&
            in_sizes[12] == 3*C && in_sizes[16] == C*(C/8) &&
            in_sizes[20] == (C/8)*(C/8) && in_sizes[22] == RTOT;
  if (!ok){
    k_sig<<<(NP*C+255)/256, 256, 0, stream>>>((float*)d_out, 10000.0f);
    return;
  }
  if (ws_size < WS_NEED){
    k_sig<<<(NP*C+255)/256, 256, 0, stream>>>((float*)d_out, 20000.0f);
    return;
  }
  const float* p    = (const float*)d_in[0];
  const float* x    = (const float*)d_in[1];
  const float* Wq   = (const float*)d_in[2];
  const float* bq   = (const float*)d_in[3];
  const float* Wk   = (const float*)d_in[4];
  const float* bk   = (const float*)d_in[5];
  const float* Wv   = (const float*)d_in[6];
  const float* bv   = (const float*)d_in[7];
  const float* pW1  = (const float*)d_in[8];
  const float* pb1  = (const float*)d_in[9];
  const float* pg1  = (const float*)d_in[10];
  const float* pbe1 = (const float*)d_in[11];
  const float* pW2  = (const float*)d_in[12];
  const float* pb2  = (const float*)d_in[13];
  const float* wg1  = (const float*)d_in[14];
  const float* wbe1 = (const float*)d_in[15];
  const float* wW1  = (const float*)d_in[16];
  const float* wb1  = (const float*)d_in[17];
  const float* wg2  = (const float*)d_in[18];
  const float* wbe2 = (const float*)d_in[19];
  const float* wW2  = (const float*)d_in[20];
  const float* wb2  = (const float*)d_in[21];
  const int* idx    = (const int*)d_in[22];

  char* ws = (char*)d_ws;
  u16* xq    = (u16*)(ws + oXQ);
  u16* xk    = (u16*)(ws + oXK);
  u16* xv    = (u16*)(ws + oXV);
  u16* w1ws  = (u16*)(ws + oW1);
  float* pa  = (float*)(ws + oPA);
  float* pb  = (float*)(ws + oPB);
  float* pc  = (float*)(ws + oPC);
  float* s1  = (float*)(ws + oS1);
  float* s2  = (float*)(ws + oS2);
  float* s3  = (float*)(ws + oS3);

  k_qkv<<<dim3(512, 3), 256, 0, stream>>>(x, Wq, Wk, Wv, bq, bk, bv, xq);
  k_bn1<<<512, 256, 0, stream>>>(p, idx, pW1, pb1, pa);
  k_fin<<<1, 256, 0, stream>>>(pa, s1, 512, 8);
  k_bn2<<<2048, 256, 0, stream>>>(p, idx, pW1, pb1, pg1, pbe1, pW2, pb2,
                                  xq, xk, s1, pb);
  k_fin<<<4, 256, 0, stream>>>(pb, s2, 2048, 256);
  k_w1 <<<2048, 256, 0, stream>>>(p, idx, pW1, pb1, pg1, pbe1, pW2, pb2,
                                  wg1, wbe1, wW1, wb1, xq, xk, w1ws, s1, s2);
  k_bn3<<<256, 256, 0, stream>>>(w1ws, pc);
  k_fin<<<1, 256, 0, stream>>>(pc, s3, 256, 32);
  k_out<<<2048, 256, 0, stream>>>(p, idx, pW1, pb1, pg1, pbe1, pW2, pb2,
                                  wg2, wbe2, wW2, wb2, xv, w1ws, s1, s3,
                                  (float*)d_out);
}

// Round 6
// 307.117 us; speedup vs baseline: 7.6405x; 1.5470x over previous
//
#include <hip/hip_runtime.h>

typedef unsigned short u16;
#define DEV __device__ __forceinline__

constexpr int NP = 32768;
constexpr int C  = 128;
constexpr int NS = 16;
constexpr int RTOT = NP * NS;              // 524288 rows of [N,NS]
constexpr float EPS = 1e-5f;
constexpr float INV_R = 1.0f / (float)RTOT;

// ---- workspace layout (bytes) ----
// Proven (round 1 ran): ws_size >= 42117120.
constexpr size_t oXQ = 0;                              // xq/xk/xv bf16: 3*8MB
constexpr size_t oXK = (size_t)NP * C * 2;             // 8388608
constexpr size_t oXV = oXK * 2;
constexpr size_t oW1 = oXK * 3;                        // w1 logits bf16: 16MB
// partials1/2 alias INTO the w1out region (dead before k_w1 overwrites it):
constexpr size_t oPA = oW1;                            // pa [512][8] f32
constexpr size_t oPB = oW1 + 16384;                    // pb [2048][256] f32 = 2MB
// mid-stage sums + bn3 partials live AFTER w1out (must survive k_w1):
constexpr size_t oST = oW1 + (size_t)RTOT * 16 * 2;    // 41943040
constexpr size_t oM1 = oST;                            // mid1[16][8]
constexpr size_t oM2 = oM1 + 16*8*4;                   // mid2[16][256]
constexpr size_t oM3 = oM2 + 16*256*4;                 // mid3[16][32]
constexpr size_t oPC = oM3 + 16*32*4;                  // pc [256][32]
constexpr size_t WS_NEED = oPC + 256*32*4;             // 41994752 < 42117120 proven

DEV float bu2f(u16 v){ return __uint_as_float(((unsigned)v) << 16); }
DEV u16 f2bu(float f){
  unsigned u = __float_as_uint(f);
  return (u16)((u + 0x7fffu + ((u >> 16) & 1u)) >> 16);   // RNE
}
DEV unsigned pk2(float a, float b){ return (unsigned)f2bu(a) | ((unsigned)f2bu(b) << 16); }
DEV void b2x2(unsigned v, float& lo, float& hi){
  lo = __uint_as_float(v << 16);
  hi = __uint_as_float(v & 0xffff0000u);
}
DEV int clampg(int g){ return g < 0 ? 0 : (g > NP-1 ? NP-1 : g); }

// ---------------- diagnostics ----------------
__global__ __launch_bounds__(256) void k_sig(float* __restrict__ out, float val){
  int i = blockIdx.x * 256 + threadIdx.x;
  if (i < NP*C) out[i] = val;
}

// ---------------- stage-1 partial reduce: mid[y][ch] = sum of slot chunk --
// grid (ceil(width/64), 16); 4 waves split the chunk; 4-acc unroll for MLP.
__global__ __launch_bounds__(256) void k_finA(const float* __restrict__ part,
                                              float* __restrict__ mid,
                                              int slots, int width){
  __shared__ float red[4][64];
  const int l = threadIdx.x & 63, w = threadIdx.x >> 6;
  const int ch = blockIdx.x * 64 + l;
  const int y = blockIdx.y;
  const int cs = slots >> 4;           // 16 slot-groups
  const int n4 = cs >> 2;              // per-wave slot count
  float a0 = 0.f, a1 = 0.f, a2 = 0.f, a3 = 0.f;
  if (ch < width){
    const float* base = part + (size_t)(y*cs + w*n4) * width + ch;
    int j = 0;
    for (; j + 4 <= n4; j += 4){
      a0 += base[(size_t)(j  ) * width];
      a1 += base[(size_t)(j+1) * width];
      a2 += base[(size_t)(j+2) * width];
      a3 += base[(size_t)(j+3) * width];
    }
    for (; j < n4; ++j) a0 += base[(size_t)j * width];
  }
  red[w][l] = (a0 + a1) + (a2 + a3);
  __syncthreads();
  if (threadIdx.x < 64 && ch < width)
    mid[(size_t)y * width + ch] = red[0][l] + red[1][l] + red[2][l] + red[3][l];
}

// ---------------- QKV GEMM (fp32, W staged in LDS, 4 rows x 8 cols/thread)
__global__ __launch_bounds__(256) void k_qkv(const float* __restrict__ x,
                                             const float* __restrict__ Wq,
                                             const float* __restrict__ Wk,
                                             const float* __restrict__ Wv,
                                             const float* __restrict__ bq,
                                             const float* __restrict__ bk,
                                             const float* __restrict__ bv,
                                             u16* __restrict__ outw){
  __shared__ __align__(16) float Wl[128*128];   // 64 KB
  const int t = threadIdx.x;
  const int mat = blockIdx.y;
  const float* W    = (mat==0) ? Wq : ((mat==1) ? Wk : Wv);
  const float* bias = (mat==0) ? bq : ((mat==1) ? bk : bv);
  u16* outp = outw + (size_t)mat * NP * C;

  {
    const float4* Ws4 = (const float4*)W;
    float4* Wl4 = (float4*)Wl;
    #pragma unroll
    for (int i = 0; i < 16; ++i) Wl4[t + i*256] = Ws4[t + i*256];
  }
  __syncthreads();

  const int tr = t >> 4, cg = t & 15;
  const int row0 = blockIdx.x * 64 + tr * 4;
  float acc[4][8];
  #pragma unroll
  for (int j = 0; j < 8; ++j){
    float bj = bias[cg*8 + j];
    #pragma unroll
    for (int rr = 0; rr < 4; ++rr) acc[rr][j] = bj;
  }
  const float4* Wl4 = (const float4*)Wl;
  for (int k0 = 0; k0 < 128; k0 += 4){
    float4 xa[4];
    #pragma unroll
    for (int rr = 0; rr < 4; ++rr)
      xa[rr] = *(const float4*)(x + (size_t)(row0+rr)*C + k0);
    #pragma unroll
    for (int u = 0; u < 4; ++u){
      float4 w0 = Wl4[(k0+u)*32 + cg*2];
      float4 w1 = Wl4[(k0+u)*32 + cg*2 + 1];
      #pragma unroll
      for (int rr = 0; rr < 4; ++rr){
        float a = (&xa[rr].x)[u];
        acc[rr][0] = fmaf(a, w0.x, acc[rr][0]);
        acc[rr][1] = fmaf(a, w0.y, acc[rr][1]);
        acc[rr][2] = fmaf(a, w0.z, acc[rr][2]);
        acc[rr][3] = fmaf(a, w0.w, acc[rr][3]);
        acc[rr][4] = fmaf(a, w1.x, acc[rr][4]);
        acc[rr][5] = fmaf(a, w1.y, acc[rr][5]);
        acc[rr][6] = fmaf(a, w1.z, acc[rr][6]);
        acc[rr][7] = fmaf(a, w1.w, acc[rr][7]);
      }
    }
  }
  #pragma unroll
  for (int rr = 0; rr < 4; ++rr){
    uint4 pkd;
    #pragma unroll
    for (int q2 = 0; q2 < 4; ++q2)
      (&pkd.x)[q2] = pk2(acc[rr][q2*2], acc[rr][q2*2+1]);
    *(uint4*)(outp + (size_t)(row0+rr)*C + cg*8) = pkd;
  }
}

// ---------------- bn1 stats -> per-block partials (no atomics) ----------
__global__ __launch_bounds__(256) void k_bn1(const float* __restrict__ p,
                                             const int* __restrict__ idx,
                                             const float* __restrict__ pW1,
                                             const float* __restrict__ pb1,
                                             float* __restrict__ partials1){
  __shared__ float wred[4][8];
  const int t = threadIdx.x;
  float w[9], b3[3];
  #pragma unroll
  for (int i = 0; i < 9; ++i) w[i] = pW1[i];
  #pragma unroll
  for (int i = 0; i < 3; ++i) b3[i] = pb1[i];
  float s[3] = {0,0,0}, q[3] = {0,0,0};
  const int base = blockIdx.x * 1024 + t;
  #pragma unroll
  for (int i = 0; i < 4; ++i){
    int r = base + i*256;
    int g = clampg(idx[r]);
    int n = r >> 4;
    float d0 = p[3*g]   - p[3*n];
    float d1 = p[3*g+1] - p[3*n+1];
    float d2 = p[3*g+2] - p[3*n+2];
    #pragma unroll
    for (int k = 0; k < 3; ++k){
      float tv = d0*w[k] + d1*w[3+k] + d2*w[6+k] + b3[k];
      s[k] += tv; q[k] = fmaf(tv, tv, q[k]);
    }
  }
  #pragma unroll
  for (int k = 0; k < 3; ++k){
    #pragma unroll
    for (int m = 1; m < 64; m <<= 1){
      s[k] += __shfl_xor(s[k], m);
      q[k] += __shfl_xor(q[k], m);
    }
  }
  if ((t & 63) == 0){
    int wv = t >> 6;
    wred[wv][0] = s[0]; wred[wv][1] = s[1]; wred[wv][2] = s[2]; wred[wv][3] = 0.f;
    wred[wv][4] = q[0]; wred[wv][5] = q[1]; wred[wv][6] = q[2]; wred[wv][7] = 0.f;
  }
  __syncthreads();
  if (t < 8)
    partials1[blockIdx.x*8 + t] = wred[0][t] + wred[1][t] + wred[2][t] + wred[3][t];
}

// ---------------- bn2 stats: wave-per-row uint gather, high occupancy ---
__global__ __launch_bounds__(256) void k_bn2(const float* __restrict__ p,
                                             const int* __restrict__ idx,
                                             const float* __restrict__ pW1,
                                             const float* __restrict__ pb1,
                                             const float* __restrict__ pg1,
                                             const float* __restrict__ pbe1,
                                             const float* __restrict__ pW2,
                                             const float* __restrict__ pb2,
                                             const u16* __restrict__ xq,
                                             const u16* __restrict__ xk,
                                             const float* __restrict__ mid1,
                                             float* __restrict__ partials2){
  __shared__ float sq0[64], sq1[64], sq2[64];
  __shared__ int   sgi[64];
  __shared__ __align__(16) float4 pW2t[128];
  __shared__ float bn1s[8];
  __shared__ __align__(16) float redS[4][128], redQ[4][128];
  const int t = threadIdx.x;
  if (t < 3){
    float sv = 0.f, sq = 0.f;
    for (int i = 0; i < 16; ++i){ sv += mid1[i*8+t]; sq += mid1[i*8+4+t]; }
    float mu = sv * INV_R, var = sq * INV_R - mu*mu;
    float rs = rsqrtf(var + EPS);
    float sc = rs * pg1[t];
    bn1s[t]   = sc;
    bn1s[4+t] = pb1[t] * sc + pbe1[t] - mu * sc;
  }
  if (t < 128)
    pW2t[t] = make_float4(pW2[t], pW2[128+t], pW2[256+t], pb2[t]);
  float w9[9];
  if (t < 64){
    #pragma unroll
    for (int i = 0; i < 9; ++i) w9[i] = pW1[i];
  }
  __syncthreads();
  const int w = t >> 6, l = t & 63;
  const float4 pwA = pW2t[2*l], pwB = pW2t[2*l+1];
  float sA = 0.f, qA = 0.f, sB = 0.f, qB = 0.f;

  for (int tile = 0; tile < 4; ++tile){
    const int b0 = (blockIdx.x * 4 + tile) * 64;
    if (t < 64){
      int r = b0 + t, n = r >> 4;
      int g = clampg(idx[r]);
      float d0 = p[3*g]   - p[3*n];
      float d1 = p[3*g+1] - p[3*n+1];
      float d2 = p[3*g+2] - p[3*n+2];
      sq0[t] = fmaxf((d0*w9[0] + d1*w9[3] + d2*w9[6]) * bn1s[0] + bn1s[4], 0.f);
      sq1[t] = fmaxf((d0*w9[1] + d1*w9[4] + d2*w9[7]) * bn1s[1] + bn1s[5], 0.f);
      sq2[t] = fmaxf((d0*w9[2] + d1*w9[5] + d2*w9[8]) * bn1s[2] + bn1s[6], 0.f);
      sgi[t] = g;
    }
    __syncthreads();
    #pragma unroll
    for (int pt = 0; pt < 4; ++pt){
      const int n = (b0 >> 4) + pt;
      unsigned qx = *(const unsigned*)(xq + (size_t)n*C + 2*l);
      float xqA, xqB; b2x2(qx, xqA, xqB);
      #pragma unroll
      for (int k = 0; k < 4; ++k){
        int rr = pt*16 + w + k*4;
        int g = sgi[rr];
        unsigned kx = *(const unsigned*)(xk + (size_t)g*C + 2*l);
        float xkA, xkB; b2x2(kx, xkA, xkB);
        float prA = sq0[rr]*pwA.x + sq1[rr]*pwA.y + sq2[rr]*pwA.z + pwA.w;
        float prB = sq0[rr]*pwB.x + sq1[rr]*pwB.y + sq2[rr]*pwB.z + pwB.w;
        float w0A = xkA - xqA + prA;
        float w0B = xkB - xqB + prB;
        sA += w0A; qA = fmaf(w0A, w0A, qA);
        sB += w0B; qB = fmaf(w0B, w0B, qB);
      }
    }
    __syncthreads();
  }
  *(float2*)&redS[w][2*l] = make_float2(sA, sB);
  *(float2*)&redQ[w][2*l] = make_float2(qA, qB);
  __syncthreads();
  if (t < 128){
    partials2[(size_t)blockIdx.x*256 + t]       = redS[0][t]+redS[1][t]+redS[2][t]+redS[3][t];
    partials2[(size_t)blockIdx.x*256 + 128 + t] = redQ[0][t]+redQ[1][t]+redQ[2][t]+redQ[3][t];
  }
}

// ---------------- w1 = relu(bn2(w0)) @ wW1 + wb1 ; cooperative tiles ----
__global__ __launch_bounds__(256) void k_w1(const float* __restrict__ p,
                                            const int* __restrict__ idx,
                                            const float* __restrict__ pW1,
                                            const float* __restrict__ pb1,
                                            const float* __restrict__ pg1,
                                            const float* __restrict__ pbe1,
                                            const float* __restrict__ pW2,
                                            const float* __restrict__ pb2,
                                            const float* __restrict__ wg1,
                                            const float* __restrict__ wbe1,
                                            const float* __restrict__ wW1,
                                            const float* __restrict__ wb1,
                                            const u16* __restrict__ xq,
                                            const u16* __restrict__ xk,
                                            u16* __restrict__ w1out,
                                            const float* __restrict__ mid1,
                                            const float* __restrict__ mid2){
  __shared__ __align__(16) float4 pW2t[128];
  __shared__ float2 ss2[128];
  __shared__ float bn1s[8];
  __shared__ __align__(16) float wW1f[2048];
  __shared__ float wb1f[16];
  __shared__ float pW1f[9];
  __shared__ float sq0[64], sq1[64], sq2[64];
  __shared__ int   sgi[64];
  __shared__ __align__(16) u16 hsb[64*132];   // bf16 h, 16.9 KB, pad 132
  const int t = threadIdx.x;
  if (t < 3){
    float sv = 0.f, sq = 0.f;
    for (int i = 0; i < 16; ++i){ sv += mid1[i*8+t]; sq += mid1[i*8+4+t]; }
    float mu = sv * INV_R, var = sq * INV_R - mu*mu;
    float rs = rsqrtf(var + EPS);
    float sc = rs * pg1[t];
    bn1s[t]   = sc;
    bn1s[4+t] = pb1[t] * sc + pbe1[t] - mu * sc;
  }
  if (t < 9)  pW1f[t] = pW1[t];
  if (t < 16) wb1f[t] = wb1[t];
  if (t < 128){
    pW2t[t] = make_float4(pW2[t], pW2[128+t], pW2[256+t], pb2[t]);
    float sv = 0.f, sq = 0.f;
    for (int i = 0; i < 16; ++i){ sv += mid2[i*256+t]; sq += mid2[i*256+128+t]; }
    float mu = sv * INV_R, var = sq * INV_R - mu*mu;
    float rs = rsqrtf(var + EPS);
    float sc = rs * wg1[t];
    ss2[t] = make_float2(sc, wbe1[t] - mu * sc);
  }
  #pragma unroll
  for (int i = 0; i < 8; ++i) wW1f[t + i*256] = wW1[t + i*256];
  __syncthreads();

  const int w = t >> 6, l = t & 63;
  const float4 pwA = pW2t[2*l], pwB = pW2t[2*l+1];
  const float2 scA = ss2[2*l],  scB = ss2[2*l+1];
  const int row = t >> 2, o4 = (t & 3) * 4;
  const float b0o = wb1f[o4], b1o = wb1f[o4+1], b2o = wb1f[o4+2], b3o = wb1f[o4+3];

  for (int tile = 0; tile < 4; ++tile){
    const int rb = (blockIdx.x * 4 + tile) * 64;
    // phase A
    if (t < 64){
      int r = rb + t, n = r >> 4;
      int g = clampg(idx[r]);
      float d0 = p[3*g]   - p[3*n];
      float d1 = p[3*g+1] - p[3*n+1];
      float d2 = p[3*g+2] - p[3*n+2];
      sq0[t] = fmaxf((d0*pW1f[0] + d1*pW1f[3] + d2*pW1f[6]) * bn1s[0] + bn1s[4], 0.f);
      sq1[t] = fmaxf((d0*pW1f[1] + d1*pW1f[4] + d2*pW1f[7]) * bn1s[1] + bn1s[5], 0.f);
      sq2[t] = fmaxf((d0*pW1f[2] + d1*pW1f[5] + d2*pW1f[8]) * bn1s[2] + bn1s[6], 0.f);
      sgi[t] = g;
    }
    __syncthreads();
    // phase B: wave-per-row uint gather -> h bf16
    #pragma unroll
    for (int pt = 0; pt < 4; ++pt){
      const int n = (rb >> 4) + pt;
      unsigned qx = *(const unsigned*)(xq + (size_t)n*C + 2*l);
      float xqA, xqB; b2x2(qx, xqA, xqB);
      #pragma unroll
      for (int k = 0; k < 4; ++k){
        int rr = pt*16 + w + k*4;
        int g = sgi[rr];
        unsigned kx = *(const unsigned*)(xk + (size_t)g*C + 2*l);
        float xkA, xkB; b2x2(kx, xkA, xkB);
        float prA = sq0[rr]*pwA.x + sq1[rr]*pwA.y + sq2[rr]*pwA.z + pwA.w;
        float prB = sq0[rr]*pwB.x + sq1[rr]*pwB.y + sq2[rr]*pwB.z + pwB.w;
        float hA = fmaxf(fmaf(xkA - xqA + prA, scA.x, scA.y), 0.f);
        float hB = fmaxf(fmaf(xkB - xqB + prB, scB.x, scB.y), 0.f);
        *(unsigned*)&hsb[rr*132 + 2*l] = pk2(hA, hB);
      }
    }
    __syncthreads();
    // phase C: matvec 128 -> 4 outputs per thread
    float a0 = b0o, a1 = b1o, a2 = b2o, a3 = b3o;
    const unsigned* hrow = (const unsigned*)&hsb[row*132];
    #pragma unroll 4
    for (int c0 = 0; c0 < 128; c0 += 4){
      unsigned u0 = hrow[c0/2], u1 = hrow[c0/2 + 1];
      float h0, h1, h2, h3;
      b2x2(u0, h0, h1); b2x2(u1, h2, h3);
      float4 w0v = *(const float4*)&wW1f[(c0  )*16 + o4];
      float4 w1v = *(const float4*)&wW1f[(c0+1)*16 + o4];
      float4 w2v = *(const float4*)&wW1f[(c0+2)*16 + o4];
      float4 w3v = *(const float4*)&wW1f[(c0+3)*16 + o4];
      a0 = fmaf(h0, w0v.x, a0); a1 = fmaf(h0, w0v.y, a1);
      a2 = fmaf(h0, w0v.z, a2); a3 = fmaf(h0, w0v.w, a3);
      a0 = fmaf(h1, w1v.x, a0); a1 = fmaf(h1, w1v.y, a1);
      a2 = fmaf(h1, w1v.z, a2); a3 = fmaf(h1, w1v.w, a3);
      a0 = fmaf(h2, w2v.x, a0); a1 = fmaf(h2, w2v.y, a1);
      a2 = fmaf(h2, w2v.z, a2); a3 = fmaf(h2, w2v.w, a3);
      a0 = fmaf(h3, w3v.x, a0); a1 = fmaf(h3, w3v.y, a1);
      a2 = fmaf(h3, w3v.z, a2); a3 = fmaf(h3, w3v.w, a3);
    }
    uint2 pv;
    pv.x = pk2(a0, a1); pv.y = pk2(a2, a3);
    *(uint2*)(w1out + (size_t)(rb + row) * 16 + o4) = pv;
    __syncthreads();
  }
}

// ---------------- bn3 stats: coalesced pass over w1 logits --------------
__global__ __launch_bounds__(256) void k_bn3(const u16* __restrict__ w1ws,
                                             float* __restrict__ partials3){
  __shared__ float rs[256][8], rq[256][8];
  const int t = threadIdx.x;
  float s[8], q[8];
  #pragma unroll
  for (int k = 0; k < 8; ++k){ s[k] = 0.f; q[k] = 0.f; }
  const uint4* w4 = (const uint4*)w1ws;
  const int base = blockIdx.x * 256 + t;
  #pragma unroll 4
  for (int it = 0; it < 16; ++it){
    uint4 v = w4[base + it * 65536];
    #pragma unroll
    for (int k = 0; k < 4; ++k){
      float lo, hi; b2x2((&v.x)[k], lo, hi);
      s[k*2]   += lo; q[k*2]   = fmaf(lo, lo, q[k*2]);
      s[k*2+1] += hi; q[k*2+1] = fmaf(hi, hi, q[k*2+1]);
    }
  }
  #pragma unroll
  for (int k = 0; k < 8; ++k){ rs[t][k] = s[k]; rq[t][k] = q[k]; }
  __syncthreads();
  // thread t (parity t&1) held channels (t&1)*8 + [0..8)
  if (t < 32){
    int isq = t >> 4, ch = t & 15;
    int par = ch >> 3, k = ch & 7;
    float acc = 0.f;
    if (isq){
      for (int i2 = par; i2 < 256; i2 += 2) acc += rq[i2][k];
    } else {
      for (int i2 = par; i2 < 256; i2 += 2) acc += rs[i2][k];
    }
    partials3[blockIdx.x*32 + isq*16 + ch] = acc;
  }
}

// ---------------- final: bn3 -> relu -> wW2 -> softmax(j) -> aggregate --
__global__ __launch_bounds__(256) void k_out(const float* __restrict__ p,
                                             const int* __restrict__ idx,
                                             const float* __restrict__ pW1,
                                             const float* __restrict__ pb1,
                                             const float* __restrict__ pg1,
                                             const float* __restrict__ pbe1,
                                             const float* __restrict__ pW2,
                                             const float* __restrict__ pb2,
                                             const float* __restrict__ wg2,
                                             const float* __restrict__ wbe2,
                                             const float* __restrict__ wW2,
                                             const float* __restrict__ wb2,
                                             const u16* __restrict__ xv,
                                             const u16* __restrict__ w1ws,
                                             const float* __restrict__ mid1,
                                             const float* __restrict__ mid3,
                                             float* __restrict__ out){
  __shared__ __align__(16) float4 pW2t[128];
  __shared__ float pW1f[9];
  __shared__ float bn1s[8];
  __shared__ float sc3[16], sh3[16], wb2f[16];
  __shared__ float wW2f[256];
  __shared__ float s_w2[16*16*16];
  __shared__ float s_q0[256], s_q1[256], s_q2[256];
  __shared__ int   s_g[256];
  const int t = threadIdx.x;
  if (t < 3){
    float sv = 0.f, sq = 0.f;
    for (int i = 0; i < 16; ++i){ sv += mid1[i*8+t]; sq += mid1[i*8+4+t]; }
    float mu = sv * INV_R, var = sq * INV_R - mu*mu;
    float rs = rsqrtf(var + EPS);
    float sc = rs * pg1[t];
    bn1s[t]   = sc;
    bn1s[4+t] = pb1[t] * sc + pbe1[t] - mu * sc;
  }
  if (t < 9) pW1f[t] = pW1[t];
  if (t < 16){
    float sv = 0.f, sq = 0.f;
    for (int i = 0; i < 16; ++i){ sv += mid3[i*32+t]; sq += mid3[i*32+16+t]; }
    float mu = sv * INV_R, var = sq * INV_R - mu*mu;
    float rs = rsqrtf(var + EPS);
    float sc = rs * wg2[t];
    sc3[t] = sc;
    sh3[t] = wbe2[t] - mu * sc;
    wb2f[t] = wb2[t];
  }
  if (t < 128)
    pW2t[t] = make_float4(pW2[t], pW2[128+t], pW2[256+t], pb2[t]);
  wW2f[t] = wW2[t];
  __syncthreads();

  const int pt = t >> 4;
  const int jj = t & 15;
  const int n0 = blockIdx.x * 16;
  {
    const int n = n0 + pt;
    const int r = n * NS + jj;
    const int g = clampg(idx[r]);
    float d0 = p[3*g]   - p[3*n];
    float d1 = p[3*g+1] - p[3*n+1];
    float d2 = p[3*g+2] - p[3*n+2];
    s_q0[t] = fmaxf((d0*pW1f[0] + d1*pW1f[3] + d2*pW1f[6]) * bn1s[0] + bn1s[4], 0.f);
    s_q1[t] = fmaxf((d0*pW1f[1] + d1*pW1f[4] + d2*pW1f[7]) * bn1s[1] + bn1s[5], 0.f);
    s_q2[t] = fmaxf((d0*pW1f[2] + d1*pW1f[5] + d2*pW1f[8]) * bn1s[2] + bn1s[6], 0.f);
    s_g[t]  = g;
    const uint4* wp = (const uint4*)(w1ws + (size_t)r * 16);
    uint4 Wa = wp[0], Wb = wp[1];
    float h2[16];
    #pragma unroll
    for (int o2 = 0; o2 < 4; ++o2){
      float lo, hi;
      b2x2((&Wa.x)[o2], lo, hi);
      h2[o2*2]     = fmaxf(lo * sc3[o2*2]     + sh3[o2*2],     0.f);
      h2[o2*2+1]   = fmaxf(hi * sc3[o2*2+1]   + sh3[o2*2+1],   0.f);
      b2x2((&Wb.x)[o2], lo, hi);
      h2[8+o2*2]   = fmaxf(lo * sc3[8+o2*2]   + sh3[8+o2*2],   0.f);
      h2[8+o2*2+1] = fmaxf(hi * sc3[8+o2*2+1] + sh3[8+o2*2+1], 0.f);
    }
    float w2[16];
    #pragma unroll
    for (int o = 0; o < 16; ++o) w2[o] = wb2f[o];
    #pragma unroll
    for (int o2 = 0; o2 < 16; ++o2){
      float h = h2[o2];
      const float* wr = &wW2f[o2*16];
      #pragma unroll
      for (int o = 0; o < 16; ++o) w2[o] = fmaf(h, wr[o], w2[o]);
    }
    float* dst = &s_w2[(pt*16 + jj)*16];
    #pragma unroll
    for (int o = 0; o < 16; ++o) dst[o] = w2[o];
  }
  __syncthreads();
  const int cs = t & 15;
  {
    float mx = -1e30f;
    #pragma unroll
    for (int j2 = 0; j2 < 16; ++j2) mx = fmaxf(mx, s_w2[(pt*16+j2)*16 + cs]);
    float e[16]; float sum = 0.f;
    #pragma unroll
    for (int j2 = 0; j2 < 16; ++j2){
      e[j2] = __expf(s_w2[(pt*16+j2)*16 + cs] - mx);
      sum += e[j2];
    }
    float inv = 1.0f / sum;
    #pragma unroll
    for (int j2 = 0; j2 < 16; ++j2) s_w2[(pt*16+j2)*16 + cs] = e[j2] * inv;
  }
  __syncthreads();
  // aggregation: wave-per-point, lane covers channels 2l, 2l+1 (uint loads)
  const int w = t >> 6, l = t & 63;
  const float4 pwA = pW2t[2*l], pwB = pW2t[2*l+1];
  const int csA = (2*l) & 15;
  #pragma unroll
  for (int pp = 0; pp < 4; ++pp){
    const int pt2 = pp * 4 + w;
    const int n = n0 + pt2;
    float accA = 0.f, accB = 0.f;
    #pragma unroll
    for (int j = 0; j < 16; ++j){
      const int base = pt2*16 + j;
      float2 pj2 = *(const float2*)&s_w2[base*16 + csA];
      int g = s_g[base];
      float qa = s_q0[base], qb = s_q1[base], qc = s_q2[base];
      unsigned v = *(const unsigned*)(xv + (size_t)g*C + 2*l);
      float xvA, xvB; b2x2(v, xvA, xvB);
      float prA = qa*pwA.x + qb*pwA.y + qc*pwA.z + pwA.w;
      float prB = qa*pwB.x + qb*pwB.y + qc*pwB.z + pwB.w;
      accA = fmaf(xvA + prA, pj2.x, accA);
      accB = fmaf(xvB + prB, pj2.y, accB);
    }
    *(float2*)(out + (size_t)n*C + 2*l) = make_float2(accA, accB);
  }
}

extern "C" void kernel_launch(void* const* d_in, const int* in_sizes, int n_in,
                              void* d_out, int out_size, void* d_ws, size_t ws_size,
                              hipStream_t stream) {
  bool ok = (n_in == 23) && (out_size == NP*C) &&
            in_sizes[0] == NP*3 && in_sizes[1] == NP*C &&
            in_sizes[2] == C*C  && in_sizes[8] == 9 &&
            in_sizes[12] == 3*C && in_sizes[16] == C*(C/8) &&
            in_sizes[20] == (C/8)*(C/8) && in_sizes[22] == RTOT;
  if (!ok){
    k_sig<<<(NP*C+255)/256, 256, 0, stream>>>((float*)d_out, 10000.0f);
    return;
  }
  if (ws_size < WS_NEED){
    k_sig<<<(NP*C+255)/256, 256, 0, stream>>>((float*)d_out, 20000.0f);
    return;
  }
  const float* p    = (const float*)d_in[0];
  const float* x    = (const float*)d_in[1];
  const float* Wq   = (const float*)d_in[2];
  const float* bq   = (const float*)d_in[3];
  const float* Wk   = (const float*)d_in[4];
  const float* bk   = (const float*)d_in[5];
  const float* Wv   = (const float*)d_in[6];
  const float* bv   = (const float*)d_in[7];
  const float* pW1  = (const float*)d_in[8];
  const float* pb1  = (const float*)d_in[9];
  const float* pg1  = (const float*)d_in[10];
  const float* pbe1 = (const float*)d_in[11];
  const float* pW2  = (const float*)d_in[12];
  const float* pb2  = (const float*)d_in[13];
  const float* wg1  = (const float*)d_in[14];
  const float* wbe1 = (const float*)d_in[15];
  const float* wW1  = (const float*)d_in[16];
  const float* wb1  = (const float*)d_in[17];
  const float* wg2  = (const float*)d_in[18];
  const float* wbe2 = (const float*)d_in[19];
  const float* wW2  = (const float*)d_in[20];
  const float* wb2  = (const float*)d_in[21];
  const int* idx    = (const int*)d_in[22];

  char* ws = (char*)d_ws;
  u16* xq    = (u16*)(ws + oXQ);
  u16* xk    = (u16*)(ws + oXK);
  u16* xv    = (u16*)(ws + oXV);
  u16* w1ws  = (u16*)(ws + oW1);
  float* pa  = (float*)(ws + oPA);
  float* pb  = (float*)(ws + oPB);
  float* pc  = (float*)(ws + oPC);
  float* m1  = (float*)(ws + oM1);
  float* m2  = (float*)(ws + oM2);
  float* m3  = (float*)(ws + oM3);

  k_qkv<<<dim3(512, 3), 256, 0, stream>>>(x, Wq, Wk, Wv, bq, bk, bv, xq);
  k_bn1<<<512, 256, 0, stream>>>(p, idx, pW1, pb1, pa);
  k_finA<<<dim3(1, 16), 256, 0, stream>>>(pa, m1, 512, 8);
  k_bn2<<<2048, 256, 0, stream>>>(p, idx, pW1, pb1, pg1, pbe1, pW2, pb2,
                                  xq, xk, m1, pb);
  k_finA<<<dim3(4, 16), 256, 0, stream>>>(pb, m2, 2048, 256);
  k_w1 <<<2048, 256, 0, stream>>>(p, idx, pW1, pb1, pg1, pbe1, pW2, pb2,
                                  wg1, wbe1, wW1, wb1, xq, xk, w1ws, m1, m2);
  k_bn3<<<256, 256, 0, stream>>>(w1ws, pc);
  k_finA<<<dim3(1, 16), 256, 0, stream>>>(pc, m3, 256, 32);
  k_out<<<2048, 256, 0, stream>>>(p, idx, pW1, pb1, pg1, pbe1, pW2, pb2,
                                  wg2, wbe2, wW2, wb2, xv, w1ws, m1, m3,
                                  (float*)d_out);
}

// Round 7
// 265.844 us; speedup vs baseline: 8.8268x; 1.1553x over previous
//
#include <hip/hip_runtime.h>

typedef unsigned short u16;
#define DEV __device__ __forceinline__

typedef short bf16x8 __attribute__((ext_vector_type(8)));
typedef float f32x4  __attribute__((ext_vector_type(4)));

constexpr int NP = 32768;
constexpr int C  = 128;
constexpr int NS = 16;
constexpr int RTOT = NP * NS;              // 524288 rows of [N,NS]
constexpr float EPS = 1e-5f;
constexpr float INV_R = 1.0f / (float)RTOT;

// ---- workspace layout (bytes) ----
// Proven (round 1 ran): ws_size >= 42117120.
constexpr size_t oXQ = 0;                              // xq/xk/xv bf16: 3*8MB
constexpr size_t oXK = (size_t)NP * C * 2;             // 8388608
constexpr size_t oXV = oXK * 2;
constexpr size_t oW1 = oXK * 3;                        // w1 logits bf16: 16MB
// partials1/2 alias INTO the w1out region (dead before k_w1 overwrites it):
constexpr size_t oPA = oW1;                            // pa [512][8] f32
constexpr size_t oPB = oW1 + 16384;                    // pb [2048][256] f32 = 2MB
// mid-stage sums + bn3 partials live AFTER w1out (must survive k_w1):
constexpr size_t oST = oW1 + (size_t)RTOT * 16 * 2;    // 41943040
constexpr size_t oM1 = oST;                            // mid1[16][8]
constexpr size_t oM2 = oM1 + 16*8*4;                   // mid2[16][256]
constexpr size_t oM3 = oM2 + 16*256*4;                 // mid3[16][32]
constexpr size_t oPC = oM3 + 16*32*4;                  // pc [256][32]
constexpr size_t WS_NEED = oPC + 256*32*4;             // 41994752 < 42117120 proven

DEV float bu2f(u16 v){ return __uint_as_float(((unsigned)v) << 16); }
DEV u16 f2bu(float f){
  unsigned u = __float_as_uint(f);
  return (u16)((u + 0x7fffu + ((u >> 16) & 1u)) >> 16);   // RNE
}
DEV unsigned pk2(float a, float b){ return (unsigned)f2bu(a) | ((unsigned)f2bu(b) << 16); }
DEV unsigned pk2tr(float a, float b){   // truncating bf16 pack (staging only)
  return (__float_as_uint(a) >> 16) | (__float_as_uint(b) & 0xffff0000u);
}
DEV void b2x2(unsigned v, float& lo, float& hi){
  lo = __uint_as_float(v << 16);
  hi = __uint_as_float(v & 0xffff0000u);
}
DEV int clampg(int g){ return g < 0 ? 0 : (g > NP-1 ? NP-1 : g); }

// ---------------- diagnostics ----------------
__global__ __launch_bounds__(256) void k_sig(float* __restrict__ out, float val){
  int i = blockIdx.x * 256 + threadIdx.x;
  if (i < NP*C) out[i] = val;
}

// ---------------- stage-1 partial reduce: mid[y][ch] = sum of slot chunk --
__global__ __launch_bounds__(256) void k_finA(const float* __restrict__ part,
                                              float* __restrict__ mid,
                                              int slots, int width){
  __shared__ float red[4][64];
  const int l = threadIdx.x & 63, w = threadIdx.x >> 6;
  const int ch = blockIdx.x * 64 + l;
  const int y = blockIdx.y;
  const int cs = slots >> 4;           // 16 slot-groups
  const int n4 = cs >> 2;              // per-wave slot count
  float a0 = 0.f, a1 = 0.f, a2 = 0.f, a3 = 0.f;
  if (ch < width){
    const float* base = part + (size_t)(y*cs + w*n4) * width + ch;
    int j = 0;
    for (; j + 4 <= n4; j += 4){
      a0 += base[(size_t)(j  ) * width];
      a1 += base[(size_t)(j+1) * width];
      a2 += base[(size_t)(j+2) * width];
      a3 += base[(size_t)(j+3) * width];
    }
    for (; j < n4; ++j) a0 += base[(size_t)j * width];
  }
  red[w][l] = (a0 + a1) + (a2 + a3);
  __syncthreads();
  if (threadIdx.x < 64 && ch < width)
    mid[(size_t)y * width + ch] = red[0][l] + red[1][l] + red[2][l] + red[3][l];
}

// ---------------- QKV GEMM (fp32, W staged in LDS, 4 rows x 8 cols/thread)
__global__ __launch_bounds__(256) void k_qkv(const float* __restrict__ x,
                                             const float* __restrict__ Wq,
                                             const float* __restrict__ Wk,
                                             const float* __restrict__ Wv,
                                             const float* __restrict__ bq,
                                             const float* __restrict__ bk,
                                             const float* __restrict__ bv,
                                             u16* __restrict__ outw){
  __shared__ __align__(16) float Wl[128*128];   // 64 KB
  const int t = threadIdx.x;
  const int mat = blockIdx.y;
  const float* W    = (mat==0) ? Wq : ((mat==1) ? Wk : Wv);
  const float* bias = (mat==0) ? bq : ((mat==1) ? bk : bv);
  u16* outp = outw + (size_t)mat * NP * C;

  {
    const float4* Ws4 = (const float4*)W;
    float4* Wl4 = (float4*)Wl;
    #pragma unroll
    for (int i = 0; i < 16; ++i) Wl4[t + i*256] = Ws4[t + i*256];
  }
  __syncthreads();

  const int tr = t >> 4, cg = t & 15;
  const int row0 = blockIdx.x * 64 + tr * 4;
  float acc[4][8];
  #pragma unroll
  for (int j = 0; j < 8; ++j){
    float bj = bias[cg*8 + j];
    #pragma unroll
    for (int rr = 0; rr < 4; ++rr) acc[rr][j] = bj;
  }
  const float4* Wl4 = (const float4*)Wl;
  for (int k0 = 0; k0 < 128; k0 += 4){
    float4 xa[4];
    #pragma unroll
    for (int rr = 0; rr < 4; ++rr)
      xa[rr] = *(const float4*)(x + (size_t)(row0+rr)*C + k0);
    #pragma unroll
    for (int u = 0; u < 4; ++u){
      float4 w0 = Wl4[(k0+u)*32 + cg*2];
      float4 w1 = Wl4[(k0+u)*32 + cg*2 + 1];
      #pragma unroll
      for (int rr = 0; rr < 4; ++rr){
        float a = (&xa[rr].x)[u];
        acc[rr][0] = fmaf(a, w0.x, acc[rr][0]);
        acc[rr][1] = fmaf(a, w0.y, acc[rr][1]);
        acc[rr][2] = fmaf(a, w0.z, acc[rr][2]);
        acc[rr][3] = fmaf(a, w0.w, acc[rr][3]);
        acc[rr][4] = fmaf(a, w1.x, acc[rr][4]);
        acc[rr][5] = fmaf(a, w1.y, acc[rr][5]);
        acc[rr][6] = fmaf(a, w1.z, acc[rr][6]);
        acc[rr][7] = fmaf(a, w1.w, acc[rr][7]);
      }
    }
  }
  #pragma unroll
  for (int rr = 0; rr < 4; ++rr){
    uint4 pkd;
    #pragma unroll
    for (int q2 = 0; q2 < 4; ++q2)
      (&pkd.x)[q2] = pk2(acc[rr][q2*2], acc[rr][q2*2+1]);
    *(uint4*)(outp + (size_t)(row0+rr)*C + cg*8) = pkd;
  }
}

// ---------------- bn1 stats -> per-block partials (no atomics) ----------
__global__ __launch_bounds__(256) void k_bn1(const float* __restrict__ p,
                                             const int* __restrict__ idx,
                                             const float* __restrict__ pW1,
                                             const float* __restrict__ pb1,
                                             float* __restrict__ partials1){
  __shared__ float wred[4][8];
  const int t = threadIdx.x;
  float w[9], b3[3];
  #pragma unroll
  for (int i = 0; i < 9; ++i) w[i] = pW1[i];
  #pragma unroll
  for (int i = 0; i < 3; ++i) b3[i] = pb1[i];
  float s[3] = {0,0,0}, q[3] = {0,0,0};
  const int base = blockIdx.x * 1024 + t;
  #pragma unroll
  for (int i = 0; i < 4; ++i){
    int r = base + i*256;
    int g = clampg(idx[r]);
    int n = r >> 4;
    float d0 = p[3*g]   - p[3*n];
    float d1 = p[3*g+1] - p[3*n+1];
    float d2 = p[3*g+2] - p[3*n+2];
    #pragma unroll
    for (int k = 0; k < 3; ++k){
      float tv = d0*w[k] + d1*w[3+k] + d2*w[6+k] + b3[k];
      s[k] += tv; q[k] = fmaf(tv, tv, q[k]);
    }
  }
  #pragma unroll
  for (int k = 0; k < 3; ++k){
    #pragma unroll
    for (int m = 1; m < 64; m <<= 1){
      s[k] += __shfl_xor(s[k], m);
      q[k] += __shfl_xor(q[k], m);
    }
  }
  if ((t & 63) == 0){
    int wv = t >> 6;
    wred[wv][0] = s[0]; wred[wv][1] = s[1]; wred[wv][2] = s[2]; wred[wv][3] = 0.f;
    wred[wv][4] = q[0]; wred[wv][5] = q[1]; wred[wv][6] = q[2]; wred[wv][7] = 0.f;
  }
  __syncthreads();
  if (t < 8)
    partials1[blockIdx.x*8 + t] = wred[0][t] + wred[1][t] + wred[2][t] + wred[3][t];
}

// ---------------- bn2 stats: wave-per-row uint gather, high occupancy ---
__global__ __launch_bounds__(256) void k_bn2(const float* __restrict__ p,
                                             const int* __restrict__ idx,
                                             const float* __restrict__ pW1,
                                             const float* __restrict__ pb1,
                                             const float* __restrict__ pg1,
                                             const float* __restrict__ pbe1,
                                             const float* __restrict__ pW2,
                                             const float* __restrict__ pb2,
                                             const u16* __restrict__ xq,
                                             const u16* __restrict__ xk,
                                             const float* __restrict__ mid1,
                                             float* __restrict__ partials2){
  __shared__ float sq0[64], sq1[64], sq2[64];
  __shared__ int   sgi[64];
  __shared__ __align__(16) float4 pW2t[128];
  __shared__ float bn1s[8];
  __shared__ __align__(16) float redS[4][128], redQ[4][128];
  const int t = threadIdx.x;
  if (t < 3){
    float sv = 0.f, sq = 0.f;
    for (int i = 0; i < 16; ++i){ sv += mid1[i*8+t]; sq += mid1[i*8+4+t]; }
    float mu = sv * INV_R, var = sq * INV_R - mu*mu;
    float rs = rsqrtf(var + EPS);
    float sc = rs * pg1[t];
    bn1s[t]   = sc;
    bn1s[4+t] = pb1[t] * sc + pbe1[t] - mu * sc;
  }
  if (t < 128)
    pW2t[t] = make_float4(pW2[t], pW2[128+t], pW2[256+t], pb2[t]);
  float w9[9];
  if (t < 64){
    #pragma unroll
    for (int i = 0; i < 9; ++i) w9[i] = pW1[i];
  }
  __syncthreads();
  const int w = t >> 6, l = t & 63;
  const float4 pwA = pW2t[2*l], pwB = pW2t[2*l+1];
  float sA = 0.f, qA = 0.f, sB = 0.f, qB = 0.f;

  for (int tile = 0; tile < 4; ++tile){
    const int b0 = (blockIdx.x * 4 + tile) * 64;
    if (t < 64){
      int r = b0 + t, n = r >> 4;
      int g = clampg(idx[r]);
      float d0 = p[3*g]   - p[3*n];
      float d1 = p[3*g+1] - p[3*n+1];
      float d2 = p[3*g+2] - p[3*n+2];
      sq0[t] = fmaxf((d0*w9[0] + d1*w9[3] + d2*w9[6]) * bn1s[0] + bn1s[4], 0.f);
      sq1[t] = fmaxf((d0*w9[1] + d1*w9[4] + d2*w9[7]) * bn1s[1] + bn1s[5], 0.f);
      sq2[t] = fmaxf((d0*w9[2] + d1*w9[5] + d2*w9[8]) * bn1s[2] + bn1s[6], 0.f);
      sgi[t] = g;
    }
    __syncthreads();
    #pragma unroll
    for (int pt = 0; pt < 4; ++pt){
      const int n = (b0 >> 4) + pt;
      unsigned qx = *(const unsigned*)(xq + (size_t)n*C + 2*l);
      float xqA, xqB; b2x2(qx, xqA, xqB);
      #pragma unroll
      for (int k = 0; k < 4; ++k){
        int rr = pt*16 + w + k*4;
        int g = sgi[rr];
        unsigned kx = *(const unsigned*)(xk + (size_t)g*C + 2*l);
        float xkA, xkB; b2x2(kx, xkA, xkB);
        float prA = sq0[rr]*pwA.x + sq1[rr]*pwA.y + sq2[rr]*pwA.z + pwA.w;
        float prB = sq0[rr]*pwB.x + sq1[rr]*pwB.y + sq2[rr]*pwB.z + pwB.w;
        float w0A = xkA - xqA + prA;
        float w0B = xkB - xqB + prB;
        sA += w0A; qA = fmaf(w0A, w0A, qA);
        sB += w0B; qB = fmaf(w0B, w0B, qB);
      }
    }
    __syncthreads();
  }
  *(float2*)&redS[w][2*l] = make_float2(sA, sB);
  *(float2*)&redQ[w][2*l] = make_float2(qA, qB);
  __syncthreads();
  if (t < 128){
    partials2[(size_t)blockIdx.x*256 + t]       = redS[0][t]+redS[1][t]+redS[2][t]+redS[3][t];
    partials2[(size_t)blockIdx.x*256 + 128 + t] = redQ[0][t]+redQ[1][t]+redQ[2][t]+redQ[3][t];
  }
}

// ---------------- w1 = relu(bn2(w0)) @ wW1 + wb1 ; MFMA phase C ---------
// Phase A: pr-q per row. Phase B: wave-per-row uint gather -> h (bf16) in
// LDS (pad 136 keeps b128 16B-aligned). Phase C: per wave 16x16 D-tile via
// 4x mfma_f32_16x16x32_bf16; B-frag (wW1 bf16) in registers.
__global__ __launch_bounds__(256) void k_w1(const float* __restrict__ p,
                                            const int* __restrict__ idx,
                                            const float* __restrict__ pW1,
                                            const float* __restrict__ pb1,
                                            const float* __restrict__ pg1,
                                            const float* __restrict__ pbe1,
                                            const float* __restrict__ pW2,
                                            const float* __restrict__ pb2,
                                            const float* __restrict__ wg1,
                                            const float* __restrict__ wbe1,
                                            const float* __restrict__ wW1,
                                            const float* __restrict__ wb1,
                                            const u16* __restrict__ xq,
                                            const u16* __restrict__ xk,
                                            u16* __restrict__ w1out,
                                            const float* __restrict__ mid1,
                                            const float* __restrict__ mid2){
  __shared__ __align__(16) float4 pW2t[128];
  __shared__ float2 ss2[128];
  __shared__ float bn1s[8];
  __shared__ float wb1f[16];
  __shared__ float pW1f[9];
  __shared__ float sq0[64], sq1[64], sq2[64];
  __shared__ int   sgi[64];
  __shared__ __align__(16) u16 hsb[64*136];   // bf16 h, 17.4 KB, pad 136
  const int t = threadIdx.x;
  if (t < 3){
    float sv = 0.f, sq = 0.f;
    for (int i = 0; i < 16; ++i){ sv += mid1[i*8+t]; sq += mid1[i*8+4+t]; }
    float mu = sv * INV_R, var = sq * INV_R - mu*mu;
    float rs = rsqrtf(var + EPS);
    float sc = rs * pg1[t];
    bn1s[t]   = sc;
    bn1s[4+t] = pb1[t] * sc + pbe1[t] - mu * sc;
  }
  if (t < 9)  pW1f[t] = pW1[t];
  if (t < 16) wb1f[t] = wb1[t];
  if (t < 128){
    pW2t[t] = make_float4(pW2[t], pW2[128+t], pW2[256+t], pb2[t]);
    float sv = 0.f, sq = 0.f;
    for (int i = 0; i < 16; ++i){ sv += mid2[i*256+t]; sq += mid2[i*256+128+t]; }
    float mu = sv * INV_R, var = sq * INV_R - mu*mu;
    float rs = rsqrtf(var + EPS);
    float sc = rs * wg1[t];
    ss2[t] = make_float2(sc, wbe1[t] - mu * sc);
  }

  const int w = t >> 6, l = t & 63;
  const int quad = l >> 4, col = l & 15;
  // B-fragment: wW1[k][o] bf16; lane l holds o=col, k=kk*32+quad*8+j
  bf16x8 bfrag[4];
  #pragma unroll
  for (int kk = 0; kk < 4; ++kk){
    #pragma unroll
    for (int j = 0; j < 8; ++j)
      bfrag[kk][j] = (short)f2bu(wW1[(size_t)(kk*32 + quad*8 + j)*16 + col]);
  }
  __syncthreads();

  const float4 pwA = pW2t[2*l], pwB = pW2t[2*l+1];
  const float2 scA = ss2[2*l],  scB = ss2[2*l+1];
  const float biasC = wb1f[col];

  for (int tile = 0; tile < 4; ++tile){
    const int rb = (blockIdx.x * 4 + tile) * 64;
    // phase A
    if (t < 64){
      int r = rb + t, n = r >> 4;
      int g = clampg(idx[r]);
      float d0 = p[3*g]   - p[3*n];
      float d1 = p[3*g+1] - p[3*n+1];
      float d2 = p[3*g+2] - p[3*n+2];
      sq0[t] = fmaxf((d0*pW1f[0] + d1*pW1f[3] + d2*pW1f[6]) * bn1s[0] + bn1s[4], 0.f);
      sq1[t] = fmaxf((d0*pW1f[1] + d1*pW1f[4] + d2*pW1f[7]) * bn1s[1] + bn1s[5], 0.f);
      sq2[t] = fmaxf((d0*pW1f[2] + d1*pW1f[5] + d2*pW1f[8]) * bn1s[2] + bn1s[6], 0.f);
      sgi[t] = g;
    }
    __syncthreads();
    // phase B: wave-per-row uint gather -> h bf16 (truncating pack)
    #pragma unroll
    for (int pt = 0; pt < 4; ++pt){
      const int n = (rb >> 4) + pt;
      unsigned qx = *(const unsigned*)(xq + (size_t)n*C + 2*l);
      float xqA, xqB; b2x2(qx, xqA, xqB);
      #pragma unroll
      for (int k = 0; k < 4; ++k){
        int rr = pt*16 + w + k*4;
        int g = sgi[rr];
        unsigned kx = *(const unsigned*)(xk + (size_t)g*C + 2*l);
        float xkA, xkB; b2x2(kx, xkA, xkB);
        float prA = sq0[rr]*pwA.x + sq1[rr]*pwA.y + sq2[rr]*pwA.z + pwA.w;
        float prB = sq0[rr]*pwB.x + sq1[rr]*pwB.y + sq2[rr]*pwB.z + pwB.w;
        float hA = fmaxf(fmaf(xkA - xqA + prA, scA.x, scA.y), 0.f);
        float hB = fmaxf(fmaf(xkB - xqB + prB, scB.x, scB.y), 0.f);
        *(unsigned*)&hsb[rr*136 + 2*l] = pk2tr(hA, hB);
      }
    }
    __syncthreads();
    // phase C: wave w computes rows [w*16, w*16+16) x 16 outs via MFMA
    f32x4 acc;
    acc[0] = biasC; acc[1] = biasC; acc[2] = biasC; acc[3] = biasC;
    const u16* hbase = &hsb[(size_t)(w*16 + col) * 136];
    #pragma unroll
    for (int kk = 0; kk < 4; ++kk){
      bf16x8 af = *(const bf16x8*)(hbase + kk*32 + quad*8);
      acc = __builtin_amdgcn_mfma_f32_16x16x32_bf16(af, bfrag[kk], acc, 0, 0, 0);
    }
    #pragma unroll
    for (int i = 0; i < 4; ++i){
      int row = w*16 + quad*4 + i;
      w1out[(size_t)(rb + row) * 16 + col] = f2bu(acc[i]);
    }
    __syncthreads();
  }
}

// ---------------- bn3 stats: coalesced pass over w1 logits --------------
__global__ __launch_bounds__(256) void k_bn3(const u16* __restrict__ w1ws,
                                             float* __restrict__ partials3){
  __shared__ float rs[256][8], rq[256][8];
  const int t = threadIdx.x;
  float s[8], q[8];
  #pragma unroll
  for (int k = 0; k < 8; ++k){ s[k] = 0.f; q[k] = 0.f; }
  const uint4* w4 = (const uint4*)w1ws;
  const int base = blockIdx.x * 256 + t;
  #pragma unroll 4
  for (int it = 0; it < 16; ++it){
    uint4 v = w4[base + it * 65536];
    #pragma unroll
    for (int k = 0; k < 4; ++k){
      float lo, hi; b2x2((&v.x)[k], lo, hi);
      s[k*2]   += lo; q[k*2]   = fmaf(lo, lo, q[k*2]);
      s[k*2+1] += hi; q[k*2+1] = fmaf(hi, hi, q[k*2+1]);
    }
  }
  #pragma unroll
  for (int k = 0; k < 8; ++k){ rs[t][k] = s[k]; rq[t][k] = q[k]; }
  __syncthreads();
  if (t < 32){
    int isq = t >> 4, ch = t & 15;
    int par = ch >> 3, k = ch & 7;
    float acc = 0.f;
    if (isq){
      for (int i2 = par; i2 < 256; i2 += 2) acc += rq[i2][k];
    } else {
      for (int i2 = par; i2 < 256; i2 += 2) acc += rs[i2][k];
    }
    partials3[blockIdx.x*32 + isq*16 + ch] = acc;
  }
}

// ---------------- final: bn3 -> relu -> wW2 -> softmax(j) -> aggregate --
__global__ __launch_bounds__(256) void k_out(const float* __restrict__ p,
                                             const int* __restrict__ idx,
                                             const float* __restrict__ pW1,
                                             const float* __restrict__ pb1,
                                             const float* __restrict__ pg1,
                                             const float* __restrict__ pbe1,
                                             const float* __restrict__ pW2,
                                             const float* __restrict__ pb2,
                                             const float* __restrict__ wg2,
                                             const float* __restrict__ wbe2,
                                             const float* __restrict__ wW2,
                                             const float* __restrict__ wb2,
                                             const u16* __restrict__ xv,
                                             const u16* __restrict__ w1ws,
                                             const float* __restrict__ mid1,
                                             const float* __restrict__ mid3,
                                             float* __restrict__ out){
  __shared__ __align__(16) float4 pW2t[128];
  __shared__ float pW1f[9];
  __shared__ float bn1s[8];
  __shared__ float sc3[16], sh3[16], wb2f[16];
  __shared__ float wW2f[256];
  __shared__ float s_w2[16*16*16];
  __shared__ float s_q0[256], s_q1[256], s_q2[256];
  __shared__ int   s_g[256];
  const int t = threadIdx.x;
  if (t < 3){
    float sv = 0.f, sq = 0.f;
    for (int i = 0; i < 16; ++i){ sv += mid1[i*8+t]; sq += mid1[i*8+4+t]; }
    float mu = sv * INV_R, var = sq * INV_R - mu*mu;
    float rs = rsqrtf(var + EPS);
    float sc = rs * pg1[t];
    bn1s[t]   = sc;
    bn1s[4+t] = pb1[t] * sc + pbe1[t] - mu * sc;
  }
  if (t < 9) pW1f[t] = pW1[t];
  if (t < 16){
    float sv = 0.f, sq = 0.f;
    for (int i = 0; i < 16; ++i){ sv += mid3[i*32+t]; sq += mid3[i*32+16+t]; }
    float mu = sv * INV_R, var = sq * INV_R - mu*mu;
    float rs = rsqrtf(var + EPS);
    float sc = rs * wg2[t];
    sc3[t] = sc;
    sh3[t] = wbe2[t] - mu * sc;
    wb2f[t] = wb2[t];
  }
  if (t < 128)
    pW2t[t] = make_float4(pW2[t], pW2[128+t], pW2[256+t], pb2[t]);
  wW2f[t] = wW2[t];
  __syncthreads();

  const int pt = t >> 4;
  const int jj = t & 15;
  const int n0 = blockIdx.x * 16;
  {
    const int n = n0 + pt;
    const int r = n * NS + jj;
    const int g = clampg(idx[r]);
    float d0 = p[3*g]   - p[3*n];
    float d1 = p[3*g+1] - p[3*n+1];
    float d2 = p[3*g+2] - p[3*n+2];
    s_q0[t] = fmaxf((d0*pW1f[0] + d1*pW1f[3] + d2*pW1f[6]) * bn1s[0] + bn1s[4], 0.f);
    s_q1[t] = fmaxf((d0*pW1f[1] + d1*pW1f[4] + d2*pW1f[7]) * bn1s[1] + bn1s[5], 0.f);
    s_q2[t] = fmaxf((d0*pW1f[2] + d1*pW1f[5] + d2*pW1f[8]) * bn1s[2] + bn1s[6], 0.f);
    s_g[t]  = g;
    const uint4* wp = (const uint4*)(w1ws + (size_t)r * 16);
    uint4 Wa = wp[0], Wb = wp[1];
    float h2[16];
    #pragma unroll
    for (int o2 = 0; o2 < 4; ++o2){
      float lo, hi;
      b2x2((&Wa.x)[o2], lo, hi);
      h2[o2*2]     = fmaxf(lo * sc3[o2*2]     + sh3[o2*2],     0.f);
      h2[o2*2+1]   = fmaxf(hi * sc3[o2*2+1]   + sh3[o2*2+1],   0.f);
      b2x2((&Wb.x)[o2], lo, hi);
      h2[8+o2*2]   = fmaxf(lo * sc3[8+o2*2]   + sh3[8+o2*2],   0.f);
      h2[8+o2*2+1] = fmaxf(hi * sc3[8+o2*2+1] + sh3[8+o2*2+1], 0.f);
    }
    float w2[16];
    #pragma unroll
    for (int o = 0; o < 16; ++o) w2[o] = wb2f[o];
    #pragma unroll
    for (int o2 = 0; o2 < 16; ++o2){
      float h = h2[o2];
      const float* wr = &wW2f[o2*16];
      #pragma unroll
      for (int o = 0; o < 16; ++o) w2[o] = fmaf(h, wr[o], w2[o]);
    }
    float* dst = &s_w2[(pt*16 + jj)*16];
    #pragma unroll
    for (int o = 0; o < 16; ++o) dst[o] = w2[o];
  }
  __syncthreads();
  const int cs = t & 15;
  {
    float mx = -1e30f;
    #pragma unroll
    for (int j2 = 0; j2 < 16; ++j2) mx = fmaxf(mx, s_w2[(pt*16+j2)*16 + cs]);
    float e[16]; float sum = 0.f;
    #pragma unroll
    for (int j2 = 0; j2 < 16; ++j2){
      e[j2] = __expf(s_w2[(pt*16+j2)*16 + cs] - mx);
      sum += e[j2];
    }
    float inv = 1.0f / sum;
    #pragma unroll
    for (int j2 = 0; j2 < 16; ++j2) s_w2[(pt*16+j2)*16 + cs] = e[j2] * inv;
  }
  __syncthreads();
  // aggregation: wave-per-point, lane covers channels 2l, 2l+1 (uint loads)
  const int w = t >> 6, l = t & 63;
  const float4 pwA = pW2t[2*l], pwB = pW2t[2*l+1];
  const int csA = (2*l) & 15;
  #pragma unroll
  for (int pp = 0; pp < 4; ++pp){
    const int pt2 = pp * 4 + w;
    const int n = n0 + pt2;
    float accA = 0.f, accB = 0.f;
    #pragma unroll
    for (int j = 0; j < 16; ++j){
      const int base = pt2*16 + j;
      float2 pj2 = *(const float2*)&s_w2[base*16 + csA];
      int g = s_g[base];
      float qa = s_q0[base], qb = s_q1[base], qc = s_q2[base];
      unsigned v = *(const unsigned*)(xv + (size_t)g*C + 2*l);
      float xvA, xvB; b2x2(v, xvA, xvB);
      float prA = qa*pwA.x + qb*pwA.y + qc*pwA.z + pwA.w;
      float prB = qa*pwB.x + qb*pwB.y + qc*pwB.z + pwB.w;
      accA = fmaf(xvA + prA, pj2.x, accA);
      accB = fmaf(xvB + prB, pj2.y, accB);
    }
    *(float2*)(out + (size_t)n*C + 2*l) = make_float2(accA, accB);
  }
}

extern "C" void kernel_launch(void* const* d_in, const int* in_sizes, int n_in,
                              void* d_out, int out_size, void* d_ws, size_t ws_size,
                              hipStream_t stream) {
  bool ok = (n_in == 23) && (out_size == NP*C) &&
            in_sizes[0] == NP*3 && in_sizes[1] == NP*C &&
            in_sizes[2] == C*C  && in_sizes[8] == 9 &&
            in_sizes[12] == 3*C && in_sizes[16] == C*(C/8) &&
            in_sizes[20] == (C/8)*(C/8) && in_sizes[22] == RTOT;
  if (!ok){
    k_sig<<<(NP*C+255)/256, 256, 0, stream>>>((float*)d_out, 10000.0f);
    return;
  }
  if (ws_size < WS_NEED){
    k_sig<<<(NP*C+255)/256, 256, 0, stream>>>((float*)d_out, 20000.0f);
    return;
  }
  const float* p    = (const float*)d_in[0];
  const float* x    = (const float*)d_in[1];
  const float* Wq   = (const float*)d_in[2];
  const float* bq   = (const float*)d_in[3];
  const float* Wk   = (const float*)d_in[4];
  const float* bk   = (const float*)d_in[5];
  const float* Wv   = (const float*)d_in[6];
  const float* bv   = (const float*)d_in[7];
  const float* pW1  = (const float*)d_in[8];
  const float* pb1  = (const float*)d_in[9];
  const float* pg1  = (const float*)d_in[10];
  const float* pbe1 = (const float*)d_in[11];
  const float* pW2  = (const float*)d_in[12];
  const float* pb2  = (const float*)d_in[13];
  const float* wg1  = (const float*)d_in[14];
  const float* wbe1 = (const float*)d_in[15];
  const float* wW1  = (const float*)d_in[16];
  const float* wb1  = (const float*)d_in[17];
  const float* wg2  = (const float*)d_in[18];
  const float* wbe2 = (const float*)d_in[19];
  const float* wW2  = (const float*)d_in[20];
  const float* wb2  = (const float*)d_in[21];
  const int* idx    = (const int*)d_in[22];

  char* ws = (char*)d_ws;
  u16* xq    = (u16*)(ws + oXQ);
  u16* xk    = (u16*)(ws + oXK);
  u16* xv    = (u16*)(ws + oXV);
  u16* w1ws  = (u16*)(ws + oW1);
  float* pa  = (float*)(ws + oPA);
  float* pb  = (float*)(ws + oPB);
  float* pc  = (float*)(ws + oPC);
  float* m1  = (float*)(ws + oM1);
  float* m2  = (float*)(ws + oM2);
  float* m3  = (float*)(ws + oM3);

  k_qkv<<<dim3(512, 3), 256, 0, stream>>>(x, Wq, Wk, Wv, bq, bk, bv, xq);
  k_bn1<<<512, 256, 0, stream>>>(p, idx, pW1, pb1, pa);
  k_finA<<<dim3(1, 16), 256, 0, stream>>>(pa, m1, 512, 8);
  k_bn2<<<2048, 256, 0, stream>>>(p, idx, pW1, pb1, pg1, pbe1, pW2, pb2,
                                  xq, xk, m1, pb);
  k_finA<<<dim3(4, 16), 256, 0, stream>>>(pb, m2, 2048, 256);
  k_w1 <<<2048, 256, 0, stream>>>(p, idx, pW1, pb1, pg1, pbe1, pW2, pb2,
                                  wg1, wbe1, wW1, wb1, xq, xk, w1ws, m1, m2);
  k_bn3<<<256, 256, 0, stream>>>(w1ws, pc);
  k_finA<<<dim3(1, 16), 256, 0, stream>>>(pc, m3, 256, 32);
  k_out<<<2048, 256, 0, stream>>>(p, idx, pW1, pb1, pg1, pbe1, pW2, pb2,
                                  wg2, wbe2, wW2, wb2, xv, w1ws, m1, m3,
                                  (float*)d_out);
}

// Round 8
// 231.735 us; speedup vs baseline: 10.1259x; 1.1472x over previous
//
#include <hip/hip_runtime.h>

typedef unsigned short u16;
#define DEV __device__ __forceinline__

typedef short bf16x8 __attribute__((ext_vector_type(8)));
typedef float f32x4  __attribute__((ext_vector_type(4)));

constexpr int NP = 32768;
constexpr int C  = 128;
constexpr int NS = 16;
constexpr int RTOT = NP * NS;              // 524288 rows of [N,NS]
constexpr float EPS = 1e-5f;
constexpr float INV_R = 1.0f / (float)RTOT;

// ---- workspace layout (bytes) ----
// Proven (round 1 ran): ws_size >= 42117120.
constexpr size_t oXQ = 0;                              // xq/xk/xv bf16: 3*8MB
constexpr size_t oXK = (size_t)NP * C * 2;             // 8388608
constexpr size_t oXV = oXK * 2;
constexpr size_t oW1 = oXK * 3;                        // w1 logits bf16: 16MB
// partials1/2 alias INTO the w1out region (dead before k_w1 overwrites it):
constexpr size_t oPA = oW1;                            // pa [512][8] f32
constexpr size_t oPB = oW1 + 16384;                    // pb [2048][256] f32 = 2MB
// mid-stage sums + bn3 partials + Wt live AFTER w1out (survive k_w1):
constexpr size_t oST = oW1 + (size_t)RTOT * 16 * 2;    // 41943040
constexpr size_t oM1 = oST;                            // mid1[16][8]
constexpr size_t oM2 = oM1 + 16*8*4;                   // mid2[16][256]
constexpr size_t oM3 = oM2 + 16*256*4;                 // mid3[16][32]
constexpr size_t oPC = oM3 + 16*32*4;                  // pc [256][32]
constexpr size_t oWT = oPC + 256*32*4;                 // Wt bf16 [3][128][128]
constexpr size_t WS_NEED = oWT + 3*128*128*2;          // 42093056 < 42117120 proven

DEV float bu2f(u16 v){ return __uint_as_float(((unsigned)v) << 16); }
DEV u16 f2bu(float f){
  unsigned u = __float_as_uint(f);
  return (u16)((u + 0x7fffu + ((u >> 16) & 1u)) >> 16);   // RNE
}
DEV unsigned pk2(float a, float b){ return (unsigned)f2bu(a) | ((unsigned)f2bu(b) << 16); }
DEV unsigned pk2tr(float a, float b){   // truncating bf16 pack (staging only)
  return (__float_as_uint(a) >> 16) | (__float_as_uint(b) & 0xffff0000u);
}
DEV void b2x2(unsigned v, float& lo, float& hi){
  lo = __uint_as_float(v << 16);
  hi = __uint_as_float(v & 0xffff0000u);
}
DEV int clampg(int g){ return g < 0 ? 0 : (g > NP-1 ? NP-1 : g); }

// ---------------- diagnostics ----------------
__global__ __launch_bounds__(256) void k_sig(float* __restrict__ out, float val){
  int i = blockIdx.x * 256 + threadIdx.x;
  if (i < NP*C) out[i] = val;
}

// ---------------- stage-1 partial reduce: mid[y][ch] = sum of slot chunk --
__global__ __launch_bounds__(256) void k_finA(const float* __restrict__ part,
                                              float* __restrict__ mid,
                                              int slots, int width){
  __shared__ float red[4][64];
  const int l = threadIdx.x & 63, w = threadIdx.x >> 6;
  const int ch = blockIdx.x * 64 + l;
  const int y = blockIdx.y;
  const int cs = slots >> 4;           // 16 slot-groups
  const int n4 = cs >> 2;              // per-wave slot count
  float a0 = 0.f, a1 = 0.f, a2 = 0.f, a3 = 0.f;
  if (ch < width){
    const float* base = part + (size_t)(y*cs + w*n4) * width + ch;
    int j = 0;
    for (; j + 4 <= n4; j += 4){
      a0 += base[(size_t)(j  ) * width];
      a1 += base[(size_t)(j+1) * width];
      a2 += base[(size_t)(j+2) * width];
      a3 += base[(size_t)(j+3) * width];
    }
    for (; j < n4; ++j) a0 += base[(size_t)j * width];
  }
  red[w][l] = (a0 + a1) + (a2 + a3);
  __syncthreads();
  if (threadIdx.x < 64 && ch < width)
    mid[(size_t)y * width + ch] = red[0][l] + red[1][l] + red[2][l] + red[3][l];
}

// ---------------- Wt: transpose + bf16-convert Wq/Wk/Wv -----------------
__global__ __launch_bounds__(256) void k_wt(const float* __restrict__ Wq,
                                            const float* __restrict__ Wk,
                                            const float* __restrict__ Wv,
                                            u16* __restrict__ wt){
  const int mat = blockIdx.y;
  const float* W = (mat==0) ? Wq : ((mat==1) ? Wk : Wv);
  int e = blockIdx.x * 256 + threadIdx.x;     // 64 blocks * 256 = 16384
  int k = e >> 7, c = e & 127;
  wt[mat*16384 + c*128 + k] = f2bu(W[e]);
}

// ---------------- QKV GEMM via MFMA (bf16) ------------------------------
// 512 blocks x 64 rows. x tile -> LDS bf16 (pad 136: 16B-aligned, 2-way
// free). Per mat: Wt bf16 -> LDS, 4 waves x 16 rows, 8 col-tiles x 4 MFMA.
__global__ __launch_bounds__(256) void k_qkv(const float* __restrict__ x,
                                             const u16* __restrict__ wt,
                                             const float* __restrict__ bq,
                                             const float* __restrict__ bk,
                                             const float* __restrict__ bv,
                                             u16* __restrict__ outw){
  __shared__ __align__(16) u16 xb[64*136];     // 17.4 KB
  __shared__ __align__(16) u16 wtl[128*136];   // 34.8 KB
  const int t = threadIdx.x;
  const int row0 = blockIdx.x * 64;
  {
    const float4* xs = (const float4*)(x + (size_t)row0 * C);
    #pragma unroll
    for (int i = 0; i < 8; ++i){
      int chunk = t + i*256;            // 2048 float4 chunks
      int row = chunk >> 5;             // 32 float4 per row
      int cp  = (chunk & 31) * 4;
      float4 v = xs[chunk];
      *(uint2*)&xb[row*136 + cp] = make_uint2(pk2(v.x, v.y), pk2(v.z, v.w));
    }
  }
  __syncthreads();
  const int w = t >> 6, l = t & 63;
  const int quad = l >> 4, col = l & 15;
  bf16x8 afrag[4];
  {
    const u16* abase = &xb[(size_t)(w*16 + col) * 136];
    #pragma unroll
    for (int kk = 0; kk < 4; ++kk)
      afrag[kk] = *(const bf16x8*)(abase + kk*32 + quad*8);
  }
  for (int mat = 0; mat < 3; ++mat){
    const float* bias = (mat==0) ? bq : ((mat==1) ? bk : bv);
    {
      const uint4* ws4 = (const uint4*)(wt + mat*16384);
      #pragma unroll
      for (int i = 0; i < 8; ++i){
        int chunk = t + i*256;          // 2048 chunks of 8 bf16
        int c = chunk >> 4, kp = (chunk & 15) * 8;
        *(uint4*)&wtl[c*136 + kp] = ws4[chunk];
      }
    }
    __syncthreads();
    u16* outp = outw + (size_t)mat * NP * C + (size_t)(row0 + w*16) * C;
    #pragma unroll
    for (int ct = 0; ct < 8; ++ct){
      bf16x8 bfrag[4];
      const u16* bbase = &wtl[(size_t)(ct*16 + col) * 136];
      #pragma unroll
      for (int kk = 0; kk < 4; ++kk)
        bfrag[kk] = *(const bf16x8*)(bbase + kk*32 + quad*8);
      float bv0 = bias[ct*16 + col];
      f32x4 acc; acc[0] = bv0; acc[1] = bv0; acc[2] = bv0; acc[3] = bv0;
      #pragma unroll
      for (int kk = 0; kk < 4; ++kk)
        acc = __builtin_amdgcn_mfma_f32_16x16x32_bf16(afrag[kk], bfrag[kk], acc, 0, 0, 0);
      #pragma unroll
      for (int i = 0; i < 4; ++i)
        outp[(size_t)(quad*4 + i) * C + ct*16 + col] = f2bu(acc[i]);
    }
    __syncthreads();
  }
}

// ---------------- bn1 stats -> per-block partials (no atomics) ----------
__global__ __launch_bounds__(256) void k_bn1(const float* __restrict__ p,
                                             const int* __restrict__ idx,
                                             const float* __restrict__ pW1,
                                             const float* __restrict__ pb1,
                                             float* __restrict__ partials1){
  __shared__ float wred[4][8];
  const int t = threadIdx.x;
  float w[9], b3[3];
  #pragma unroll
  for (int i = 0; i < 9; ++i) w[i] = pW1[i];
  #pragma unroll
  for (int i = 0; i < 3; ++i) b3[i] = pb1[i];
  float s[3] = {0,0,0}, q[3] = {0,0,0};
  const int base = blockIdx.x * 1024 + t;
  #pragma unroll
  for (int i = 0; i < 4; ++i){
    int r = base + i*256;
    int g = clampg(idx[r]);
    int n = r >> 4;
    float d0 = p[3*g]   - p[3*n];
    float d1 = p[3*g+1] - p[3*n+1];
    float d2 = p[3*g+2] - p[3*n+2];
    #pragma unroll
    for (int k = 0; k < 3; ++k){
      float tv = d0*w[k] + d1*w[3+k] + d2*w[6+k] + b3[k];
      s[k] += tv; q[k] = fmaf(tv, tv, q[k]);
    }
  }
  #pragma unroll
  for (int k = 0; k < 3; ++k){
    #pragma unroll
    for (int m = 1; m < 64; m <<= 1){
      s[k] += __shfl_xor(s[k], m);
      q[k] += __shfl_xor(q[k], m);
    }
  }
  if ((t & 63) == 0){
    int wv = t >> 6;
    wred[wv][0] = s[0]; wred[wv][1] = s[1]; wred[wv][2] = s[2]; wred[wv][3] = 0.f;
    wred[wv][4] = q[0]; wred[wv][5] = q[1]; wred[wv][6] = q[2]; wred[wv][7] = 0.f;
  }
  __syncthreads();
  if (t < 8)
    partials1[blockIdx.x*8 + t] = wred[0][t] + wred[1][t] + wred[2][t] + wred[3][t];
}

// ---------------- bn2 stats: wave-per-row uint gather, high occupancy ---
__global__ __launch_bounds__(256) void k_bn2(const float* __restrict__ p,
                                             const int* __restrict__ idx,
                                             const float* __restrict__ pW1,
                                             const float* __restrict__ pb1,
                                             const float* __restrict__ pg1,
                                             const float* __restrict__ pbe1,
                                             const float* __restrict__ pW2,
                                             const float* __restrict__ pb2,
                                             const u16* __restrict__ xq,
                                             const u16* __restrict__ xk,
                                             const float* __restrict__ mid1,
                                             float* __restrict__ partials2){
  __shared__ float sq0[64], sq1[64], sq2[64];
  __shared__ int   sgi[64];
  __shared__ __align__(16) float4 pW2t[128];
  __shared__ float bn1s[8];
  __shared__ __align__(16) float redS[4][128], redQ[4][128];
  const int t = threadIdx.x;
  if (t < 3){
    float sv = 0.f, sq = 0.f;
    for (int i = 0; i < 16; ++i){ sv += mid1[i*8+t]; sq += mid1[i*8+4+t]; }
    float mu = sv * INV_R, var = sq * INV_R - mu*mu;
    float rs = rsqrtf(var + EPS);
    float sc = rs * pg1[t];
    bn1s[t]   = sc;
    bn1s[4+t] = pb1[t] * sc + pbe1[t] - mu * sc;
  }
  if (t < 128)
    pW2t[t] = make_float4(pW2[t], pW2[128+t], pW2[256+t], pb2[t]);
  float w9[9];
  if (t < 64){
    #pragma unroll
    for (int i = 0; i < 9; ++i) w9[i] = pW1[i];
  }
  __syncthreads();
  const int w = t >> 6, l = t & 63;
  const float4 pwA = pW2t[2*l], pwB = pW2t[2*l+1];
  float sA = 0.f, qA = 0.f, sB = 0.f, qB = 0.f;

  for (int tile = 0; tile < 4; ++tile){
    const int b0 = (blockIdx.x * 4 + tile) * 64;
    if (t < 64){
      int r = b0 + t, n = r >> 4;
      int g = clampg(idx[r]);
      float d0 = p[3*g]   - p[3*n];
      float d1 = p[3*g+1] - p[3*n+1];
      float d2 = p[3*g+2] - p[3*n+2];
      sq0[t] = fmaxf((d0*w9[0] + d1*w9[3] + d2*w9[6]) * bn1s[0] + bn1s[4], 0.f);
      sq1[t] = fmaxf((d0*w9[1] + d1*w9[4] + d2*w9[7]) * bn1s[1] + bn1s[5], 0.f);
      sq2[t] = fmaxf((d0*w9[2] + d1*w9[5] + d2*w9[8]) * bn1s[2] + bn1s[6], 0.f);
      sgi[t] = g;
    }
    __syncthreads();
    #pragma unroll
    for (int pt = 0; pt < 4; ++pt){
      const int n = (b0 >> 4) + pt;
      unsigned qx = *(const unsigned*)(xq + (size_t)n*C + 2*l);
      float xqA, xqB; b2x2(qx, xqA, xqB);
      #pragma unroll
      for (int k = 0; k < 4; ++k){
        int rr = pt*16 + w + k*4;
        int g = sgi[rr];
        unsigned kx = *(const unsigned*)(xk + (size_t)g*C + 2*l);
        float xkA, xkB; b2x2(kx, xkA, xkB);
        float prA = sq0[rr]*pwA.x + sq1[rr]*pwA.y + sq2[rr]*pwA.z + pwA.w;
        float prB = sq0[rr]*pwB.x + sq1[rr]*pwB.y + sq2[rr]*pwB.z + pwB.w;
        float w0A = xkA - xqA + prA;
        float w0B = xkB - xqB + prB;
        sA += w0A; qA = fmaf(w0A, w0A, qA);
        sB += w0B; qB = fmaf(w0B, w0B, qB);
      }
    }
    __syncthreads();
  }
  *(float2*)&redS[w][2*l] = make_float2(sA, sB);
  *(float2*)&redQ[w][2*l] = make_float2(qA, qB);
  __syncthreads();
  if (t < 128){
    partials2[(size_t)blockIdx.x*256 + t]       = redS[0][t]+redS[1][t]+redS[2][t]+redS[3][t];
    partials2[(size_t)blockIdx.x*256 + 128 + t] = redQ[0][t]+redQ[1][t]+redQ[2][t]+redQ[3][t];
  }
}

// ---------------- w1 = relu(bn2(w0)) @ wW1 + wb1 ; MFMA phase C ---------
__global__ __launch_bounds__(256) void k_w1(const float* __restrict__ p,
                                            const int* __restrict__ idx,
                                            const float* __restrict__ pW1,
                                            const float* __restrict__ pb1,
                                            const float* __restrict__ pg1,
                                            const float* __restrict__ pbe1,
                                            const float* __restrict__ pW2,
                                            const float* __restrict__ pb2,
                                            const float* __restrict__ wg1,
                                            const float* __restrict__ wbe1,
                                            const float* __restrict__ wW1,
                                            const float* __restrict__ wb1,
                                            const u16* __restrict__ xq,
                                            const u16* __restrict__ xk,
                                            u16* __restrict__ w1out,
                                            const float* __restrict__ mid1,
                                            const float* __restrict__ mid2){
  __shared__ __align__(16) float4 pW2t[128];
  __shared__ float2 ss2[128];
  __shared__ float bn1s[8];
  __shared__ float wb1f[16];
  __shared__ float pW1f[9];
  __shared__ float sq0[64], sq1[64], sq2[64];
  __shared__ int   sgi[64];
  __shared__ __align__(16) u16 hsb[64*136];   // bf16 h, 17.4 KB, pad 136
  const int t = threadIdx.x;
  if (t < 3){
    float sv = 0.f, sq = 0.f;
    for (int i = 0; i < 16; ++i){ sv += mid1[i*8+t]; sq += mid1[i*8+4+t]; }
    float mu = sv * INV_R, var = sq * INV_R - mu*mu;
    float rs = rsqrtf(var + EPS);
    float sc = rs * pg1[t];
    bn1s[t]   = sc;
    bn1s[4+t] = pb1[t] * sc + pbe1[t] - mu * sc;
  }
  if (t < 9)  pW1f[t] = pW1[t];
  if (t < 16) wb1f[t] = wb1[t];
  if (t < 128){
    pW2t[t] = make_float4(pW2[t], pW2[128+t], pW2[256+t], pb2[t]);
    float sv = 0.f, sq = 0.f;
    for (int i = 0; i < 16; ++i){ sv += mid2[i*256+t]; sq += mid2[i*256+128+t]; }
    float mu = sv * INV_R, var = sq * INV_R - mu*mu;
    float rs = rsqrtf(var + EPS);
    float sc = rs * wg1[t];
    ss2[t] = make_float2(sc, wbe1[t] - mu * sc);
  }

  const int w = t >> 6, l = t & 63;
  const int quad = l >> 4, col = l & 15;
  bf16x8 bfrag[4];
  #pragma unroll
  for (int kk = 0; kk < 4; ++kk){
    #pragma unroll
    for (int j = 0; j < 8; ++j)
      bfrag[kk][j] = (short)f2bu(wW1[(size_t)(kk*32 + quad*8 + j)*16 + col]);
  }
  __syncthreads();

  const float4 pwA = pW2t[2*l], pwB = pW2t[2*l+1];
  const float2 scA = ss2[2*l],  scB = ss2[2*l+1];
  const float biasC = wb1f[col];

  for (int tile = 0; tile < 4; ++tile){
    const int rb = (blockIdx.x * 4 + tile) * 64;
    if (t < 64){
      int r = rb + t, n = r >> 4;
      int g = clampg(idx[r]);
      float d0 = p[3*g]   - p[3*n];
      float d1 = p[3*g+1] - p[3*n+1];
      float d2 = p[3*g+2] - p[3*n+2];
      sq0[t] = fmaxf((d0*pW1f[0] + d1*pW1f[3] + d2*pW1f[6]) * bn1s[0] + bn1s[4], 0.f);
      sq1[t] = fmaxf((d0*pW1f[1] + d1*pW1f[4] + d2*pW1f[7]) * bn1s[1] + bn1s[5], 0.f);
      sq2[t] = fmaxf((d0*pW1f[2] + d1*pW1f[5] + d2*pW1f[8]) * bn1s[2] + bn1s[6], 0.f);
      sgi[t] = g;
    }
    __syncthreads();
    #pragma unroll
    for (int pt = 0; pt < 4; ++pt){
      const int n = (rb >> 4) + pt;
      unsigned qx = *(const unsigned*)(xq + (size_t)n*C + 2*l);
      float xqA, xqB; b2x2(qx, xqA, xqB);
      #pragma unroll
      for (int k = 0; k < 4; ++k){
        int rr = pt*16 + w + k*4;
        int g = sgi[rr];
        unsigned kx = *(const unsigned*)(xk + (size_t)g*C + 2*l);
        float xkA, xkB; b2x2(kx, xkA, xkB);
        float prA = sq0[rr]*pwA.x + sq1[rr]*pwA.y + sq2[rr]*pwA.z + pwA.w;
        float prB = sq0[rr]*pwB.x + sq1[rr]*pwB.y + sq2[rr]*pwB.z + pwB.w;
        float hA = fmaxf(fmaf(xkA - xqA + prA, scA.x, scA.y), 0.f);
        float hB = fmaxf(fmaf(xkB - xqB + prB, scB.x, scB.y), 0.f);
        *(unsigned*)&hsb[rr*136 + 2*l] = pk2tr(hA, hB);
      }
    }
    __syncthreads();
    f32x4 acc;
    acc[0] = biasC; acc[1] = biasC; acc[2] = biasC; acc[3] = biasC;
    const u16* hbase = &hsb[(size_t)(w*16 + col) * 136];
    #pragma unroll
    for (int kk = 0; kk < 4; ++kk){
      bf16x8 af = *(const bf16x8*)(hbase + kk*32 + quad*8);
      acc = __builtin_amdgcn_mfma_f32_16x16x32_bf16(af, bfrag[kk], acc, 0, 0, 0);
    }
    #pragma unroll
    for (int i = 0; i < 4; ++i){
      int row = w*16 + quad*4 + i;
      w1out[(size_t)(rb + row) * 16 + col] = f2bu(acc[i]);
    }
    __syncthreads();
  }
}

// ---------------- bn3 stats: coalesced pass over w1 logits --------------
__global__ __launch_bounds__(256) void k_bn3(const u16* __restrict__ w1ws,
                                             float* __restrict__ partials3){
  __shared__ float rs[256][8], rq[256][8];
  const int t = threadIdx.x;
  float s[8], q[8];
  #pragma unroll
  for (int k = 0; k < 8; ++k){ s[k] = 0.f; q[k] = 0.f; }
  const uint4* w4 = (const uint4*)w1ws;
  const int base = blockIdx.x * 256 + t;
  #pragma unroll 4
  for (int it = 0; it < 16; ++it){
    uint4 v = w4[base + it * 65536];
    #pragma unroll
    for (int k = 0; k < 4; ++k){
      float lo, hi; b2x2((&v.x)[k], lo, hi);
      s[k*2]   += lo; q[k*2]   = fmaf(lo, lo, q[k*2]);
      s[k*2+1] += hi; q[k*2+1] = fmaf(hi, hi, q[k*2+1]);
    }
  }
  #pragma unroll
  for (int k = 0; k < 8; ++k){ rs[t][k] = s[k]; rq[t][k] = q[k]; }
  __syncthreads();
  if (t < 32){
    int isq = t >> 4, ch = t & 15;
    int par = ch >> 3, k = ch & 7;
    float acc = 0.f;
    if (isq){
      for (int i2 = par; i2 < 256; i2 += 2) acc += rq[i2][k];
    } else {
      for (int i2 = par; i2 < 256; i2 += 2) acc += rs[i2][k];
    }
    partials3[blockIdx.x*32 + isq*16 + ch] = acc;
  }
}

// ---------------- final: bn3 -> relu -> wW2 -> softmax(j) -> aggregate --
__global__ __launch_bounds__(256) void k_out(const float* __restrict__ p,
                                             const int* __restrict__ idx,
                                             const float* __restrict__ pW1,
                                             const float* __restrict__ pb1,
                                             const float* __restrict__ pg1,
                                             const float* __restrict__ pbe1,
                                             const float* __restrict__ pW2,
                                             const float* __restrict__ pb2,
                                             const float* __restrict__ wg2,
                                             const float* __restrict__ wbe2,
                                             const float* __restrict__ wW2,
                                             const float* __restrict__ wb2,
                                             const u16* __restrict__ xv,
                                             const u16* __restrict__ w1ws,
                                             const float* __restrict__ mid1,
                                             const float* __restrict__ mid3,
                                             float* __restrict__ out){
  __shared__ __align__(16) float4 pW2t[128];
  __shared__ float pW1f[9];
  __shared__ float bn1s[8];
  __shared__ float sc3[16], sh3[16], wb2f[16];
  __shared__ float wW2f[256];
  __shared__ float s_w2[16*16*16];
  __shared__ float s_q0[256], s_q1[256], s_q2[256];
  __shared__ int   s_g[256];
  const int t = threadIdx.x;
  if (t < 3){
    float sv = 0.f, sq = 0.f;
    for (int i = 0; i < 16; ++i){ sv += mid1[i*8+t]; sq += mid1[i*8+4+t]; }
    float mu = sv * INV_R, var = sq * INV_R - mu*mu;
    float rs = rsqrtf(var + EPS);
    float sc = rs * pg1[t];
    bn1s[t]   = sc;
    bn1s[4+t] = pb1[t] * sc + pbe1[t] - mu * sc;
  }
  if (t < 9) pW1f[t] = pW1[t];
  if (t < 16){
    float sv = 0.f, sq = 0.f;
    for (int i = 0; i < 16; ++i){ sv += mid3[i*32+t]; sq += mid3[i*32+16+t]; }
    float mu = sv * INV_R, var = sq * INV_R - mu*mu;
    float rs = rsqrtf(var + EPS);
    float sc = rs * wg2[t];
    sc3[t] = sc;
    sh3[t] = wbe2[t] - mu * sc;
    wb2f[t] = wb2[t];
  }
  if (t < 128)
    pW2t[t] = make_float4(pW2[t], pW2[128+t], pW2[256+t], pb2[t]);
  wW2f[t] = wW2[t];
  __syncthreads();

  const int pt = t >> 4;
  const int jj = t & 15;
  const int n0 = blockIdx.x * 16;
  {
    const int n = n0 + pt;
    const int r = n * NS + jj;
    const int g = clampg(idx[r]);
    float d0 = p[3*g]   - p[3*n];
    float d1 = p[3*g+1] - p[3*n+1];
    float d2 = p[3*g+2] - p[3*n+2];
    s_q0[t] = fmaxf((d0*pW1f[0] + d1*pW1f[3] + d2*pW1f[6]) * bn1s[0] + bn1s[4], 0.f);
    s_q1[t] = fmaxf((d0*pW1f[1] + d1*pW1f[4] + d2*pW1f[7]) * bn1s[1] + bn1s[5], 0.f);
    s_q2[t] = fmaxf((d0*pW1f[2] + d1*pW1f[5] + d2*pW1f[8]) * bn1s[2] + bn1s[6], 0.f);
    s_g[t]  = g;
    const uint4* wp = (const uint4*)(w1ws + (size_t)r * 16);
    uint4 Wa = wp[0], Wb = wp[1];
    float h2[16];
    #pragma unroll
    for (int o2 = 0; o2 < 4; ++o2){
      float lo, hi;
      b2x2((&Wa.x)[o2], lo, hi);
      h2[o2*2]     = fmaxf(lo * sc3[o2*2]     + sh3[o2*2],     0.f);
      h2[o2*2+1]   = fmaxf(hi * sc3[o2*2+1]   + sh3[o2*2+1],   0.f);
      b2x2((&Wb.x)[o2], lo, hi);
      h2[8+o2*2]   = fmaxf(lo * sc3[8+o2*2]   + sh3[8+o2*2],   0.f);
      h2[8+o2*2+1] = fmaxf(hi * sc3[8+o2*2+1] + sh3[8+o2*2+1], 0.f);
    }
    float w2[16];
    #pragma unroll
    for (int o = 0; o < 16; ++o) w2[o] = wb2f[o];
    #pragma unroll
    for (int o2 = 0; o2 < 16; ++o2){
      float h = h2[o2];
      const float* wr = &wW2f[o2*16];
      #pragma unroll
      for (int o = 0; o < 16; ++o) w2[o] = fmaf(h, wr[o], w2[o]);
    }
    float* dst = &s_w2[(pt*16 + jj)*16];
    #pragma unroll
    for (int o = 0; o < 16; ++o) dst[o] = w2[o];
  }
  __syncthreads();
  const int cs = t & 15;
  {
    float mx = -1e30f;
    #pragma unroll
    for (int j2 = 0; j2 < 16; ++j2) mx = fmaxf(mx, s_w2[(pt*16+j2)*16 + cs]);
    float e[16]; float sum = 0.f;
    #pragma unroll
    for (int j2 = 0; j2 < 16; ++j2){
      e[j2] = __expf(s_w2[(pt*16+j2)*16 + cs] - mx);
      sum += e[j2];
    }
    float inv = 1.0f / sum;
    #pragma unroll
    for (int j2 = 0; j2 < 16; ++j2) s_w2[(pt*16+j2)*16 + cs] = e[j2] * inv;
  }
  __syncthreads();
  const int w = t >> 6, l = t & 63;
  const float4 pwA = pW2t[2*l], pwB = pW2t[2*l+1];
  const int csA = (2*l) & 15;
  #pragma unroll
  for (int pp = 0; pp < 4; ++pp){
    const int pt2 = pp * 4 + w;
    const int n = n0 + pt2;
    float accA = 0.f, accB = 0.f;
    #pragma unroll
    for (int j = 0; j < 16; ++j){
      const int base = pt2*16 + j;
      float2 pj2 = *(const float2*)&s_w2[base*16 + csA];
      int g = s_g[base];
      float qa = s_q0[base], qb = s_q1[base], qc = s_q2[base];
      unsigned v = *(const unsigned*)(xv + (size_t)g*C + 2*l);
      float xvA, xvB; b2x2(v, xvA, xvB);
      float prA = qa*pwA.x + qb*pwA.y + qc*pwA.z + pwA.w;
      float prB = qa*pwB.x + qb*pwB.y + qc*pwB.z + pwB.w;
      accA = fmaf(xvA + prA, pj2.x, accA);
      accB = fmaf(xvB + prB, pj2.y, accB);
    }
    *(float2*)(out + (size_t)n*C + 2*l) = make_float2(accA, accB);
  }
}

extern "C" void kernel_launch(void* const* d_in, const int* in_sizes, int n_in,
                              void* d_out, int out_size, void* d_ws, size_t ws_size,
                              hipStream_t stream) {
  bool ok = (n_in == 23) && (out_size == NP*C) &&
            in_sizes[0] == NP*3 && in_sizes[1] == NP*C &&
            in_sizes[2] == C*C  && in_sizes[8] == 9 &&
            in_sizes[12] == 3*C && in_sizes[16] == C*(C/8) &&
            in_sizes[20] == (C/8)*(C/8) && in_sizes[22] == RTOT;
  if (!ok){
    k_sig<<<(NP*C+255)/256, 256, 0, stream>>>((float*)d_out, 10000.0f);
    return;
  }
  if (ws_size < WS_NEED){
    k_sig<<<(NP*C+255)/256, 256, 0, stream>>>((float*)d_out, 20000.0f);
    return;
  }
  const float* p    = (const float*)d_in[0];
  const float* x    = (const float*)d_in[1];
  const float* Wq   = (const float*)d_in[2];
  const float* bq   = (const float*)d_in[3];
  const float* Wk   = (const float*)d_in[4];
  const float* bk   = (const float*)d_in[5];
  const float* Wv   = (const float*)d_in[6];
  const float* bv   = (const float*)d_in[7];
  const float* pW1  = (const float*)d_in[8];
  const float* pb1  = (const float*)d_in[9];
  const float* pg1  = (const float*)d_in[10];
  const float* pbe1 = (const float*)d_in[11];
  const float* pW2  = (const float*)d_in[12];
  const float* pb2  = (const float*)d_in[13];
  const float* wg1  = (const float*)d_in[14];
  const float* wbe1 = (const float*)d_in[15];
  const float* wW1  = (const float*)d_in[16];
  const float* wb1  = (const float*)d_in[17];
  const float* wg2  = (const float*)d_in[18];
  const float* wbe2 = (const float*)d_in[19];
  const float* wW2  = (const float*)d_in[20];
  const float* wb2  = (const float*)d_in[21];
  const int* idx    = (const int*)d_in[22];

  char* ws = (char*)d_ws;
  u16* xq    = (u16*)(ws + oXQ);
  u16* xk    = (u16*)(ws + oXK);
  u16* xv    = (u16*)(ws + oXV);
  u16* w1ws  = (u16*)(ws + oW1);
  float* pa  = (float*)(ws + oPA);
  float* pb  = (float*)(ws + oPB);
  float* pc  = (float*)(ws + oPC);
  float* m1  = (float*)(ws + oM1);
  float* m2  = (float*)(ws + oM2);
  float* m3  = (float*)(ws + oM3);
  u16* wtp   = (u16*)(ws + oWT);

  k_wt <<<dim3(64, 3), 256, 0, stream>>>(Wq, Wk, Wv, wtp);
  k_qkv<<<512, 256, 0, stream>>>(x, wtp, bq, bk, bv, xq);
  k_bn1<<<512, 256, 0, stream>>>(p, idx, pW1, pb1, pa);
  k_finA<<<dim3(1, 16), 256, 0, stream>>>(pa, m1, 512, 8);
  k_bn2<<<2048, 256, 0, stream>>>(p, idx, pW1, pb1, pg1, pbe1, pW2, pb2,
                                  xq, xk, m1, pb);
  k_finA<<<dim3(4, 16), 256, 0, stream>>>(pb, m2, 2048, 256);
  k_w1 <<<2048, 256, 0, stream>>>(p, idx, pW1, pb1, pg1, pbe1, pW2, pb2,
                                  wg1, wbe1, wW1, wb1, xq, xk, w1ws, m1, m2);
  k_bn3<<<256, 256, 0, stream>>>(w1ws, pc);
  k_finA<<<dim3(1, 16), 256, 0, stream>>>(pc, m3, 256, 32);
  k_out<<<2048, 256, 0, stream>>>(p, idx, pW1, pb1, pg1, pbe1, pW2, pb2,
                                  wg2, wbe2, wW2, wb2, xv, w1ws, m1, m3,
                                  (float*)d_out);
}

// Round 9
// 220.518 us; speedup vs baseline: 10.6411x; 1.0509x over previous
//
#include <hip/hip_runtime.h>

typedef unsigned short u16;
#define DEV __device__ __forceinline__

typedef short bf16x8 __attribute__((ext_vector_type(8)));
typedef float f32x4  __attribute__((ext_vector_type(4)));

constexpr int NP = 32768;
constexpr int C  = 128;
constexpr int NS = 16;
constexpr int RTOT = NP * NS;              // 524288 rows of [N,NS]
constexpr float EPS = 1e-5f;
constexpr float INV_R = 1.0f / (float)RTOT;

// ---- workspace layout (bytes). Measured: harness poisons 256 MiB of ws. --
constexpr size_t oXQ = 0;                              // xq bf16 8MB
constexpr size_t oXK = (size_t)NP * C * 2;             // xk bf16 8MB
constexpr size_t oXV = oXK * 2;                        // xv bf16 8MB
constexpr size_t oW1 = oXK * 3;                        // w1 logits bf16 16MB
constexpr size_t oPA = oW1 + (size_t)RTOT * 16 * 2;    // pa [512][8] f32
constexpr size_t oPB = oPA + 512*8*4;                  // pb [2048][256] f32 2MB
constexpr size_t oPC = oPB + (size_t)2048*256*4;       // pc [2048][32] f32 256KB
constexpr size_t oM1 = oPC + (size_t)2048*32*4;        // mid1[16][8]
constexpr size_t oM2 = oM1 + 16*8*4;                   // mid2[16][256]
constexpr size_t oM3 = oM2 + 16*256*4;                 // mid3[16][32]
constexpr size_t oWT = oM3 + 16*32*4;                  // Wt bf16 [3][128][128]
constexpr size_t WS_NEED = oWT + 3*128*128*2;          // ~44.4 MB << 256 MiB

DEV float bu2f(u16 v){ return __uint_as_float(((unsigned)v) << 16); }
DEV u16 f2bu(float f){
  unsigned u = __float_as_uint(f);
  return (u16)((u + 0x7fffu + ((u >> 16) & 1u)) >> 16);   // RNE
}
DEV unsigned pk2(float a, float b){ return (unsigned)f2bu(a) | ((unsigned)f2bu(b) << 16); }
DEV unsigned pk2tr(float a, float b){   // truncating bf16 pack (staging only)
  return (__float_as_uint(a) >> 16) | (__float_as_uint(b) & 0xffff0000u);
}
DEV void b2x2(unsigned v, float& lo, float& hi){
  lo = __uint_as_float(v << 16);
  hi = __uint_as_float(v & 0xffff0000u);
}
DEV int clampg(int g){ return g < 0 ? 0 : (g > NP-1 ? NP-1 : g); }

// ---------------- diagnostics ----------------
__global__ __launch_bounds__(256) void k_sig(float* __restrict__ out, float val){
  int i = blockIdx.x * 256 + threadIdx.x;
  if (i < NP*C) out[i] = val;
}

// ---------------- stage-1 partial reduce: mid[y][ch] = sum of slot chunk --
__global__ __launch_bounds__(256) void k_finA(const float* __restrict__ part,
                                              float* __restrict__ mid,
                                              int slots, int width){
  __shared__ float red[4][64];
  const int l = threadIdx.x & 63, w = threadIdx.x >> 6;
  const int ch = blockIdx.x * 64 + l;
  const int y = blockIdx.y;
  const int cs = slots >> 4;           // 16 slot-groups
  const int n4 = cs >> 2;              // per-wave slot count
  float a0 = 0.f, a1 = 0.f, a2 = 0.f, a3 = 0.f;
  if (ch < width){
    const float* base = part + (size_t)(y*cs + w*n4) * width + ch;
    int j = 0;
    for (; j + 4 <= n4; j += 4){
      a0 += base[(size_t)(j  ) * width];
      a1 += base[(size_t)(j+1) * width];
      a2 += base[(size_t)(j+2) * width];
      a3 += base[(size_t)(j+3) * width];
    }
    for (; j < n4; ++j) a0 += base[(size_t)j * width];
  }
  red[w][l] = (a0 + a1) + (a2 + a3);
  __syncthreads();
  if (threadIdx.x < 64 && ch < width)
    mid[(size_t)y * width + ch] = red[0][l] + red[1][l] + red[2][l] + red[3][l];
}

// ---------------- Wt: transpose + bf16-convert Wq/Wk/Wv -----------------
__global__ __launch_bounds__(256) void k_wt(const float* __restrict__ Wq,
                                            const float* __restrict__ Wk,
                                            const float* __restrict__ Wv,
                                            u16* __restrict__ wt){
  const int mat = blockIdx.y;
  const float* W = (mat==0) ? Wq : ((mat==1) ? Wk : Wv);
  int e = blockIdx.x * 256 + threadIdx.x;     // 64 blocks * 256 = 16384
  int k = e >> 7, c = e & 127;
  wt[mat*16384 + c*128 + k] = f2bu(W[e]);
}

// ---------------- QKV GEMM via MFMA (bf16) ------------------------------
__global__ __launch_bounds__(256) void k_qkv(const float* __restrict__ x,
                                             const u16* __restrict__ wt,
                                             const float* __restrict__ bq,
                                             const float* __restrict__ bk,
                                             const float* __restrict__ bv,
                                             u16* __restrict__ outw){
  __shared__ __align__(16) u16 xb[64*136];     // 17.4 KB
  __shared__ __align__(16) u16 wtl[128*136];   // 34.8 KB
  const int t = threadIdx.x;
  const int row0 = blockIdx.x * 64;
  {
    const float4* xs = (const float4*)(x + (size_t)row0 * C);
    #pragma unroll
    for (int i = 0; i < 8; ++i){
      int chunk = t + i*256;            // 2048 float4 chunks
      int row = chunk >> 5;             // 32 float4 per row
      int cp  = (chunk & 31) * 4;
      float4 v = xs[chunk];
      *(uint2*)&xb[row*136 + cp] = make_uint2(pk2(v.x, v.y), pk2(v.z, v.w));
    }
  }
  __syncthreads();
  const int w = t >> 6, l = t & 63;
  const int quad = l >> 4, col = l & 15;
  bf16x8 afrag[4];
  {
    const u16* abase = &xb[(size_t)(w*16 + col) * 136];
    #pragma unroll
    for (int kk = 0; kk < 4; ++kk)
      afrag[kk] = *(const bf16x8*)(abase + kk*32 + quad*8);
  }
  for (int mat = 0; mat < 3; ++mat){
    const float* bias = (mat==0) ? bq : ((mat==1) ? bk : bv);
    {
      const uint4* ws4 = (const uint4*)(wt + mat*16384);
      #pragma unroll
      for (int i = 0; i < 8; ++i){
        int chunk = t + i*256;          // 2048 chunks of 8 bf16
        int c = chunk >> 4, kp = (chunk & 15) * 8;
        *(uint4*)&wtl[c*136 + kp] = ws4[chunk];
      }
    }
    __syncthreads();
    u16* outp = outw + (size_t)mat * NP * C + (size_t)(row0 + w*16) * C;
    #pragma unroll
    for (int ct = 0; ct < 8; ++ct){
      bf16x8 bfrag[4];
      const u16* bbase = &wtl[(size_t)(ct*16 + col) * 136];
      #pragma unroll
      for (int kk = 0; kk < 4; ++kk)
        bfrag[kk] = *(const bf16x8*)(bbase + kk*32 + quad*8);
      float bv0 = bias[ct*16 + col];
      f32x4 acc; acc[0] = bv0; acc[1] = bv0; acc[2] = bv0; acc[3] = bv0;
      #pragma unroll
      for (int kk = 0; kk < 4; ++kk)
        acc = __builtin_amdgcn_mfma_f32_16x16x32_bf16(afrag[kk], bfrag[kk], acc, 0, 0, 0);
      #pragma unroll
      for (int i = 0; i < 4; ++i)
        outp[(size_t)(quad*4 + i) * C + ct*16 + col] = f2bu(acc[i]);
    }
    __syncthreads();
  }
}

// ---------------- bn1 stats -> per-block partials (no atomics) ----------
__global__ __launch_bounds__(256) void k_bn1(const float* __restrict__ p,
                                             const int* __restrict__ idx,
                                             const float* __restrict__ pW1,
                                             const float* __restrict__ pb1,
                                             float* __restrict__ partials1){
  __shared__ float wred[4][8];
  const int t = threadIdx.x;
  float w[9], b3[3];
  #pragma unroll
  for (int i = 0; i < 9; ++i) w[i] = pW1[i];
  #pragma unroll
  for (int i = 0; i < 3; ++i) b3[i] = pb1[i];
  float s[3] = {0,0,0}, q[3] = {0,0,0};
  const int base = blockIdx.x * 1024 + t;
  #pragma unroll
  for (int i = 0; i < 4; ++i){
    int r = base + i*256;
    int g = clampg(idx[r]);
    int n = r >> 4;
    float d0 = p[3*g]   - p[3*n];
    float d1 = p[3*g+1] - p[3*n+1];
    float d2 = p[3*g+2] - p[3*n+2];
    #pragma unroll
    for (int k = 0; k < 3; ++k){
      float tv = d0*w[k] + d1*w[3+k] + d2*w[6+k] + b3[k];
      s[k] += tv; q[k] = fmaf(tv, tv, q[k]);
    }
  }
  #pragma unroll
  for (int k = 0; k < 3; ++k){
    #pragma unroll
    for (int m = 1; m < 64; m <<= 1){
      s[k] += __shfl_xor(s[k], m);
      q[k] += __shfl_xor(q[k], m);
    }
  }
  if ((t & 63) == 0){
    int wv = t >> 6;
    wred[wv][0] = s[0]; wred[wv][1] = s[1]; wred[wv][2] = s[2]; wred[wv][3] = 0.f;
    wred[wv][4] = q[0]; wred[wv][5] = q[1]; wred[wv][6] = q[2]; wred[wv][7] = 0.f;
  }
  __syncthreads();
  if (t < 8)
    partials1[blockIdx.x*8 + t] = wred[0][t] + wred[1][t] + wred[2][t] + wred[3][t];
}

// ---------------- bn2 stats: full-parallel phase A, 2 barriers ----------
__global__ __launch_bounds__(256) void k_bn2(const float* __restrict__ p,
                                             const int* __restrict__ idx,
                                             const float* __restrict__ pW1,
                                             const float* __restrict__ pb1,
                                             const float* __restrict__ pg1,
                                             const float* __restrict__ pbe1,
                                             const float* __restrict__ pW2,
                                             const float* __restrict__ pb2,
                                             const u16* __restrict__ xq,
                                             const u16* __restrict__ xk,
                                             const float* __restrict__ mid1,
                                             float* __restrict__ partials2){
  __shared__ float sq0[256], sq1[256], sq2[256];
  __shared__ int   sgi[256];
  __shared__ __align__(16) float4 pW2t[128];
  __shared__ float bn1s[8];
  __shared__ __align__(16) float redS[4][128], redQ[4][128];
  const int t = threadIdx.x;
  if (t < 3){
    float sv = 0.f, sq = 0.f;
    for (int i = 0; i < 16; ++i){ sv += mid1[i*8+t]; sq += mid1[i*8+4+t]; }
    float mu = sv * INV_R, var = sq * INV_R - mu*mu;
    float rs = rsqrtf(var + EPS);
    float sc = rs * pg1[t];
    bn1s[t]   = sc;
    bn1s[4+t] = pb1[t] * sc + pbe1[t] - mu * sc;
  }
  if (t < 128)
    pW2t[t] = make_float4(pW2[t], pW2[128+t], pW2[256+t], pb2[t]);
  float w9[9];
  #pragma unroll
  for (int i = 0; i < 9; ++i) w9[i] = pW1[i];
  __syncthreads();
  // phase A: all 256 rows of this block, all threads
  {
    int r = blockIdx.x * 256 + t, n = r >> 4;
    int g = clampg(idx[r]);
    float d0 = p[3*g]   - p[3*n];
    float d1 = p[3*g+1] - p[3*n+1];
    float d2 = p[3*g+2] - p[3*n+2];
    sq0[t] = fmaxf((d0*w9[0] + d1*w9[3] + d2*w9[6]) * bn1s[0] + bn1s[4], 0.f);
    sq1[t] = fmaxf((d0*w9[1] + d1*w9[4] + d2*w9[7]) * bn1s[1] + bn1s[5], 0.f);
    sq2[t] = fmaxf((d0*w9[2] + d1*w9[5] + d2*w9[8]) * bn1s[2] + bn1s[6], 0.f);
    sgi[t] = g;
  }
  __syncthreads();
  const int w = t >> 6, l = t & 63;
  const float4 pwA = pW2t[2*l], pwB = pW2t[2*l+1];
  float sA = 0.f, qA = 0.f, sB = 0.f, qB = 0.f;
  #pragma unroll
  for (int pp = 0; pp < 4; ++pp){
    const int nl = w*4 + pp;                  // wave-local point (16/block)
    const int n  = blockIdx.x*16 + nl;
    unsigned qx = *(const unsigned*)(xq + (size_t)n*C + 2*l);
    float xqA, xqB; b2x2(qx, xqA, xqB);
    #pragma unroll
    for (int j = 0; j < 16; ++j){
      int rr = nl*16 + j;
      int g = sgi[rr];
      unsigned kx = *(const unsigned*)(xk + (size_t)g*C + 2*l);
      float xkA, xkB; b2x2(kx, xkA, xkB);
      float prA = sq0[rr]*pwA.x + sq1[rr]*pwA.y + sq2[rr]*pwA.z + pwA.w;
      float prB = sq0[rr]*pwB.x + sq1[rr]*pwB.y + sq2[rr]*pwB.z + pwB.w;
      float w0A = xkA - xqA + prA;
      float w0B = xkB - xqB + prB;
      sA += w0A; qA = fmaf(w0A, w0A, qA);
      sB += w0B; qB = fmaf(w0B, w0B, qB);
    }
  }
  *(float2*)&redS[w][2*l] = make_float2(sA, sB);
  *(float2*)&redQ[w][2*l] = make_float2(qA, qB);
  __syncthreads();
  if (t < 128){
    partials2[(size_t)blockIdx.x*256 + t]       = redS[0][t]+redS[1][t]+redS[2][t]+redS[3][t];
    partials2[(size_t)blockIdx.x*256 + 128 + t] = redQ[0][t]+redQ[1][t]+redQ[2][t]+redQ[3][t];
  }
}

// ---------------- w1 = relu(bn2(w0)) @ wW1 + wb1 ; MFMA + fused bn3 -----
// Phase A once for 256 rows (all threads). Per 64-row tile: wave-per-point
// gather -> h bf16 in LDS, MFMA 16x16, store. bn3 partials accumulated in
// fp32 from MFMA accs, reduced per block -> pc[2048][32]. No k_bn3 pass.
__global__ __launch_bounds__(256) void k_w1(const float* __restrict__ p,
                                            const int* __restrict__ idx,
                                            const float* __restrict__ pW1,
                                            const float* __restrict__ pb1,
                                            const float* __restrict__ pg1,
                                            const float* __restrict__ pbe1,
                                            const float* __restrict__ pW2,
                                            const float* __restrict__ pb2,
                                            const float* __restrict__ wg1,
                                            const float* __restrict__ wbe1,
                                            const float* __restrict__ wW1,
                                            const float* __restrict__ wb1,
                                            const u16* __restrict__ xq,
                                            const u16* __restrict__ xk,
                                            u16* __restrict__ w1out,
                                            const float* __restrict__ mid1,
                                            const float* __restrict__ mid2,
                                            float* __restrict__ pc){
  __shared__ __align__(16) float4 pW2t[128];
  __shared__ float2 ss2[128];
  __shared__ float bn1s[8];
  __shared__ float wb1f[16];
  __shared__ float pW1f[9];
  __shared__ float sq0[256], sq1[256], sq2[256];
  __shared__ int   sgi[256];
  __shared__ __align__(16) u16 hsb[64*136];   // bf16 h, 17.4 KB, pad 136
  __shared__ float wredS[4][16], wredQ[4][16];
  const int t = threadIdx.x;
  if (t < 3){
    float sv = 0.f, sq = 0.f;
    for (int i = 0; i < 16; ++i){ sv += mid1[i*8+t]; sq += mid1[i*8+4+t]; }
    float mu = sv * INV_R, var = sq * INV_R - mu*mu;
    float rs = rsqrtf(var + EPS);
    float sc = rs * pg1[t];
    bn1s[t]   = sc;
    bn1s[4+t] = pb1[t] * sc + pbe1[t] - mu * sc;
  }
  if (t < 9)  pW1f[t] = pW1[t];
  if (t < 16) wb1f[t] = wb1[t];
  if (t < 128){
    pW2t[t] = make_float4(pW2[t], pW2[128+t], pW2[256+t], pb2[t]);
    float sv = 0.f, sq = 0.f;
    for (int i = 0; i < 16; ++i){ sv += mid2[i*256+t]; sq += mid2[i*256+128+t]; }
    float mu = sv * INV_R, var = sq * INV_R - mu*mu;
    float rs = rsqrtf(var + EPS);
    float sc = rs * wg1[t];
    ss2[t] = make_float2(sc, wbe1[t] - mu * sc);
  }
  const int w = t >> 6, l = t & 63;
  const int quad = l >> 4, col = l & 15;
  bf16x8 bfrag[4];
  #pragma unroll
  for (int kk = 0; kk < 4; ++kk){
    #pragma unroll
    for (int j = 0; j < 8; ++j)
      bfrag[kk][j] = (short)f2bu(wW1[(size_t)(kk*32 + quad*8 + j)*16 + col]);
  }
  __syncthreads();
  // phase A: all 256 rows
  {
    int r = blockIdx.x * 256 + t, n = r >> 4;
    int g = clampg(idx[r]);
    float d0 = p[3*g]   - p[3*n];
    float d1 = p[3*g+1] - p[3*n+1];
    float d2 = p[3*g+2] - p[3*n+2];
    sq0[t] = fmaxf((d0*pW1f[0] + d1*pW1f[3] + d2*pW1f[6]) * bn1s[0] + bn1s[4], 0.f);
    sq1[t] = fmaxf((d0*pW1f[1] + d1*pW1f[4] + d2*pW1f[7]) * bn1s[1] + bn1s[5], 0.f);
    sq2[t] = fmaxf((d0*pW1f[2] + d1*pW1f[5] + d2*pW1f[8]) * bn1s[2] + bn1s[6], 0.f);
    sgi[t] = g;
  }
  __syncthreads();

  const float4 pwA = pW2t[2*l], pwB = pW2t[2*l+1];
  const float2 scA = ss2[2*l],  scB = ss2[2*l+1];
  const float biasC = wb1f[col];
  float sSt = 0.f, qSt = 0.f;            // fused bn3 per-lane partials

  for (int tile = 0; tile < 4; ++tile){
    // phase B: wave w gathers point nl = tile*4+w (16 rows)
    {
      const int nl = tile*4 + w;
      const int n  = blockIdx.x*16 + nl;
      unsigned qx = *(const unsigned*)(xq + (size_t)n*C + 2*l);
      float xqA, xqB; b2x2(qx, xqA, xqB);
      #pragma unroll
      for (int j = 0; j < 16; ++j){
        int rrb = nl*16 + j;             // block-space row
        int g = sgi[rrb];
        unsigned kx = *(const unsigned*)(xk + (size_t)g*C + 2*l);
        float xkA, xkB; b2x2(kx, xkA, xkB);
        float prA = sq0[rrb]*pwA.x + sq1[rrb]*pwA.y + sq2[rrb]*pwA.z + pwA.w;
        float prB = sq0[rrb]*pwB.x + sq1[rrb]*pwB.y + sq2[rrb]*pwB.z + pwB.w;
        float hA = fmaxf(fmaf(xkA - xqA + prA, scA.x, scA.y), 0.f);
        float hB = fmaxf(fmaf(xkB - xqB + prB, scB.x, scB.y), 0.f);
        *(unsigned*)&hsb[(w*16 + j)*136 + 2*l] = pk2tr(hA, hB);
      }
    }
    __syncthreads();
    // phase C: MFMA 16x16 per wave + bn3 accumulation
    f32x4 acc;
    acc[0] = biasC; acc[1] = biasC; acc[2] = biasC; acc[3] = biasC;
    const u16* hbase = &hsb[(size_t)(w*16 + col) * 136];
    #pragma unroll
    for (int kk = 0; kk < 4; ++kk){
      bf16x8 af = *(const bf16x8*)(hbase + kk*32 + quad*8);
      acc = __builtin_amdgcn_mfma_f32_16x16x32_bf16(af, bfrag[kk], acc, 0, 0, 0);
    }
    const int rowbase = blockIdx.x*256 + tile*64 + w*16 + quad*4;
    #pragma unroll
    for (int i = 0; i < 4; ++i){
      w1out[(size_t)(rowbase + i) * 16 + col] = f2bu(acc[i]);
      sSt += acc[i];
      qSt = fmaf(acc[i], acc[i], qSt);
    }
    __syncthreads();
  }
  // reduce bn3 partials: combine quads (lanes same col), then waves
  sSt += __shfl_xor(sSt, 16); sSt += __shfl_xor(sSt, 32);
  qSt += __shfl_xor(qSt, 16); qSt += __shfl_xor(qSt, 32);
  if (l < 16){ wredS[w][l] = sSt; wredQ[w][l] = qSt; }
  __syncthreads();
  if (t < 16)
    pc[(size_t)blockIdx.x*32 + t] = wredS[0][t]+wredS[1][t]+wredS[2][t]+wredS[3][t];
  else if (t < 32){
    int c = t - 16;
    pc[(size_t)blockIdx.x*32 + 16 + c] = wredQ[0][c]+wredQ[1][c]+wredQ[2][c]+wredQ[3][c];
  }
}

// ---------------- final: bn3 -> relu -> wW2 -> softmax(j) -> aggregate --
__global__ __launch_bounds__(256) void k_out(const float* __restrict__ p,
                                             const int* __restrict__ idx,
                                             const float* __restrict__ pW1,
                                             const float* __restrict__ pb1,
                                             const float* __restrict__ pg1,
                                             const float* __restrict__ pbe1,
                                             const float* __restrict__ pW2,
                                             const float* __restrict__ pb2,
                                             const float* __restrict__ wg2,
                                             const float* __restrict__ wbe2,
                                             const float* __restrict__ wW2,
                                             const float* __restrict__ wb2,
                                             const u16* __restrict__ xv,
                                             const u16* __restrict__ w1ws,
                                             const float* __restrict__ mid1,
                                             const float* __restrict__ mid3,
                                             float* __restrict__ out){
  __shared__ __align__(16) float4 pW2t[128];
  __shared__ float pW1f[9];
  __shared__ float bn1s[8];
  __shared__ float sc3[16], sh3[16], wb2f[16];
  __shared__ float wW2f[256];
  __shared__ float s_w2[16*16*16];
  __shared__ float s_q0[256], s_q1[256], s_q2[256];
  __shared__ int   s_g[256];
  const int t = threadIdx.x;
  if (t < 3){
    float sv = 0.f, sq = 0.f;
    for (int i = 0; i < 16; ++i){ sv += mid1[i*8+t]; sq += mid1[i*8+4+t]; }
    float mu = sv * INV_R, var = sq * INV_R - mu*mu;
    float rs = rsqrtf(var + EPS);
    float sc = rs * pg1[t];
    bn1s[t]   = sc;
    bn1s[4+t] = pb1[t] * sc + pbe1[t] - mu * sc;
  }
  if (t < 9) pW1f[t] = pW1[t];
  if (t < 16){
    float sv = 0.f, sq = 0.f;
    for (int i = 0; i < 16; ++i){ sv += mid3[i*32+t]; sq += mid3[i*32+16+t]; }
    float mu = sv * INV_R, var = sq * INV_R - mu*mu;
    float rs = rsqrtf(var + EPS);
    float sc = rs * wg2[t];
    sc3[t] = sc;
    sh3[t] = wbe2[t] - mu * sc;
    wb2f[t] = wb2[t];
  }
  if (t < 128)
    pW2t[t] = make_float4(pW2[t], pW2[128+t], pW2[256+t], pb2[t]);
  wW2f[t] = wW2[t];
  __syncthreads();

  const int pt = t >> 4;
  const int jj = t & 15;
  const int n0 = blockIdx.x * 16;
  {
    const int n = n0 + pt;
    const int r = n * NS + jj;
    const int g = clampg(idx[r]);
    float d0 = p[3*g]   - p[3*n];
    float d1 = p[3*g+1] - p[3*n+1];
    float d2 = p[3*g+2] - p[3*n+2];
    s_q0[t] = fmaxf((d0*pW1f[0] + d1*pW1f[3] + d2*pW1f[6]) * bn1s[0] + bn1s[4], 0.f);
    s_q1[t] = fmaxf((d0*pW1f[1] + d1*pW1f[4] + d2*pW1f[7]) * bn1s[1] + bn1s[5], 0.f);
    s_q2[t] = fmaxf((d0*pW1f[2] + d1*pW1f[5] + d2*pW1f[8]) * bn1s[2] + bn1s[6], 0.f);
    s_g[t]  = g;
    const uint4* wp = (const uint4*)(w1ws + (size_t)r * 16);
    uint4 Wa = wp[0], Wb = wp[1];
    float h2[16];
    #pragma unroll
    for (int o2 = 0; o2 < 4; ++o2){
      float lo, hi;
      b2x2((&Wa.x)[o2], lo, hi);
      h2[o2*2]     = fmaxf(lo * sc3[o2*2]     + sh3[o2*2],     0.f);
      h2[o2*2+1]   = fmaxf(hi * sc3[o2*2+1]   + sh3[o2*2+1],   0.f);
      b2x2((&Wb.x)[o2], lo, hi);
      h2[8+o2*2]   = fmaxf(lo * sc3[8+o2*2]   + sh3[8+o2*2],   0.f);
      h2[8+o2*2+1] = fmaxf(hi * sc3[8+o2*2+1] + sh3[8+o2*2+1], 0.f);
    }
    float w2[16];
    #pragma unroll
    for (int o = 0; o < 16; ++o) w2[o] = wb2f[o];
    #pragma unroll
    for (int o2 = 0; o2 < 16; ++o2){
      float h = h2[o2];
      const float* wr = &wW2f[o2*16];
      #pragma unroll
      for (int o = 0; o < 16; ++o) w2[o] = fmaf(h, wr[o], w2[o]);
    }
    float* dst = &s_w2[(pt*16 + jj)*16];
    #pragma unroll
    for (int o = 0; o < 16; ++o) dst[o] = w2[o];
  }
  __syncthreads();
  const int cs = t & 15;
  {
    float mx = -1e30f;
    #pragma unroll
    for (int j2 = 0; j2 < 16; ++j2) mx = fmaxf(mx, s_w2[(pt*16+j2)*16 + cs]);
    float e[16]; float sum = 0.f;
    #pragma unroll
    for (int j2 = 0; j2 < 16; ++j2){
      e[j2] = __expf(s_w2[(pt*16+j2)*16 + cs] - mx);
      sum += e[j2];
    }
    float inv = 1.0f / sum;
    #pragma unroll
    for (int j2 = 0; j2 < 16; ++j2) s_w2[(pt*16+j2)*16 + cs] = e[j2] * inv;
  }
  __syncthreads();
  const int w = t >> 6, l = t & 63;
  const float4 pwA = pW2t[2*l], pwB = pW2t[2*l+1];
  const int csA = (2*l) & 15;
  #pragma unroll
  for (int pp = 0; pp < 4; ++pp){
    const int pt2 = pp * 4 + w;
    const int n = n0 + pt2;
    float accA = 0.f, accB = 0.f;
    #pragma unroll
    for (int j = 0; j < 16; ++j){
      const int base = pt2*16 + j;
      float2 pj2 = *(const float2*)&s_w2[base*16 + csA];
      int g = s_g[base];
      float qa = s_q0[base], qb = s_q1[base], qc = s_q2[base];
      unsigned v = *(const unsigned*)(xv + (size_t)g*C + 2*l);
      float xvA, xvB; b2x2(v, xvA, xvB);
      float prA = qa*pwA.x + qb*pwA.y + qc*pwA.z + pwA.w;
      float prB = qa*pwB.x + qb*pwB.y + qc*pwB.z + pwB.w;
      accA = fmaf(xvA + prA, pj2.x, accA);
      accB = fmaf(xvB + prB, pj2.y, accB);
    }
    *(float2*)(out + (size_t)n*C + 2*l) = make_float2(accA, accB);
  }
}

extern "C" void kernel_launch(void* const* d_in, const int* in_sizes, int n_in,
                              void* d_out, int out_size, void* d_ws, size_t ws_size,
                              hipStream_t stream) {
  bool ok = (n_in == 23) && (out_size == NP*C) &&
            in_sizes[0] == NP*3 && in_sizes[1] == NP*C &&
            in_sizes[2] == C*C  && in_sizes[8] == 9 &&
            in_sizes[12] == 3*C && in_sizes[16] == C*(C/8) &&
            in_sizes[20] == (C/8)*(C/8) && in_sizes[22] == RTOT;
  if (!ok){
    k_sig<<<(NP*C+255)/256, 256, 0, stream>>>((float*)d_out, 10000.0f);
    return;
  }
  if (ws_size < WS_NEED){
    k_sig<<<(NP*C+255)/256, 256, 0, stream>>>((float*)d_out, 20000.0f);
    return;
  }
  const float* p    = (const float*)d_in[0];
  const float* x    = (const float*)d_in[1];
  const float* Wq   = (const float*)d_in[2];
  const float* bq   = (const float*)d_in[3];
  const float* Wk   = (const float*)d_in[4];
  const float* bk   = (const float*)d_in[5];
  const float* Wv   = (const float*)d_in[6];
  const float* bv   = (const float*)d_in[7];
  const float* pW1  = (const float*)d_in[8];
  const float* pb1  = (const float*)d_in[9];
  const float* pg1  = (const float*)d_in[10];
  const float* pbe1 = (const float*)d_in[11];
  const float* pW2  = (const float*)d_in[12];
  const float* pb2  = (const float*)d_in[13];
  const float* wg1  = (const float*)d_in[14];
  const float* wbe1 = (const float*)d_in[15];
  const float* wW1  = (const float*)d_in[16];
  const float* wb1  = (const float*)d_in[17];
  const float* wg2  = (const float*)d_in[18];
  const float* wbe2 = (const float*)d_in[19];
  const float* wW2  = (const float*)d_in[20];
  const float* wb2  = (const float*)d_in[21];
  const int* idx    = (const int*)d_in[22];

  char* ws = (char*)d_ws;
  u16* xq    = (u16*)(ws + oXQ);
  u16* xk    = (u16*)(ws + oXK);
  u16* xv    = (u16*)(ws + oXV);
  u16* w1ws  = (u16*)(ws + oW1);
  float* pa  = (float*)(ws + oPA);
  float* pb  = (float*)(ws + oPB);
  float* pc  = (float*)(ws + oPC);
  float* m1  = (float*)(ws + oM1);
  float* m2  = (float*)(ws + oM2);
  float* m3  = (float*)(ws + oM3);
  u16* wtp   = (u16*)(ws + oWT);

  k_wt <<<dim3(64, 3), 256, 0, stream>>>(Wq, Wk, Wv, wtp);
  k_qkv<<<512, 256, 0, stream>>>(x, wtp, bq, bk, bv, xq);
  k_bn1<<<512, 256, 0, stream>>>(p, idx, pW1, pb1, pa);
  k_finA<<<dim3(1, 16), 256, 0, stream>>>(pa, m1, 512, 8);
  k_bn2<<<2048, 256, 0, stream>>>(p, idx, pW1, pb1, pg1, pbe1, pW2, pb2,
                                  xq, xk, m1, pb);
  k_finA<<<dim3(4, 16), 256, 0, stream>>>(pb, m2, 2048, 256);
  k_w1 <<<2048, 256, 0, stream>>>(p, idx, pW1, pb1, pg1, pbe1, pW2, pb2,
                                  wg1, wbe1, wW1, wb1, xq, xk, w1ws, m1, m2, pc);
  k_finA<<<dim3(1, 16), 256, 0, stream>>>(pc, m3, 2048, 32);
  k_out<<<2048, 256, 0, stream>>>(p, idx, pW1, pb1, pg1, pbe1, pW2, pb2,
                                  wg2, wbe2, wW2, wb2, xv, w1ws, m1, m3,
                                  (float*)d_out);
}